// Round 2
// baseline (812.662 us; speedup 1.0000x reference)
//
#include <hip/hip_runtime.h>
#include <hip/hip_cooperative_groups.h>
#include <hip/hip_bf16.h>
#include <math.h>

namespace cg = cooperative_groups;

#define B_ 2
#define T_ 1024
#define HID_ 768
#define INTER_ 1536
#define NH_ 24
#define HD_ 64
#define NS_ 128
#define NLVL_ 15
#define CONV_DIM_ 1792
#define P_ 3712
#define EPS_ 1e-5f

typedef short short8_t __attribute__((ext_vector_type(8)));
typedef short short4_t __attribute__((ext_vector_type(4)));
typedef float float4_t __attribute__((ext_vector_type(4)));

// K-permutation (within each 32-element K-group): physical p = 8a + 4h + r for
// logical k = 16h + 4a + r. A lane's MFMA operand (k = lg*4+{0..3} and +16) is then
// ONE contiguous 16B chunk at p = 8*lg  ->  single ds_read_b128 per fragment.

__device__ __forceinline__ float softplus_f(float x) {
  return (x > 20.f) ? x : log1pf(__expf(x));
}
__device__ __forceinline__ short f2bf(float f) {
  union { float f; unsigned u; } v; v.f = f;
  unsigned r = v.u + 0x7FFF + ((v.u >> 16) & 1);   // RNE
  return (short)(r >> 16);
}
__device__ __forceinline__ float bf2f(short s) {
  union { unsigned u; float f; } v; v.u = ((unsigned)(unsigned short)s) << 16;
  return v.f;
}
__device__ __forceinline__ void gl_lds16(const void* g, void* l) {
  __builtin_amdgcn_global_load_lds(
      (const __attribute__((address_space(1))) unsigned int*)g,
      (__attribute__((address_space(3))) unsigned int*)l, 16, 0, 0);
}

// Permuted LDS fragment read (BK-panel of 32 K): one b128 per fragment.
__device__ __forceinline__ short8_t ldfrag(const short* Ts, int row, int lg) {
  return *(const short8_t*)(Ts + row * 32 + lg * 8);
}

// Permuted+row-swizzled 64-wide fragment read (attn): one b128 per fragment.
__device__ __forceinline__ short8_t ldfrag64(const short* Ts, int row, int kk, int lg) {
  const int cc = (kk * 4 + lg) ^ (row & 7);
  return *(const short8_t*)(Ts + row * 64 + cc * 8);
}

// =====================================================================================
// MEGA KERNEL: whole pipeline, 512 blocks x 256 threads (2 blocks/CU @ 64KB LDS),
// phases separated by grid-wide sync. Eliminates 6 kernel-boundary gaps/drains.
// =====================================================================================
struct MegaArgs {
  const float *hs, *Win, *cw, *cb, *dtb, *Alog, *Lw, *Dv, *nw, *Wout;
  float *out;
  short *hsbf, *wibf, *wobf;
  float *dtraw, *dtT, *cAT, *qT;
  short *projh, *xTr, *xTq, *Bh, *Chh, *CBh, *ybh, *ynrmb;
};

__global__ __launch_bounds__(256, 2) void mega_k(MegaArgs a)
{
  cg::grid_group grid = cg::this_grid();
  const int bid = blockIdx.x;
  const int tid = threadIdx.x;
  const int w = tid >> 6, lane = tid & 63;
  const int lr = lane & 15, lg = lane >> 4;
  const int wr = w >> 1, wc = w & 1;
  __shared__ char SMEM[65536] __attribute__((aligned(16)));

  // ---------------- phase 0: f32->bf16 K-permuted cvt (hs/Win/Wout) + fp32 dt columns ----------
  {
    const long na = (long)B_ * T_ * HID_, nb = (long)P_ * HID_, nc = (long)HID_ * INTER_;
    const long tot8 = (na + nb + nc) / 8;
    for (long it = (long)bid * 256 + tid; it < tot8; it += 512L * 256) {
      const long i = it * 8;
      const float* src; short* dst; long off;
      if (i < na)           { src = a.hs;   dst = a.hsbf; off = i; }
      else if (i < na + nb) { src = a.Win;  dst = a.wibf; off = i - na; }
      else                  { src = a.Wout; dst = a.wobf; off = i - na - nb; }
      const long base = (off & ~31L) + ((off >> 3) & 3) * 4;
      float4 v0 = *(const float4*)(src + base);
      float4 v1 = *(const float4*)(src + base + 16);
      short8_t o;
      o[0] = f2bf(v0.x); o[1] = f2bf(v0.y); o[2] = f2bf(v0.z); o[3] = f2bf(v0.w);
      o[4] = f2bf(v1.x); o[5] = f2bf(v1.y); o[6] = f2bf(v1.z); o[7] = f2bf(v1.w);
      *(short8_t*)(dst + off) = o;
    }
    // dt GEMV: one bt-row per wave, 4 per block (512*4 = 2048)
    const int rowbt = bid * 4 + w;
    float hv[12];
    const float* hrow = a.hs + (long)rowbt * HID_ + lane * 12;
    #pragma unroll
    for (int j = 0; j < 12; j++) hv[j] = hrow[j];
    const float* wbase = a.Win + (long)(INTER_ + CONV_DIM_) * HID_ + lane * 12;
    for (int h = 0; h < NH_; h++) {
      const float* wrp = wbase + (long)h * HID_;
      float s = 0.f;
      #pragma unroll
      for (int j = 0; j < 12; j++) s = fmaf(hv[j], wrp[j], s);
      #pragma unroll
      for (int sof = 32; sof; sof >>= 1) s += __shfl_xor(s, sof);
      if (lane == 0) a.dtraw[(long)rowbt * NH_ + h] = s;
    }
  }
  __threadfence();
  grid.sync();

  // ---------------- phase 1: in-proj GEMM (128x128, BK=64, bf16 out) + dt_scan ----------------
  {
    if (bid < 464) {
      constexpr int K = HID_, BK = 64;
      constexpr int PSZ = 128 * 32;     // 4096 shorts
      constexpr int ASZ = 2 * PSZ;      // per buffer: 8192 shorts
      short* As = (short*)SMEM;                 // 2*ASZ = 32KB
      short* Bs = (short*)SMEM + 2 * ASZ;       // 32KB
      const int by = bid / 29, bx = bid - by * 29;
      const int m0 = by * 128, n0 = bx * 128;
      const int srow = lane >> 2;
      const int sc2 = (lane & 3) * 8;
      const short* A = a.hsbf;
      const short* Bm = a.wibf;

      auto stage = [&](int buf, int k0) {
        #pragma unroll
        for (int it2 = 0; it2 < 2; it2++) {
          const int cb = w + 4 * it2;
          const int row = cb * 16 + srow;
          #pragma unroll
          for (int kg = 0; kg < 2; kg++) {
            gl_lds16(A + (long)(m0 + row) * K + k0 + kg * 32 + sc2,
                     As + buf * ASZ + kg * PSZ + cb * 512);
            gl_lds16(Bm + (long)(n0 + row) * K + k0 + kg * 32 + sc2,
                     Bs + buf * ASZ + kg * PSZ + cb * 512);
          }
        }
      };

      float4_t acc[4][4] = {};
      int cur = 0;
      stage(0, 0);
      for (int k0 = 0; k0 < K; k0 += BK) {
        __syncthreads();
        if (k0 + BK < K) stage(cur ^ 1, k0 + BK);
        #pragma unroll
        for (int kg = 0; kg < 2; kg++) {
          const short* Ab = As + cur * ASZ + kg * PSZ;
          const short* Bb = Bs + cur * ASZ + kg * PSZ;
          short8_t af[4], bf[4];
          #pragma unroll
          for (int m = 0; m < 4; m++) af[m] = ldfrag(Ab, wr * 64 + m * 16 + lr, lg);
          #pragma unroll
          for (int n = 0; n < 4; n++) bf[n] = ldfrag(Bb, wc * 64 + n * 16 + lr, lg);
          #pragma unroll
          for (int m = 0; m < 4; m++)
            #pragma unroll
            for (int n = 0; n < 4; n++)
              acc[m][n] = __builtin_amdgcn_mfma_f32_16x16x32_bf16(af[m], bf[n], acc[m][n], 0, 0, 0);
        }
        cur ^= 1;
      }
      #pragma unroll
      for (int m = 0; m < 4; m++)
        #pragma unroll
        for (int n = 0; n < 4; n++)
          #pragma unroll
          for (int r = 0; r < 4; r++) {
            const int row = m0 + wr * 64 + m * 16 + lg * 4 + r;
            const int col = n0 + wc * 64 + n * 16 + lr;
            a.projh[(long)row * P_ + col] = f2bf(acc[m][n][r]);
          }
    } else {
      const int sid = bid - 464;     // 0..47 == B_*NH_
      const int b = sid / NH_;
      const int h = sid % NH_;
      const float bias = a.dtb[h];
      const float Ah = -__expf(a.Alog[h]);
      const long ob = (long)(h * B_ + b) * T_;
      float* scn = (float*)SMEM;
      float carry = 0.f;
      for (int c0 = 0; c0 < T_; c0 += 256) {
        const int t = c0 + tid;
        const long bt = (long)b * T_ + t;
        float sp = softplus_f(a.dtraw[bt * NH_ + h] + bias);
        a.dtT[ob + t] = sp;
        scn[tid] = sp * Ah;
        __syncthreads();
        for (int off = 1; off < 256; off <<= 1) {
          float add = (tid >= off) ? scn[tid - off] : 0.f;
          __syncthreads();
          scn[tid] += add;
          __syncthreads();
        }
        a.cAT[ob + t] = carry + scn[tid];
        a.qT[ob + t] = sp * __expf(scn[tid | 63] - scn[tid]);
        float tot = scn[255];
        __syncthreads();
        carry += tot;
      }
    }
  }
  __threadfence();
  grid.sync();

  // ---------------- phase 2: conv (K=4) + bias + SiLU + fused x-transpose; B/C permuted --------
  {
    float* S = (float*)SMEM;   // [19][256]
    #pragma unroll 1
    for (int u = bid; u < 7 * 64 * B_; u += 512) {
      const int cgi = u % 7;
      const int rest = u / 7;
      const int ty = rest % 64;
      const int b = rest / 64;
      const int c0 = cgi * 256, t0 = ty * 16;
      __syncthreads();   // guard LDS reuse across units/phases
      #pragma unroll
      for (int r = 0; r < 19; r++) {
        const int t = t0 - 3 + r;
        S[r * 256 + tid] = (t >= 0) ? bf2f(a.projh[((long)b * T_ + t) * P_ + INTER_ + c0 + tid]) : 0.f;
      }
      __syncthreads();
      const int c = c0 + tid;
      const float4 cwv = *(const float4*)(a.cw + c * 4);
      const float bias = a.cb[c];
      float acc[16];
      #pragma unroll
      for (int tt = 0; tt < 16; tt++) {
        float v = bias + cwv.w * S[(tt + 3) * 256 + tid] + cwv.z * S[(tt + 2) * 256 + tid]
                       + cwv.y * S[(tt + 1) * 256 + tid] + cwv.x * S[tt * 256 + tid];
        acc[tt] = v / (1.f + __expf(-v));   // SiLU
      }
      if (c < INTER_) {
        const int h = c >> 6, hd = c & 63;
        const long chb = (long)(h * B_ + b) * T_;
        float qv[16];
        #pragma unroll
        for (int qq = 0; qq < 4; qq++) {
          float4 q4 = *(const float4*)(a.qT + chb + t0 + qq * 4);
          qv[qq*4+0] = q4.x; qv[qq*4+1] = q4.y; qv[qq*4+2] = q4.z; qv[qq*4+3] = q4.w;
        }
        const long base = ((long)(b * NH_ + h) * HD_ + hd) * T_ + (t0 & ~63);
        const int g = (t0 >> 5) & 1, h2 = (t0 >> 4) & 1, sw = hd & 7;
        #pragma unroll
        for (int aa = 0; aa < 4; aa++) {
          short4_t xr, xq;
          #pragma unroll
          for (int r = 0; r < 4; r++) {
            xr[r] = f2bf(acc[aa * 4 + r]);
            xq[r] = f2bf(acc[aa * 4 + r] * qv[aa * 4 + r]);
          }
          const int off = (((g * 4 + aa) ^ sw) * 8) + h2 * 4;
          *(short4_t*)(a.xTr + base + off) = xr;
          *(short4_t*)(a.xTq + base + off) = xq;
        }
      } else {
        const int ch0 = c - INTER_;
        const bool isB = ch0 < NS_;
        const int k = isB ? ch0 : ch0 - NS_;
        const int k32 = k & 31;
        const int Pp = (k & ~31) + 8 * ((k32 >> 2) & 3) + 4 * (k32 >> 4) + (k32 & 3);
        short* dst = isB ? a.Bh : a.Chh;
        #pragma unroll
        for (int tt = 0; tt < 16; tt++) {
          const long bt = (long)b * T_ + t0 + tt;
          dst[bt * NS_ + Pp] = f2bf(acc[tt]);
        }
      }
    }
  }
  __threadfence();
  grid.sync();

  // ---------------- phase 3: CB GEMM (single-phase K=128, lower-tri, swizzled bf16 out) --------
  {
    const int x = bid & 15, y = (bid >> 4) & 15, b = bid >> 8;
    if (x <= y) {
      constexpr int PSZ = 64 * 32;
      short* As = (short*)SMEM;                 // 4*PSZ = 16KB
      short* Bs = (short*)SMEM + 4 * PSZ;       // 16KB
      const short* Chh = a.Chh + (long)b * T_ * NS_;
      const short* Bhp = a.Bh + (long)b * T_ * NS_;
      short* CBhp = a.CBh + (long)b * T_ * T_;
      const int m0 = y * 64, n0 = x * 64;
      const int srow = lane >> 2;
      const int sc3 = (lane & 3) * 8;
      {
        const int row = w * 16 + srow;
        #pragma unroll
        for (int kg = 0; kg < 4; kg++) {
          gl_lds16(Chh + (long)(m0 + row) * NS_ + kg * 32 + sc3, As + kg * PSZ + w * 512);
          gl_lds16(Bhp + (long)(n0 + row) * NS_ + kg * 32 + sc3, Bs + kg * PSZ + w * 512);
        }
      }
      __syncthreads();
      float4_t acc[2][2] = {};
      #pragma unroll
      for (int kg = 0; kg < 4; kg++) {
        const short* Ab = As + kg * PSZ;
        const short* Bb = Bs + kg * PSZ;
        short8_t af[2], bf[2];
        #pragma unroll
        for (int m = 0; m < 2; m++) af[m] = ldfrag(Ab, wr * 32 + m * 16 + lr, lg);
        #pragma unroll
        for (int n = 0; n < 2; n++) bf[n] = ldfrag(Bb, wc * 32 + n * 16 + lr, lg);
        #pragma unroll
        for (int m = 0; m < 2; m++)
          #pragma unroll
          for (int n = 0; n < 2; n++)
            acc[m][n] = __builtin_amdgcn_mfma_f32_16x16x32_bf16(af[m], bf[n], acc[m][n], 0, 0, 0);
      }
      #pragma unroll
      for (int m = 0; m < 2; m++)
        #pragma unroll
        for (int n = 0; n < 2; n++)
          #pragma unroll
          for (int r = 0; r < 4; r++) {
            const int row = m0 + wr * 32 + m * 16 + lg * 4 + r;
            const int sl = wc * 32 + n * 16 + lr;
            const int g = sl >> 5, k32 = sl & 31;
            const int cc = g * 4 + ((k32 >> 2) & 3);
            const int off = ((cc ^ (row & 7)) * 8) + 4 * (k32 >> 4) + (k32 & 3);
            CBhp[(long)row * T_ + n0 + off] = f2bf(acc[m][n][r]);
          }
    }
  }
  __threadfence();
  grid.sync();

  // ---------------- phase 4: MFMA attention (snake-paired units, D*x folded epilogue) ----------
  {
    short* CBl = (short*)SMEM;                               // [2][4096]
    short* Xl  = (short*)SMEM + 8192;                        // [2][4096]
    float (*lamS)[17] = (float (*)[17])((short*)SMEM + 16384);
    #pragma unroll 1
    for (int pass = 0; pass < 2; pass++) {
      const int u = pass ? (1023 - bid) : bid;
      if (u < NH_ * 16 * B_) {
        const int ttrank = u / 48, rem = u - ttrank * 48;
        const int h = rem >> 1, b = rem & 1;
        const int tt = 15 - ttrank;
        const int t0 = tt * 64;
        __syncthreads();   // guard LDS reuse from previous unit/phase
        for (int f = tid; f < 64 * NLVL_; f += 256) {
          int r = f / NLVL_, l = f - r * NLVL_;
          lamS[r][l] = softplus_f(
              bf2f(a.projh[((long)b * T_ + t0 + r) * P_ + INTER_ + CONV_DIM_ + NH_ + h * NLVL_ + l]))
              * a.Lw[h * NLVL_ + l];
        }
        const int tl = w * 16 + lr;
        const int t  = t0 + tl;
        const int orow = w * 16 + lg * 4;
        const long chb = (long)(h * B_ + b) * T_;
        const float catv = a.cAT[chb + t];
        float cao[4];
        #pragma unroll
        for (int r = 0; r < 4; r++) cao[r] = a.cAT[chb + t0 + orow + r];
        const short* xbr = a.xTr + (long)(b * NH_ + h) * HD_ * T_;
        const short* xbq = a.xTq + (long)(b * NH_ + h) * HD_ * T_;
        const short* CBbase = a.CBh + (long)b * T_ * T_ + (long)t0 * T_;
        const int srow2 = w * 16 + (lane >> 3);
        const int sch = (lane & 7) * 8;

        auto stage = [&](int buf, int st) {
          const int s0 = st * 64;
          const short* xsrc = (st == tt) ? xbr : xbq;
          #pragma unroll
          for (int i = 0; i < 2; i++) {
            gl_lds16(CBbase + (long)(srow2 + i * 8) * T_ + s0 + sch,
                     CBl + buf * 4096 + (w * 16 + i * 8) * 64);
            gl_lds16(xsrc + (long)(srow2 + i * 8) * T_ + s0 + sch,
                     Xl + buf * 4096 + (w * 16 + i * 8) * 64);
          }
        };

        float4_t acc[4] = {};
        int cur = 0;
        stage(0, 0);
        for (int st = 0; st <= tt; st++) {
          __syncthreads();
          if (st < tt) stage(cur ^ 1, st + 1);
          const int s0 = st * 64;
          if (st < tt) {
            const float caE = a.cAT[chb + s0 + 63];
            const int lev = 32 - __clz(t0 ^ s0);
            float k1o[4];
            #pragma unroll
            for (int r = 0; r < 4; r++)
              k1o[r] = __expf(cao[r] - caE) * lamS[orow + r][lev];
            float4_t dtile[4] = {};
            __builtin_amdgcn_s_setprio(1);
            #pragma unroll
            for (int kk = 0; kk < 2; kk++) {
              short8_t af = ldfrag64(CBl + cur * 4096, tl, kk, lg);
              #pragma unroll
              for (int n = 0; n < 4; n++) {
                short8_t bfv = ldfrag64(Xl + cur * 4096, n * 16 + lr, kk, lg);
                dtile[n] = __builtin_amdgcn_mfma_f32_16x16x32_bf16(af, bfv, dtile[n], 0, 0, 0);
              }
            }
            __builtin_amdgcn_s_setprio(0);
            #pragma unroll
            for (int n = 0; n < 4; n++)
              #pragma unroll
              for (int r = 0; r < 4; r++)
                acc[n][r] = fmaf(k1o[r], dtile[n][r], acc[n][r]);
          } else {
            #pragma unroll
            for (int kk = 0; kk < 2; kk++) {
              short8_t cb8 = ldfrag64(CBl + cur * 4096, tl, kk, lg);
              short8_t af;
              #pragma unroll
              for (int g = 0; g < 2; g++) {
                const int sb = s0 + kk * 32 + g * 16 + lg * 4;
                float4_t ca4 = *(const float4_t*)(a.cAT + chb + sb);
                float4_t dt4 = *(const float4_t*)(a.dtT + chb + sb);
                #pragma unroll
                for (int aa = 0; aa < 4; aa++) {
                  const int sg = sb + aa;
                  float m = 0.f;
                  if (sg <= t) {
                    const int xo = t ^ sg;
                    const int lev2 = xo ? (32 - __clz(xo)) : 0;
                    m = bf2f(cb8[g * 4 + aa]) * __expf(catv - ca4[aa]) * lamS[tl][lev2] * dt4[aa];
                  }
                  af[g * 4 + aa] = f2bf(m);
                }
              }
              __builtin_amdgcn_s_setprio(1);
              #pragma unroll
              for (int n = 0; n < 4; n++) {
                short8_t bfv = ldfrag64(Xl + cur * 4096, n * 16 + lr, kk, lg);
                acc[n] = __builtin_amdgcn_mfma_f32_16x16x32_bf16(af, bfv, acc[n], 0, 0, 0);
              }
              __builtin_amdgcn_s_setprio(0);
            }
          }
          cur ^= 1;
        }

        // epilogue: y + D*x -> bf16 (x tile still in Xl[cur^1])
        const float Dh = a.Dv[h];
        const short* Xd = Xl + (cur ^ 1) * 4096;
        #pragma unroll
        for (int n = 0; n < 4; n++) {
          #pragma unroll
          for (int r = 0; r < 4; r++) {
            const int trow = t0 + orow + r;
            const int hd = n * 16 + lr;
            const int xoff = hd * 64 + ((((w >> 1) * 4 + lg) ^ (hd & 7)) * 8) + (w & 1) * 4 + r;
            const float xv = bf2f(Xd[xoff]);
            a.ybh[((long)b * T_ + trow) * INTER_ + h * HD_ + hd] = f2bf(acc[n][r] + Dh * xv);
          }
        }
      }
    }
  }
  __threadfence();
  grid.sync();

  // ---------------- phase 5: gate * SiLU + RMSNorm -> bf16 permuted (4 rows/block) -------------
  {
    float* part = (float*)SMEM;
    const int i = tid;
    const int lo = (i >> 2) * 32 + (i & 3) * 4;
    const int hi = lo + 16;
    #pragma unroll 1
    for (int rr = 0; rr < 4; rr++) {
      const long bt = (long)bid * 4 + rr;
      float v[8];
      float ss = 0.f;
      if (i < 192) {
        const short* gp = a.projh + bt * P_;
        const short* yp = a.ybh + bt * INTER_;
        short4_t g0 = *(const short4_t*)(gp + lo);
        short4_t g1 = *(const short4_t*)(gp + hi);
        short4_t y0 = *(const short4_t*)(yp + lo);
        short4_t y1 = *(const short4_t*)(yp + hi);
        float ga[8] = {bf2f(g0[0]), bf2f(g0[1]), bf2f(g0[2]), bf2f(g0[3]),
                       bf2f(g1[0]), bf2f(g1[1]), bf2f(g1[2]), bf2f(g1[3])};
        float ya[8] = {bf2f(y0[0]), bf2f(y0[1]), bf2f(y0[2]), bf2f(y0[3]),
                       bf2f(y1[0]), bf2f(y1[1]), bf2f(y1[2]), bf2f(y1[3])};
        #pragma unroll
        for (int j = 0; j < 8; j++) {
          float val = ya[j] * (ga[j] / (1.f + __expf(-ga[j])));
          v[j] = val;
          ss += val * val;
        }
      }
      #pragma unroll
      for (int sof = 32; sof > 0; sof >>= 1) ss += __shfl_xor(ss, sof);
      __syncthreads();   // guard part[] reuse
      if ((i & 63) == 0 && i < 192) part[i >> 6] = ss;
      __syncthreads();
      if (i < 192) {
        const float tot = part[0] + part[1] + part[2];
        const float r2 = rsqrtf(tot * (1.f / INTER_) + EPS_);
        short8_t o;
        #pragma unroll
        for (int j = 0; j < 8; j++) {
          const int idx = (j < 4) ? (lo + j) : (hi + j - 4);
          o[j] = f2bf(v[j] * r2 * a.nw[idx]);
        }
        *(short8_t*)(a.ynrmb + bt * INTER_ + i * 8) = o;
      }
    }
  }
  __threadfence();
  grid.sync();

  // ---------------- phase 6: out-proj GEMM (64x64, BK=128) -> fp32 out ----------------
  {
    if (bid < 384) {
      constexpr int PSZ = 64 * 32;
      constexpr int BKG = 4;
      constexpr int BUF = PSZ * BKG;    // 8192 shorts per matrix per buffer
      constexpr int N = HID_, K = INTER_;
      short* As = (short*)SMEM;                 // 2*BUF = 32KB
      short* Bs = (short*)SMEM + 2 * BUF;       // 32KB
      const int m0 = (bid / 12) * 64, n0 = (bid % 12) * 64;
      const int srow = lane >> 2;
      const int sc6 = (lane & 3) * 8;
      const short* A = a.ynrmb;
      const short* Bm = a.wobf;

      auto stage = [&](int buf, int k0) {
        const int row = w * 16 + srow;
        #pragma unroll
        for (int kg = 0; kg < BKG; kg++) {
          gl_lds16(A + (long)(m0 + row) * K + k0 + kg * 32 + sc6, As + buf * BUF + kg * PSZ + w * 512);
          gl_lds16(Bm + (long)(n0 + row) * K + k0 + kg * 32 + sc6, Bs + buf * BUF + kg * PSZ + w * 512);
        }
      };

      float4_t acc[2][2] = {};
      int cur = 0;
      stage(0, 0);
      for (int k0 = 0; k0 < K; k0 += 128) {
        __syncthreads();
        if (k0 + 128 < K) stage(cur ^ 1, k0 + 128);
        #pragma unroll
        for (int kg = 0; kg < BKG; kg++) {
          const short* Ab = As + cur * BUF + kg * PSZ;
          const short* Bb = Bs + cur * BUF + kg * PSZ;
          short8_t af[2], bf[2];
          #pragma unroll
          for (int m = 0; m < 2; m++) af[m] = ldfrag(Ab, wr * 32 + m * 16 + lr, lg);
          #pragma unroll
          for (int n = 0; n < 2; n++) bf[n] = ldfrag(Bb, wc * 32 + n * 16 + lr, lg);
          #pragma unroll
          for (int m = 0; m < 2; m++)
            #pragma unroll
            for (int n = 0; n < 2; n++)
              acc[m][n] = __builtin_amdgcn_mfma_f32_16x16x32_bf16(af[m], bf[n], acc[m][n], 0, 0, 0);
        }
        cur ^= 1;
      }
      #pragma unroll
      for (int m = 0; m < 2; m++)
        #pragma unroll
        for (int n = 0; n < 2; n++)
          #pragma unroll
          for (int r = 0; r < 4; r++) {
            const int row = m0 + wr * 32 + m * 16 + lg * 4 + r;
            const int col = n0 + wc * 32 + n * 16 + lr;
            a.out[(long)row * N + col] = acc[m][n][r];
          }
    }
  }
}

// =====================================================================================
// FALLBACK: original 7-kernel pipeline (used if cooperative launch is rejected)
// =====================================================================================

__global__ __launch_bounds__(256) void cvtdt_k(
    const float* __restrict__ hs, const float* __restrict__ Win, const float* __restrict__ Wout,
    short* __restrict__ hsbf, short* __restrict__ wibf, short* __restrict__ wobf,
    float* __restrict__ dtraw, int ncvt)
{
  const long na = (long)B_ * T_ * HID_, nb = (long)P_ * HID_, nc = (long)HID_ * INTER_;
  if ((int)blockIdx.x < ncvt) {
    const long i = ((long)blockIdx.x * 256 + threadIdx.x) * 8;
    const float* src; short* dst; long off;
    if (i < na)           { src = hs;   dst = hsbf; off = i; }
    else if (i < na + nb) { src = Win;  dst = wibf; off = i - na; }
    else if (i < na + nb + nc) { src = Wout; dst = wobf; off = i - na - nb; }
    else return;
    const long base = (off & ~31L) + ((off >> 3) & 3) * 4;
    float4 v0 = *(const float4*)(src + base);
    float4 v1 = *(const float4*)(src + base + 16);
    short8_t o;
    o[0] = f2bf(v0.x); o[1] = f2bf(v0.y); o[2] = f2bf(v0.z); o[3] = f2bf(v0.w);
    o[4] = f2bf(v1.x); o[5] = f2bf(v1.y); o[6] = f2bf(v1.z); o[7] = f2bf(v1.w);
    *(short8_t*)(dst + off) = o;
  } else {
    const int rowbt = ((int)blockIdx.x - ncvt) * 4 + (threadIdx.x >> 6);
    const int lane = threadIdx.x & 63;
    float hv[12];
    const float* hrow = hs + (long)rowbt * HID_ + lane * 12;
    #pragma unroll
    for (int j = 0; j < 12; j++) hv[j] = hrow[j];
    const float* wbase = Win + (long)(INTER_ + CONV_DIM_) * HID_ + lane * 12;
    for (int h = 0; h < NH_; h++) {
      const float* wr = wbase + (long)h * HID_;
      float s = 0.f;
      #pragma unroll
      for (int j = 0; j < 12; j++) s = fmaf(hv[j], wr[j], s);
      #pragma unroll
      for (int off = 32; off; off >>= 1) s += __shfl_xor(s, off);
      if (lane == 0) dtraw[(long)rowbt * NH_ + h] = s;
    }
  }
}

__global__ __launch_bounds__(256) void inproj_scan_k(
    const short* __restrict__ A, const short* __restrict__ B, short* __restrict__ C,
    const float* __restrict__ dtraw, const float* __restrict__ dt_bias,
    const float* __restrict__ A_log, float* __restrict__ dtT, float* __restrict__ cAT,
    float* __restrict__ qT)
{
  constexpr int TM = 128, TN = 128, K = HID_, BK = 64;
  constexpr int PSZ = TM * 32;
  constexpr int ASZ = 2 * PSZ;
  __shared__ short As[2 * ASZ];
  __shared__ short Bs[2 * ASZ];

  if (blockIdx.y >= 16) {
    const int sid = ((int)blockIdx.y - 16) * 29 + (int)blockIdx.x;
    if (sid >= B_ * NH_) return;
    const int b = sid / NH_;
    const int h = sid % NH_;
    const float bias = dt_bias[h];
    const float Ah = -__expf(A_log[h]);
    const long ob = (long)(h * B_ + b) * T_;
    float* sc = (float*)As;
    float carry = 0.f;
    for (int c0 = 0; c0 < T_; c0 += 256) {
      const int t = c0 + threadIdx.x;
      const long bt = (long)b * T_ + t;
      float sp = softplus_f(dtraw[bt * NH_ + h] + bias);
      dtT[ob + t] = sp;
      sc[threadIdx.x] = sp * Ah;
      __syncthreads();
      for (int off = 1; off < 256; off <<= 1) {
        float add = (threadIdx.x >= off) ? sc[threadIdx.x - off] : 0.f;
        __syncthreads();
        sc[threadIdx.x] += add;
        __syncthreads();
      }
      cAT[ob + t] = carry + sc[threadIdx.x];
      qT[ob + t] = sp * __expf(sc[threadIdx.x | 63] - sc[threadIdx.x]);
      float tot = sc[255];
      __syncthreads();
      carry += tot;
    }
    return;
  }

  const int tid = threadIdx.x;
  const int w = tid >> 6, lane = tid & 63;
  const int lr = lane & 15, lg = lane >> 4;
  const int wr = w >> 1, wc = w & 1;
  const int m0 = blockIdx.y * TM, n0 = blockIdx.x * TN;
  const int srow = lane >> 2;
  const int sc2 = (lane & 3) * 8;

  auto stage = [&](int buf, int k0) {
    #pragma unroll
    for (int it = 0; it < 2; it++) {
      const int cb = w + 4 * it;
      const int row = cb * 16 + srow;
      #pragma unroll
      for (int kg = 0; kg < 2; kg++) {
        gl_lds16(A + (long)(m0 + row) * K + k0 + kg * 32 + sc2,
                 As + buf * ASZ + kg * PSZ + cb * 512);
        gl_lds16(B + (long)(n0 + row) * K + k0 + kg * 32 + sc2,
                 Bs + buf * ASZ + kg * PSZ + cb * 512);
      }
    }
  };

  float4_t acc[4][4] = {};
  int cur = 0;
  stage(0, 0);
  for (int k0 = 0; k0 < K; k0 += BK) {
    __syncthreads();
    if (k0 + BK < K) stage(cur ^ 1, k0 + BK);
    #pragma unroll
    for (int kg = 0; kg < 2; kg++) {
      const short* Ab = As + cur * ASZ + kg * PSZ;
      const short* Bb = Bs + cur * ASZ + kg * PSZ;
      short8_t af[4], bf[4];
      #pragma unroll
      for (int m = 0; m < 4; m++) af[m] = ldfrag(Ab, wr * 64 + m * 16 + lr, lg);
      #pragma unroll
      for (int n = 0; n < 4; n++) bf[n] = ldfrag(Bb, wc * 64 + n * 16 + lr, lg);
      #pragma unroll
      for (int m = 0; m < 4; m++)
        #pragma unroll
        for (int n = 0; n < 4; n++)
          acc[m][n] = __builtin_amdgcn_mfma_f32_16x16x32_bf16(af[m], bf[n], acc[m][n], 0, 0, 0);
    }
    cur ^= 1;
  }

  #pragma unroll
  for (int m = 0; m < 4; m++)
    #pragma unroll
    for (int n = 0; n < 4; n++)
      #pragma unroll
      for (int r = 0; r < 4; r++) {
        const int row = m0 + wr * 64 + m * 16 + lg * 4 + r;
        const int col = n0 + wc * 64 + n * 16 + lr;
        C[(long)row * P_ + col] = f2bf(acc[m][n][r]);
      }
}

__global__ __launch_bounds__(256) void gemm_out_k(
    const short* __restrict__ A, const short* __restrict__ B, float* __restrict__ C,
    int M, int N, int K)
{
  constexpr int PSZ = 64 * 32;
  constexpr int BKG = 4;
  constexpr int BUF = PSZ * BKG;
  __shared__ short As[2 * BUF];
  __shared__ short Bs[2 * BUF];
  const int tid = threadIdx.x;
  const int w = tid >> 6, lane = tid & 63;
  const int lr = lane & 15, lg = lane >> 4;
  const int wr = w >> 1, wc = w & 1;
  const int m0 = blockIdx.y * 64, n0 = blockIdx.x * 64;
  const int srow = lane >> 2;
  const int sc = (lane & 3) * 8;

  auto stage = [&](int buf, int k0) {
    const int row = w * 16 + srow;
    #pragma unroll
    for (int kg = 0; kg < BKG; kg++) {
      gl_lds16(A + (long)(m0 + row) * K + k0 + kg * 32 + sc, As + buf * BUF + kg * PSZ + w * 512);
      gl_lds16(B + (long)(n0 + row) * K + k0 + kg * 32 + sc, Bs + buf * BUF + kg * PSZ + w * 512);
    }
  };

  float4_t acc[2][2] = {};
  int cur = 0;
  stage(0, 0);
  for (int k0 = 0; k0 < K; k0 += 128) {
    __syncthreads();
    if (k0 + 128 < K) stage(cur ^ 1, k0 + 128);
    #pragma unroll
    for (int kg = 0; kg < BKG; kg++) {
      const short* Ab = As + cur * BUF + kg * PSZ;
      const short* Bb = Bs + cur * BUF + kg * PSZ;
      short8_t af[2], bf[2];
      #pragma unroll
      for (int m = 0; m < 2; m++) af[m] = ldfrag(Ab, wr * 32 + m * 16 + lr, lg);
      #pragma unroll
      for (int n = 0; n < 2; n++) bf[n] = ldfrag(Bb, wc * 32 + n * 16 + lr, lg);
      #pragma unroll
      for (int m = 0; m < 2; m++)
        #pragma unroll
        for (int n = 0; n < 2; n++)
          acc[m][n] = __builtin_amdgcn_mfma_f32_16x16x32_bf16(af[m], bf[n], acc[m][n], 0, 0, 0);
    }
    cur ^= 1;
  }

  #pragma unroll
  for (int m = 0; m < 2; m++)
    #pragma unroll
    for (int n = 0; n < 2; n++)
      #pragma unroll
      for (int r = 0; r < 4; r++) {
        const int row = m0 + wr * 32 + m * 16 + lg * 4 + r;
        const int col = n0 + wc * 32 + n * 16 + lr;
        C[(long)row * N + col] = acc[m][n][r];
      }
}

__global__ __launch_bounds__(256) void gemm_cbh_k(
    const short* __restrict__ Chh, const short* __restrict__ Bh, short* __restrict__ CBh)
{
  if (blockIdx.x > blockIdx.y) return;
  Chh += (long)blockIdx.z * T_ * NS_;
  Bh  += (long)blockIdx.z * T_ * NS_;
  CBh += (long)blockIdx.z * T_ * T_;
  constexpr int PSZ = 64 * 32;
  __shared__ short As[4 * PSZ];
  __shared__ short Bs[4 * PSZ];
  const int tid = threadIdx.x;
  const int w = tid >> 6, lane = tid & 63;
  const int lr = lane & 15, lg = lane >> 4;
  const int wr = w >> 1, wc = w & 1;
  const int m0 = blockIdx.y * 64, n0 = blockIdx.x * 64;
  const int srow = lane >> 2;
  const int sc = (lane & 3) * 8;

  {
    const int row = w * 16 + srow;
    #pragma unroll
    for (int kg = 0; kg < 4; kg++) {
      gl_lds16(Chh + (long)(m0 + row) * NS_ + kg * 32 + sc, As + kg * PSZ + w * 512);
      gl_lds16(Bh  + (long)(n0 + row) * NS_ + kg * 32 + sc, Bs + kg * PSZ + w * 512);
    }
  }
  __syncthreads();

  float4_t acc[2][2] = {};
  #pragma unroll
  for (int kg = 0; kg < 4; kg++) {
    const short* Ab = As + kg * PSZ;
    const short* Bb = Bs + kg * PSZ;
    short8_t af[2], bf[2];
    #pragma unroll
    for (int m = 0; m < 2; m++) af[m] = ldfrag(Ab, wr * 32 + m * 16 + lr, lg);
    #pragma unroll
    for (int n = 0; n < 2; n++) bf[n] = ldfrag(Bb, wc * 32 + n * 16 + lr, lg);
    #pragma unroll
    for (int m = 0; m < 2; m++)
      #pragma unroll
      for (int n = 0; n < 2; n++)
        acc[m][n] = __builtin_amdgcn_mfma_f32_16x16x32_bf16(af[m], bf[n], acc[m][n], 0, 0, 0);
  }

  #pragma unroll
  for (int m = 0; m < 2; m++)
    #pragma unroll
    for (int n = 0; n < 2; n++)
      #pragma unroll
      for (int r = 0; r < 4; r++) {
        const int row = m0 + wr * 32 + m * 16 + lg * 4 + r;
        const int sl = wc * 32 + n * 16 + lr;
        const int g = sl >> 5, k32 = sl & 31;
        const int cc = g * 4 + ((k32 >> 2) & 3);
        const int off = ((cc ^ (row & 7)) * 8) + 4 * (k32 >> 4) + (k32 & 3);
        CBh[(long)row * T_ + n0 + off] = f2bf(acc[m][n][r]);
      }
}

__global__ __launch_bounds__(256) void conv_silu_k(
    const short* __restrict__ projh, const float* __restrict__ cw, const float* __restrict__ cbias,
    const float* __restrict__ qT,
    short* __restrict__ xTr, short* __restrict__ xTq,
    short* __restrict__ Bh, short* __restrict__ Chh)
{
  const int c0 = blockIdx.x * 256;
  const int t0 = blockIdx.y * 16;
  const int b  = blockIdx.z;
  const int tid = threadIdx.x;
  __shared__ float S[19][256];
  #pragma unroll
  for (int r = 0; r < 19; r++) {
    const int t = t0 - 3 + r;
    S[r][tid] = (t >= 0) ? bf2f(projh[((long)b * T_ + t) * P_ + INTER_ + c0 + tid]) : 0.f;
  }
  __syncthreads();
  const int c = c0 + tid;
  const float4 w = *(const float4*)(cw + c * 4);
  const float bias = cbias[c];
  float acc[16];
  #pragma unroll
  for (int tt = 0; tt < 16; tt++) {
    float a = bias + w.w * S[tt + 3][tid] + w.z * S[tt + 2][tid]
                   + w.y * S[tt + 1][tid] + w.x * S[tt][tid];
    acc[tt] = a / (1.f + __expf(-a));
  }
  if (c < INTER_) {
    const int h = c >> 6, hd = c & 63;
    const long chb = (long)(h * B_ + b) * T_;
    float qv[16];
    #pragma unroll
    for (int qq = 0; qq < 4; qq++) {
      float4 q4 = *(const float4*)(qT + chb + t0 + qq * 4);
      qv[qq*4+0] = q4.x; qv[qq*4+1] = q4.y; qv[qq*4+2] = q4.z; qv[qq*4+3] = q4.w;
    }
    const long base = ((long)(b * NH_ + h) * HD_ + hd) * T_ + (t0 & ~63);
    const int g = (t0 >> 5) & 1, h2 = (t0 >> 4) & 1, sw = hd & 7;
    #pragma unroll
    for (int a = 0; a < 4; a++) {
      short4_t xr, xq;
      #pragma unroll
      for (int r = 0; r < 4; r++) {
        xr[r] = f2bf(acc[a * 4 + r]);
        xq[r] = f2bf(acc[a * 4 + r] * qv[a * 4 + r]);
      }
      const int off = (((g * 4 + a) ^ sw) * 8) + h2 * 4;
      *(short4_t*)(xTr + base + off) = xr;
      *(short4_t*)(xTq + base + off) = xq;
    }
  } else {
    const int ch0 = c - INTER_;
    const bool isB = ch0 < NS_;
    const int k = isB ? ch0 : ch0 - NS_;
    const int k32 = k & 31;
    const int P = (k & ~31) + 8 * ((k32 >> 2) & 3) + 4 * (k32 >> 4) + (k32 & 3);
    short* dst = isB ? Bh : Chh;
    #pragma unroll
    for (int tt = 0; tt < 16; tt++) {
      const long bt = (long)b * T_ + t0 + tt;
      dst[bt * NS_ + P] = f2bf(acc[tt]);
    }
  }
}

__global__ __launch_bounds__(256) void attn_mfma3_k(
    const short* __restrict__ xTr, const short* __restrict__ xTq,
    const short* __restrict__ CBh,
    const float* __restrict__ cAT, const float* __restrict__ dtT,
    const short* __restrict__ projh, const float* __restrict__ Lw,
    const float* __restrict__ Dv,
    short* __restrict__ ybh)
{
  const int h = blockIdx.x;
  const int tt = (T_ / 64 - 1) - blockIdx.y;
  const int b = blockIdx.z;
  const int t0 = tt * 64;
  const int tid = threadIdx.x;
  const int w = tid >> 6, lane = tid & 63;
  const int lr = lane & 15, lg = lane >> 4;

  __shared__ short CBl[2][64 * 64];
  __shared__ short Xl[2][64 * 64];
  __shared__ float lamS[64][17];

  for (int f = tid; f < 64 * NLVL_; f += 256) {
    int r = f / NLVL_, l = f - r * NLVL_;
    lamS[r][l] = softplus_f(
        bf2f(projh[((long)b * T_ + t0 + r) * P_ + INTER_ + CONV_DIM_ + NH_ + h * NLVL_ + l]))
        * Lw[h * NLVL_ + l];
  }

  const int tl = w * 16 + lr;
  const int t  = t0 + tl;
  const int orow = w * 16 + lg * 4;
  const long chb = (long)(h * B_ + b) * T_;
  const float catv = cAT[chb + t];
  float cao[4];
  #pragma unroll
  for (int r = 0; r < 4; r++) cao[r] = cAT[chb + t0 + orow + r];

  const short* xbr = xTr + (long)(b * NH_ + h) * HD_ * T_;
  const short* xbq = xTq + (long)(b * NH_ + h) * HD_ * T_;
  const short* CBbase = CBh + (long)b * T_ * T_ + (long)t0 * T_;

  const int srow = w * 16 + (lane >> 3);
  const int sch = (lane & 7) * 8;

  auto stage = [&](int buf, int st) {
    const int s0 = st * 64;
    const short* xsrc = (st == tt) ? xbr : xbq;
    #pragma unroll
    for (int i = 0; i < 2; i++) {
      gl_lds16(CBbase + (long)(srow + i * 8) * T_ + s0 + sch, &CBl[buf][(w * 16 + i * 8) * 64]);
      gl_lds16(xsrc + (long)(srow + i * 8) * T_ + s0 + sch, &Xl[buf][(w * 16 + i * 8) * 64]);
    }
  };

  float4_t acc[4] = {};
  int cur = 0;
  stage(0, 0);
  for (int st = 0; st <= tt; st++) {
    __syncthreads();
    if (st < tt) stage(cur ^ 1, st + 1);
    const int s0 = st * 64;
    if (st < tt) {
      const float caE = cAT[chb + s0 + 63];
      const int lev = 32 - __clz(t0 ^ s0);
      float k1o[4];
      #pragma unroll
      for (int r = 0; r < 4; r++)
        k1o[r] = __expf(cao[r] - caE) * lamS[orow + r][lev];
      float4_t dtile[4] = {};
      __builtin_amdgcn_s_setprio(1);
      #pragma unroll
      for (int kk = 0; kk < 2; kk++) {
        short8_t af = ldfrag64(CBl[cur], tl, kk, lg);
        #pragma unroll
        for (int n = 0; n < 4; n++) {
          short8_t bfv = ldfrag64(Xl[cur], n * 16 + lr, kk, lg);
          dtile[n] = __builtin_amdgcn_mfma_f32_16x16x32_bf16(af, bfv, dtile[n], 0, 0, 0);
        }
      }
      __builtin_amdgcn_s_setprio(0);
      #pragma unroll
      for (int n = 0; n < 4; n++)
        #pragma unroll
        for (int r = 0; r < 4; r++)
          acc[n][r] = fmaf(k1o[r], dtile[n][r], acc[n][r]);
    } else {
      #pragma unroll
      for (int kk = 0; kk < 2; kk++) {
        short8_t cb8 = ldfrag64(CBl[cur], tl, kk, lg);
        short8_t af;
        #pragma unroll
        for (int g = 0; g < 2; g++) {
          const int sb = s0 + kk * 32 + g * 16 + lg * 4;
          float4_t ca4 = *(const float4_t*)(cAT + chb + sb);
          float4_t dt4 = *(const float4_t*)(dtT + chb + sb);
          #pragma unroll
          for (int a = 0; a < 4; a++) {
            const int sg = sb + a;
            float m = 0.f;
            if (sg <= t) {
              const int xo = t ^ sg;
              const int lev2 = xo ? (32 - __clz(xo)) : 0;
              m = bf2f(cb8[g * 4 + a]) * __expf(catv - ca4[a]) * lamS[tl][lev2] * dt4[a];
            }
            af[g * 4 + a] = f2bf(m);
          }
        }
        __builtin_amdgcn_s_setprio(1);
        #pragma unroll
        for (int n = 0; n < 4; n++) {
          short8_t bfv = ldfrag64(Xl[cur], n * 16 + lr, kk, lg);
          acc[n] = __builtin_amdgcn_mfma_f32_16x16x32_bf16(af, bfv, acc[n], 0, 0, 0);
        }
        __builtin_amdgcn_s_setprio(0);
      }
    }
    cur ^= 1;
  }

  const float Dh = Dv[h];
  const short* Xd = Xl[cur ^ 1];
  #pragma unroll
  for (int n = 0; n < 4; n++) {
    #pragma unroll
    for (int r = 0; r < 4; r++) {
      const int trow = t0 + orow + r;
      const int hd = n * 16 + lr;
      const int xoff = hd * 64 + ((((w >> 1) * 4 + lg) ^ (hd & 7)) * 8) + (w & 1) * 4 + r;
      const float xv = bf2f(Xd[xoff]);
      ybh[((long)b * T_ + trow) * INTER_ + h * HD_ + hd] = f2bf(acc[n][r] + Dh * xv);
    }
  }
}

__global__ __launch_bounds__(192) void gate_rms_k(
    const short* __restrict__ ybh, const short* __restrict__ projh,
    const float* __restrict__ nw, short* __restrict__ ynorm)
{
  const long bt = blockIdx.x;
  const short* gp = projh + bt * P_;
  const short* yp = ybh + bt * INTER_;
  const int i = threadIdx.x;
  const int lo = (i >> 2) * 32 + (i & 3) * 4;
  const int hi = lo + 16;
  float v[8];
  float ss = 0.f;
  {
    short4_t g0 = *(const short4_t*)(gp + lo);
    short4_t g1 = *(const short4_t*)(gp + hi);
    short4_t y0 = *(const short4_t*)(yp + lo);
    short4_t y1 = *(const short4_t*)(yp + hi);
    float ga[8] = {bf2f(g0[0]), bf2f(g0[1]), bf2f(g0[2]), bf2f(g0[3]),
                   bf2f(g1[0]), bf2f(g1[1]), bf2f(g1[2]), bf2f(g1[3])};
    float ya[8] = {bf2f(y0[0]), bf2f(y0[1]), bf2f(y0[2]), bf2f(y0[3]),
                   bf2f(y1[0]), bf2f(y1[1]), bf2f(y1[2]), bf2f(y1[3])};
    #pragma unroll
    for (int j = 0; j < 8; j++) {
      float val = ya[j] * (ga[j] / (1.f + __expf(-ga[j])));
      v[j] = val;
      ss += val * val;
    }
  }
  #pragma unroll
  for (int off = 32; off > 0; off >>= 1) ss += __shfl_xor(ss, off);
  __shared__ float part[3];
  if ((i & 63) == 0) part[i >> 6] = ss;
  __syncthreads();
  const float tot = part[0] + part[1] + part[2];
  const float r = rsqrtf(tot * (1.f / INTER_) + EPS_);
  short8_t o;
  #pragma unroll
  for (int j = 0; j < 8; j++) {
    const int idx = (j < 4) ? (lo + j) : (hi + j - 4);
    o[j] = f2bf(v[j] * r * nw[idx]);
  }
  *(short8_t*)(ynorm + bt * INTER_ + i * 8) = o;
}

extern "C" void kernel_launch(void* const* d_in, const int* in_sizes, int n_in,
                              void* d_out, int out_size, void* d_ws, size_t ws_size,
                              hipStream_t stream) {
  const float* hs   = (const float*)d_in[0];
  const float* Win  = (const float*)d_in[1];
  const float* cw   = (const float*)d_in[2];
  const float* cb   = (const float*)d_in[3];
  const float* dtb  = (const float*)d_in[4];
  const float* Alog = (const float*)d_in[5];
  const float* Lw   = (const float*)d_in[6];
  const float* Dv   = (const float*)d_in[7];
  const float* nw   = (const float*)d_in[8];
  const float* Wout = (const float*)d_in[9];
  float* out = (float*)d_out;

  const long n_hs = (long)B_ * T_ * HID_;
  const long n_wi = (long)P_ * HID_;
  const long n_wo = (long)HID_ * INTER_;

  float* ws = (float*)d_ws;
  long o = 0;
  float* projreg = ws + o; o += (long)B_ * T_ * P_ / 2 + 16;
  short* xbf   = (short*)(ws + o); o += (long)B_ * T_ * INTER_ / 2;  // (slot retained, unused)
  short* Bh    = (short*)(ws + o); o += (long)B_ * T_ * NS_ / 2;
  short* Chh   = (short*)(ws + o); o += (long)B_ * T_ * NS_ / 2;
  float* dtT   = ws + o; o += (long)B_ * T_ * NH_;
  float* cAT   = ws + o; o += (long)B_ * T_ * NH_;
  float* qT    = ws + o; o += (long)B_ * T_ * NH_;
  float* dtraw = ws + o; o += (long)B_ * T_ * NH_;
  short* CBh   = (short*)(ws + o); o += (long)B_ * T_ * T_ / 2;
  short* ybh   = (short*)(ws + o); o += (long)B_ * T_ * INTER_ / 2;
  float* yxreg = ws + o; o += (long)B_ * T_ * INTER_ / 2;
  short* hsbf  = (short*)(ws + o); o += n_hs / 2;
  short* wibf  = (short*)(ws + o); o += n_wi / 2;
  short* wobf  = (short*)(ws + o); o += n_wo / 2;
  short* projh = (short*)projreg;
  short* xTr   = (short*)yxreg;
  short* ynrmb = (short*)yxreg;
  short* xTq   = hsbf;
  (void)xbf;

  // ---- preferred path: single cooperative mega-kernel (512 blocks = 2/CU @ 64KB LDS) ----
  MegaArgs ma;
  ma.hs = hs; ma.Win = Win; ma.cw = cw; ma.cb = cb; ma.dtb = dtb; ma.Alog = Alog;
  ma.Lw = Lw; ma.Dv = Dv; ma.nw = nw; ma.Wout = Wout; ma.out = out;
  ma.hsbf = hsbf; ma.wibf = wibf; ma.wobf = wobf;
  ma.dtraw = dtraw; ma.dtT = dtT; ma.cAT = cAT; ma.qT = qT;
  ma.projh = projh; ma.xTr = xTr; ma.xTq = xTq; ma.Bh = Bh; ma.Chh = Chh;
  ma.CBh = CBh; ma.ybh = ybh; ma.ynrmb = ynrmb;
  void* kargs[] = { (void*)&ma };
  hipError_t ce = hipLaunchCooperativeKernel(
      (const void*)mega_k, dim3(512), dim3(256), kargs, 0, stream);
  if (ce == hipSuccess) return;

  // ---- fallback: proven 7-kernel pipeline ----
  const int ncvt = (int)((n_hs + n_wi + n_wo) / 8 / 256);
  cvtdt_k<<<ncvt + (B_ * T_) / 4, 256, 0, stream>>>(
      hs, Win, Wout, hsbf, wibf, wobf, dtraw, ncvt);
  inproj_scan_k<<<dim3(P_ / 128, 18), 256, 0, stream>>>(
      hsbf, wibf, projh, dtraw, dtb, Alog, dtT, cAT, qT);
  conv_silu_k<<<dim3(CONV_DIM_ / 256, T_ / 16, B_), 256, 0, stream>>>(
      projh, cw, cb, qT, xTr, xTq, Bh, Chh);
  gemm_cbh_k<<<dim3(T_ / 64, T_ / 64, B_), 256, 0, stream>>>(Chh, Bh, CBh);
  attn_mfma3_k<<<dim3(NH_, T_ / 64, B_), 256, 0, stream>>>(
      xTr, xTq, CBh, cAT, dtT, projh, Lw, Dv, ybh);
  gate_rms_k<<<B_ * T_, 192, 0, stream>>>(ybh, projh, nw, ynrmb);
  gemm_out_k<<<dim3(HID_ / 64, (B_ * T_) / 64), 256, 0, stream>>>(
      ynrmb, wobf, out, B_ * T_, HID_, INTER_);
}

// Round 3
// 585.354 us; speedup vs baseline: 1.3883x; 1.3883x over previous
//
#include <hip/hip_runtime.h>
#include <hip/hip_bf16.h>
#include <math.h>

#define B_ 2
#define T_ 1024
#define HID_ 768
#define INTER_ 1536
#define NH_ 24
#define HD_ 64
#define NS_ 128
#define NLVL_ 15
#define CONV_DIM_ 1792
#define P_ 3712
#define EPS_ 1e-5f

typedef short short8_t __attribute__((ext_vector_type(8)));
typedef short short4_t __attribute__((ext_vector_type(4)));
typedef float float4_t __attribute__((ext_vector_type(4)));

// K-permutation (within each 32-element K-group): physical p = 8a + 4h + r for
// logical k = 16h + 4a + r. A lane's MFMA operand (k = lg*4+{0..3} and +16) is then
// ONE contiguous 16B chunk at p = 8*lg  ->  single ds_read_b128 per fragment.

__device__ __forceinline__ float softplus_f(float x) {
  return (x > 20.f) ? x : log1pf(__expf(x));
}
__device__ __forceinline__ short f2bf(float f) {
  union { float f; unsigned u; } v; v.f = f;
  unsigned r = v.u + 0x7FFF + ((v.u >> 16) & 1);   // RNE
  return (short)(r >> 16);
}
__device__ __forceinline__ float bf2f(short s) {
  union { unsigned u; float f; } v; v.u = ((unsigned)(unsigned short)s) << 16;
  return v.f;
}
__device__ __forceinline__ void gl_lds16(const void* g, void* l) {
  __builtin_amdgcn_global_load_lds(
      (const __attribute__((address_space(1))) unsigned int*)g,
      (__attribute__((address_space(3))) unsigned int*)l, 16, 0, 0);
}

// Lightweight grid barrier: monotonic counter, agent-scope atomics, short-sleep spin.
// Replaces cg::grid_group::sync() (measured ~120us/sync in R2 -> device 97% idle).
// Requires co-residency (hipLaunchCooperativeKernel) and *bar zeroed before launch.
__device__ __forceinline__ void grid_bar(unsigned* bar, unsigned target) {
  __syncthreads();
  if (threadIdx.x == 0) {
    __threadfence();                                  // release: wb this XCD's L2
    __hip_atomic_fetch_add(bar, 1u, __ATOMIC_RELAXED, __HIP_MEMORY_SCOPE_AGENT);
    while (__hip_atomic_load(bar, __ATOMIC_RELAXED, __HIP_MEMORY_SCOPE_AGENT) < target)
      __builtin_amdgcn_s_sleep(8);                    // ~512 cycles per poll
  }
  __syncthreads();
  __threadfence();                                    // acquire: inv stale caches
}

// Permuted LDS fragment read (BK-panel of 32 K): one b128 per fragment.
__device__ __forceinline__ short8_t ldfrag(const short* Ts, int row, int lg) {
  return *(const short8_t*)(Ts + row * 32 + lg * 8);
}

// Permuted+row-swizzled 64-wide fragment read (attn): one b128 per fragment.
__device__ __forceinline__ short8_t ldfrag64(const short* Ts, int row, int kk, int lg) {
  const int cc = (kk * 4 + lg) ^ (row & 7);
  return *(const short8_t*)(Ts + row * 64 + cc * 8);
}

// =====================================================================================
// MEGA KERNEL: whole pipeline, 512 blocks x 256 threads (2 blocks/CU @ 64KB LDS),
// phases separated by custom grid barrier. Eliminates 6 kernel-boundary gaps/drains.
// =====================================================================================
struct MegaArgs {
  const float *hs, *Win, *cw, *cb, *dtb, *Alog, *Lw, *Dv, *nw, *Wout;
  float *out;
  short *hsbf, *wibf, *wobf;
  float *dtraw, *dtT, *cAT, *qT;
  short *projh, *xTr, *xTq, *Bh, *Chh, *CBh, *ybh, *ynrmb;
  unsigned *bar;
};

__global__ __launch_bounds__(256, 2) void mega_k(MegaArgs a)
{
  const int bid = blockIdx.x;
  const int tid = threadIdx.x;
  const int w = tid >> 6, lane = tid & 63;
  const int lr = lane & 15, lg = lane >> 4;
  const int wr = w >> 1, wc = w & 1;
  __shared__ char SMEM[65536] __attribute__((aligned(16)));

  // ---------------- phase 0: f32->bf16 K-permuted cvt (hs/Win/Wout) + fp32 dt columns ----------
  {
    const long na = (long)B_ * T_ * HID_, nb = (long)P_ * HID_, nc = (long)HID_ * INTER_;
    const long tot8 = (na + nb + nc) / 8;
    for (long it = (long)bid * 256 + tid; it < tot8; it += 512L * 256) {
      const long i = it * 8;
      const float* src; short* dst; long off;
      if (i < na)           { src = a.hs;   dst = a.hsbf; off = i; }
      else if (i < na + nb) { src = a.Win;  dst = a.wibf; off = i - na; }
      else                  { src = a.Wout; dst = a.wobf; off = i - na - nb; }
      const long base = (off & ~31L) + ((off >> 3) & 3) * 4;
      float4 v0 = *(const float4*)(src + base);
      float4 v1 = *(const float4*)(src + base + 16);
      short8_t o;
      o[0] = f2bf(v0.x); o[1] = f2bf(v0.y); o[2] = f2bf(v0.z); o[3] = f2bf(v0.w);
      o[4] = f2bf(v1.x); o[5] = f2bf(v1.y); o[6] = f2bf(v1.z); o[7] = f2bf(v1.w);
      *(short8_t*)(dst + off) = o;
    }
    // dt GEMV: one bt-row per wave, 4 per block (512*4 = 2048)
    const int rowbt = bid * 4 + w;
    float hv[12];
    const float* hrow = a.hs + (long)rowbt * HID_ + lane * 12;
    #pragma unroll
    for (int j = 0; j < 12; j++) hv[j] = hrow[j];
    const float* wbase = a.Win + (long)(INTER_ + CONV_DIM_) * HID_ + lane * 12;
    for (int h = 0; h < NH_; h++) {
      const float* wrp = wbase + (long)h * HID_;
      float s = 0.f;
      #pragma unroll
      for (int j = 0; j < 12; j++) s = fmaf(hv[j], wrp[j], s);
      #pragma unroll
      for (int sof = 32; sof; sof >>= 1) s += __shfl_xor(s, sof);
      if (lane == 0) a.dtraw[(long)rowbt * NH_ + h] = s;
    }
  }
  grid_bar(a.bar, 512u * 1);

  // ---------------- phase 1: in-proj GEMM (128x128, BK=64, bf16 out) + dt_scan ----------------
  {
    if (bid < 464) {
      constexpr int K = HID_, BK = 64;
      constexpr int PSZ = 128 * 32;     // 4096 shorts
      constexpr int ASZ = 2 * PSZ;      // per buffer: 8192 shorts
      short* As = (short*)SMEM;                 // 2*ASZ = 32KB
      short* Bs = (short*)SMEM + 2 * ASZ;       // 32KB
      const int by = bid / 29, bx = bid - by * 29;
      const int m0 = by * 128, n0 = bx * 128;
      const int srow = lane >> 2;
      const int sc2 = (lane & 3) * 8;
      const short* A = a.hsbf;
      const short* Bm = a.wibf;

      auto stage = [&](int buf, int k0) {
        #pragma unroll
        for (int it2 = 0; it2 < 2; it2++) {
          const int cb = w + 4 * it2;
          const int row = cb * 16 + srow;
          #pragma unroll
          for (int kg = 0; kg < 2; kg++) {
            gl_lds16(A + (long)(m0 + row) * K + k0 + kg * 32 + sc2,
                     As + buf * ASZ + kg * PSZ + cb * 512);
            gl_lds16(Bm + (long)(n0 + row) * K + k0 + kg * 32 + sc2,
                     Bs + buf * ASZ + kg * PSZ + cb * 512);
          }
        }
      };

      float4_t acc[4][4] = {};
      int cur = 0;
      stage(0, 0);
      for (int k0 = 0; k0 < K; k0 += BK) {
        __syncthreads();
        if (k0 + BK < K) stage(cur ^ 1, k0 + BK);
        #pragma unroll
        for (int kg = 0; kg < 2; kg++) {
          const short* Ab = As + cur * ASZ + kg * PSZ;
          const short* Bb = Bs + cur * ASZ + kg * PSZ;
          short8_t af[4], bf[4];
          #pragma unroll
          for (int m = 0; m < 4; m++) af[m] = ldfrag(Ab, wr * 64 + m * 16 + lr, lg);
          #pragma unroll
          for (int n = 0; n < 4; n++) bf[n] = ldfrag(Bb, wc * 64 + n * 16 + lr, lg);
          #pragma unroll
          for (int m = 0; m < 4; m++)
            #pragma unroll
            for (int n = 0; n < 4; n++)
              acc[m][n] = __builtin_amdgcn_mfma_f32_16x16x32_bf16(af[m], bf[n], acc[m][n], 0, 0, 0);
        }
        cur ^= 1;
      }
      #pragma unroll
      for (int m = 0; m < 4; m++)
        #pragma unroll
        for (int n = 0; n < 4; n++)
          #pragma unroll
          for (int r = 0; r < 4; r++) {
            const int row = m0 + wr * 64 + m * 16 + lg * 4 + r;
            const int col = n0 + wc * 64 + n * 16 + lr;
            a.projh[(long)row * P_ + col] = f2bf(acc[m][n][r]);
          }
    } else {
      const int sid = bid - 464;     // 0..47 == B_*NH_
      const int b = sid / NH_;
      const int h = sid % NH_;
      const float bias = a.dtb[h];
      const float Ah = -__expf(a.Alog[h]);
      const long ob = (long)(h * B_ + b) * T_;
      float* scn = (float*)SMEM;
      float carry = 0.f;
      for (int c0 = 0; c0 < T_; c0 += 256) {
        const int t = c0 + tid;
        const long bt = (long)b * T_ + t;
        float sp = softplus_f(a.dtraw[bt * NH_ + h] + bias);
        a.dtT[ob + t] = sp;
        scn[tid] = sp * Ah;
        __syncthreads();
        for (int off = 1; off < 256; off <<= 1) {
          float add = (tid >= off) ? scn[tid - off] : 0.f;
          __syncthreads();
          scn[tid] += add;
          __syncthreads();
        }
        a.cAT[ob + t] = carry + scn[tid];
        a.qT[ob + t] = sp * __expf(scn[tid | 63] - scn[tid]);
        float tot = scn[255];
        __syncthreads();
        carry += tot;
      }
    }
  }
  grid_bar(a.bar, 512u * 2);

  // ---------------- phase 2: conv (K=4) + bias + SiLU + fused x-transpose; B/C permuted --------
  {
    float* S = (float*)SMEM;   // [19][256]
    #pragma unroll 1
    for (int u = bid; u < 7 * 64 * B_; u += 512) {
      const int cgi = u % 7;
      const int rest = u / 7;
      const int ty = rest % 64;
      const int b = rest / 64;
      const int c0 = cgi * 256, t0 = ty * 16;
      __syncthreads();   // guard LDS reuse across units/phases
      #pragma unroll
      for (int r = 0; r < 19; r++) {
        const int t = t0 - 3 + r;
        S[r * 256 + tid] = (t >= 0) ? bf2f(a.projh[((long)b * T_ + t) * P_ + INTER_ + c0 + tid]) : 0.f;
      }
      __syncthreads();
      const int c = c0 + tid;
      const float4 cwv = *(const float4*)(a.cw + c * 4);
      const float bias = a.cb[c];
      float acc[16];
      #pragma unroll
      for (int tt = 0; tt < 16; tt++) {
        float v = bias + cwv.w * S[(tt + 3) * 256 + tid] + cwv.z * S[(tt + 2) * 256 + tid]
                       + cwv.y * S[(tt + 1) * 256 + tid] + cwv.x * S[tt * 256 + tid];
        acc[tt] = v / (1.f + __expf(-v));   // SiLU
      }
      if (c < INTER_) {
        const int h = c >> 6, hd = c & 63;
        const long chb = (long)(h * B_ + b) * T_;
        float qv[16];
        #pragma unroll
        for (int qq = 0; qq < 4; qq++) {
          float4 q4 = *(const float4*)(a.qT + chb + t0 + qq * 4);
          qv[qq*4+0] = q4.x; qv[qq*4+1] = q4.y; qv[qq*4+2] = q4.z; qv[qq*4+3] = q4.w;
        }
        const long base = ((long)(b * NH_ + h) * HD_ + hd) * T_ + (t0 & ~63);
        const int g = (t0 >> 5) & 1, h2 = (t0 >> 4) & 1, sw = hd & 7;
        #pragma unroll
        for (int aa = 0; aa < 4; aa++) {
          short4_t xr, xq;
          #pragma unroll
          for (int r = 0; r < 4; r++) {
            xr[r] = f2bf(acc[aa * 4 + r]);
            xq[r] = f2bf(acc[aa * 4 + r] * qv[aa * 4 + r]);
          }
          const int off = (((g * 4 + aa) ^ sw) * 8) + h2 * 4;
          *(short4_t*)(a.xTr + base + off) = xr;
          *(short4_t*)(a.xTq + base + off) = xq;
        }
      } else {
        const int ch0 = c - INTER_;
        const bool isB = ch0 < NS_;
        const int k = isB ? ch0 : ch0 - NS_;
        const int k32 = k & 31;
        const int Pp = (k & ~31) + 8 * ((k32 >> 2) & 3) + 4 * (k32 >> 4) + (k32 & 3);
        short* dst = isB ? a.Bh : a.Chh;
        #pragma unroll
        for (int tt = 0; tt < 16; tt++) {
          const long bt = (long)b * T_ + t0 + tt;
          dst[bt * NS_ + Pp] = f2bf(acc[tt]);
        }
      }
    }
  }
  grid_bar(a.bar, 512u * 3);

  // ---------------- phase 3: CB GEMM (single-phase K=128, lower-tri, swizzled bf16 out) --------
  {
    const int x = bid & 15, y = (bid >> 4) & 15, b = bid >> 8;
    if (x <= y) {
      constexpr int PSZ = 64 * 32;
      short* As = (short*)SMEM;                 // 4*PSZ = 16KB
      short* Bs = (short*)SMEM + 4 * PSZ;       // 16KB
      const short* Chh = a.Chh + (long)b * T_ * NS_;
      const short* Bhp = a.Bh + (long)b * T_ * NS_;
      short* CBhp = a.CBh + (long)b * T_ * T_;
      const int m0 = y * 64, n0 = x * 64;
      const int srow = lane >> 2;
      const int sc3 = (lane & 3) * 8;
      {
        const int row = w * 16 + srow;
        #pragma unroll
        for (int kg = 0; kg < 4; kg++) {
          gl_lds16(Chh + (long)(m0 + row) * NS_ + kg * 32 + sc3, As + kg * PSZ + w * 512);
          gl_lds16(Bhp + (long)(n0 + row) * NS_ + kg * 32 + sc3, Bs + kg * PSZ + w * 512);
        }
      }
      __syncthreads();
      float4_t acc[2][2] = {};
      #pragma unroll
      for (int kg = 0; kg < 4; kg++) {
        const short* Ab = As + kg * PSZ;
        const short* Bb = Bs + kg * PSZ;
        short8_t af[2], bf[2];
        #pragma unroll
        for (int m = 0; m < 2; m++) af[m] = ldfrag(Ab, wr * 32 + m * 16 + lr, lg);
        #pragma unroll
        for (int n = 0; n < 2; n++) bf[n] = ldfrag(Bb, wc * 32 + n * 16 + lr, lg);
        #pragma unroll
        for (int m = 0; m < 2; m++)
          #pragma unroll
          for (int n = 0; n < 2; n++)
            acc[m][n] = __builtin_amdgcn_mfma_f32_16x16x32_bf16(af[m], bf[n], acc[m][n], 0, 0, 0);
      }
      #pragma unroll
      for (int m = 0; m < 2; m++)
        #pragma unroll
        for (int n = 0; n < 2; n++)
          #pragma unroll
          for (int r = 0; r < 4; r++) {
            const int row = m0 + wr * 32 + m * 16 + lg * 4 + r;
            const int sl = wc * 32 + n * 16 + lr;
            const int g = sl >> 5, k32 = sl & 31;
            const int cc = g * 4 + ((k32 >> 2) & 3);
            const int off = ((cc ^ (row & 7)) * 8) + 4 * (k32 >> 4) + (k32 & 3);
            CBhp[(long)row * T_ + n0 + off] = f2bf(acc[m][n][r]);
          }
    }
  }
  grid_bar(a.bar, 512u * 4);

  // ---------------- phase 4: MFMA attention (snake-paired units, D*x folded epilogue) ----------
  {
    short* CBl = (short*)SMEM;                               // [2][4096]
    short* Xl  = (short*)SMEM + 8192;                        // [2][4096]
    float (*lamS)[17] = (float (*)[17])((short*)SMEM + 16384);
    #pragma unroll 1
    for (int pass = 0; pass < 2; pass++) {
      const int u = pass ? (1023 - bid) : bid;
      if (u < NH_ * 16 * B_) {
        const int ttrank = u / 48, rem = u - ttrank * 48;
        const int h = rem >> 1, b = rem & 1;
        const int tt = 15 - ttrank;
        const int t0 = tt * 64;
        __syncthreads();   // guard LDS reuse from previous unit/phase
        for (int f = tid; f < 64 * NLVL_; f += 256) {
          int r = f / NLVL_, l = f - r * NLVL_;
          lamS[r][l] = softplus_f(
              bf2f(a.projh[((long)b * T_ + t0 + r) * P_ + INTER_ + CONV_DIM_ + NH_ + h * NLVL_ + l]))
              * a.Lw[h * NLVL_ + l];
        }
        const int tl = w * 16 + lr;
        const int t  = t0 + tl;
        const int orow = w * 16 + lg * 4;
        const long chb = (long)(h * B_ + b) * T_;
        const float catv = a.cAT[chb + t];
        float cao[4];
        #pragma unroll
        for (int r = 0; r < 4; r++) cao[r] = a.cAT[chb + t0 + orow + r];
        const short* xbr = a.xTr + (long)(b * NH_ + h) * HD_ * T_;
        const short* xbq = a.xTq + (long)(b * NH_ + h) * HD_ * T_;
        const short* CBbase = a.CBh + (long)b * T_ * T_ + (long)t0 * T_;
        const int srow2 = w * 16 + (lane >> 3);
        const int sch = (lane & 7) * 8;

        auto stage = [&](int buf, int st) {
          const int s0 = st * 64;
          const short* xsrc = (st == tt) ? xbr : xbq;
          #pragma unroll
          for (int i = 0; i < 2; i++) {
            gl_lds16(CBbase + (long)(srow2 + i * 8) * T_ + s0 + sch,
                     CBl + buf * 4096 + (w * 16 + i * 8) * 64);
            gl_lds16(xsrc + (long)(srow2 + i * 8) * T_ + s0 + sch,
                     Xl + buf * 4096 + (w * 16 + i * 8) * 64);
          }
        };

        float4_t acc[4] = {};
        int cur = 0;
        stage(0, 0);
        for (int st = 0; st <= tt; st++) {
          __syncthreads();
          if (st < tt) stage(cur ^ 1, st + 1);
          const int s0 = st * 64;
          if (st < tt) {
            const float caE = a.cAT[chb + s0 + 63];
            const int lev = 32 - __clz(t0 ^ s0);
            float k1o[4];
            #pragma unroll
            for (int r = 0; r < 4; r++)
              k1o[r] = __expf(cao[r] - caE) * lamS[orow + r][lev];
            float4_t dtile[4] = {};
            __builtin_amdgcn_s_setprio(1);
            #pragma unroll
            for (int kk = 0; kk < 2; kk++) {
              short8_t af = ldfrag64(CBl + cur * 4096, tl, kk, lg);
              #pragma unroll
              for (int n = 0; n < 4; n++) {
                short8_t bfv = ldfrag64(Xl + cur * 4096, n * 16 + lr, kk, lg);
                dtile[n] = __builtin_amdgcn_mfma_f32_16x16x32_bf16(af, bfv, dtile[n], 0, 0, 0);
              }
            }
            __builtin_amdgcn_s_setprio(0);
            #pragma unroll
            for (int n = 0; n < 4; n++)
              #pragma unroll
              for (int r = 0; r < 4; r++)
                acc[n][r] = fmaf(k1o[r], dtile[n][r], acc[n][r]);
          } else {
            #pragma unroll
            for (int kk = 0; kk < 2; kk++) {
              short8_t cb8 = ldfrag64(CBl + cur * 4096, tl, kk, lg);
              short8_t af;
              #pragma unroll
              for (int g = 0; g < 2; g++) {
                const int sb = s0 + kk * 32 + g * 16 + lg * 4;
                float4_t ca4 = *(const float4_t*)(a.cAT + chb + sb);
                float4_t dt4 = *(const float4_t*)(a.dtT + chb + sb);
                #pragma unroll
                for (int aa = 0; aa < 4; aa++) {
                  const int sg = sb + aa;
                  float m = 0.f;
                  if (sg <= t) {
                    const int xo = t ^ sg;
                    const int lev2 = xo ? (32 - __clz(xo)) : 0;
                    m = bf2f(cb8[g * 4 + aa]) * __expf(catv - ca4[aa]) * lamS[tl][lev2] * dt4[aa];
                  }
                  af[g * 4 + aa] = f2bf(m);
                }
              }
              __builtin_amdgcn_s_setprio(1);
              #pragma unroll
              for (int n = 0; n < 4; n++) {
                short8_t bfv = ldfrag64(Xl + cur * 4096, n * 16 + lr, kk, lg);
                acc[n] = __builtin_amdgcn_mfma_f32_16x16x32_bf16(af, bfv, acc[n], 0, 0, 0);
              }
              __builtin_amdgcn_s_setprio(0);
            }
          }
          cur ^= 1;
        }

        // epilogue: y + D*x -> bf16 (x tile still in Xl[cur^1])
        const float Dh = a.Dv[h];
        const short* Xd = Xl + (cur ^ 1) * 4096;
        #pragma unroll
        for (int n = 0; n < 4; n++) {
          #pragma unroll
          for (int r = 0; r < 4; r++) {
            const int trow = t0 + orow + r;
            const int hd = n * 16 + lr;
            const int xoff = hd * 64 + ((((w >> 1) * 4 + lg) ^ (hd & 7)) * 8) + (w & 1) * 4 + r;
            const float xv = bf2f(Xd[xoff]);
            a.ybh[((long)b * T_ + trow) * INTER_ + h * HD_ + hd] = f2bf(acc[n][r] + Dh * xv);
          }
        }
      }
    }
  }
  grid_bar(a.bar, 512u * 5);

  // ---------------- phase 5: gate * SiLU + RMSNorm -> bf16 permuted (4 rows/block) -------------
  {
    float* part = (float*)SMEM;
    const int i = tid;
    const int lo = (i >> 2) * 32 + (i & 3) * 4;
    const int hi = lo + 16;
    #pragma unroll 1
    for (int rr = 0; rr < 4; rr++) {
      const long bt = (long)bid * 4 + rr;
      float v[8];
      float ss = 0.f;
      if (i < 192) {
        const short* gp = a.projh + bt * P_;
        const short* yp = a.ybh + bt * INTER_;
        short4_t g0 = *(const short4_t*)(gp + lo);
        short4_t g1 = *(const short4_t*)(gp + hi);
        short4_t y0 = *(const short4_t*)(yp + lo);
        short4_t y1 = *(const short4_t*)(yp + hi);
        float ga[8] = {bf2f(g0[0]), bf2f(g0[1]), bf2f(g0[2]), bf2f(g0[3]),
                       bf2f(g1[0]), bf2f(g1[1]), bf2f(g1[2]), bf2f(g1[3])};
        float ya[8] = {bf2f(y0[0]), bf2f(y0[1]), bf2f(y0[2]), bf2f(y0[3]),
                       bf2f(y1[0]), bf2f(y1[1]), bf2f(y1[2]), bf2f(y1[3])};
        #pragma unroll
        for (int j = 0; j < 8; j++) {
          float val = ya[j] * (ga[j] / (1.f + __expf(-ga[j])));
          v[j] = val;
          ss += val * val;
        }
      }
      #pragma unroll
      for (int sof = 32; sof > 0; sof >>= 1) ss += __shfl_xor(ss, sof);
      __syncthreads();   // guard part[] reuse
      if ((i & 63) == 0 && i < 192) part[i >> 6] = ss;
      __syncthreads();
      if (i < 192) {
        const float tot = part[0] + part[1] + part[2];
        const float r2 = rsqrtf(tot * (1.f / INTER_) + EPS_);
        short8_t o;
        #pragma unroll
        for (int j = 0; j < 8; j++) {
          const int idx = (j < 4) ? (lo + j) : (hi + j - 4);
          o[j] = f2bf(v[j] * r2 * a.nw[idx]);
        }
        *(short8_t*)(a.ynrmb + bt * INTER_ + i * 8) = o;
      }
    }
  }
  grid_bar(a.bar, 512u * 6);

  // ---------------- phase 6: out-proj GEMM (64x64, BK=128) -> fp32 out ----------------
  {
    if (bid < 384) {
      constexpr int PSZ = 64 * 32;
      constexpr int BKG = 4;
      constexpr int BUF = PSZ * BKG;    // 8192 shorts per matrix per buffer
      constexpr int N = HID_, K = INTER_;
      short* As = (short*)SMEM;                 // 2*BUF = 32KB
      short* Bs = (short*)SMEM + 2 * BUF;       // 32KB
      const int m0 = (bid / 12) * 64, n0 = (bid % 12) * 64;
      const int srow = lane >> 2;
      const int sc6 = (lane & 3) * 8;
      const short* A = a.ynrmb;
      const short* Bm = a.wobf;

      auto stage = [&](int buf, int k0) {
        const int row = w * 16 + srow;
        #pragma unroll
        for (int kg = 0; kg < BKG; kg++) {
          gl_lds16(A + (long)(m0 + row) * K + k0 + kg * 32 + sc6, As + buf * BUF + kg * PSZ + w * 512);
          gl_lds16(Bm + (long)(n0 + row) * K + k0 + kg * 32 + sc6, Bs + buf * BUF + kg * PSZ + w * 512);
        }
      };

      float4_t acc[2][2] = {};
      int cur = 0;
      stage(0, 0);
      for (int k0 = 0; k0 < K; k0 += 128) {
        __syncthreads();
        if (k0 + 128 < K) stage(cur ^ 1, k0 + 128);
        #pragma unroll
        for (int kg = 0; kg < BKG; kg++) {
          const short* Ab = As + cur * BUF + kg * PSZ;
          const short* Bb = Bs + cur * BUF + kg * PSZ;
          short8_t af[2], bf[2];
          #pragma unroll
          for (int m = 0; m < 2; m++) af[m] = ldfrag(Ab, wr * 32 + m * 16 + lr, lg);
          #pragma unroll
          for (int n = 0; n < 2; n++) bf[n] = ldfrag(Bb, wc * 32 + n * 16 + lr, lg);
          #pragma unroll
          for (int m = 0; m < 2; m++)
            #pragma unroll
            for (int n = 0; n < 2; n++)
              acc[m][n] = __builtin_amdgcn_mfma_f32_16x16x32_bf16(af[m], bf[n], acc[m][n], 0, 0, 0);
        }
        cur ^= 1;
      }
      #pragma unroll
      for (int m = 0; m < 2; m++)
        #pragma unroll
        for (int n = 0; n < 2; n++)
          #pragma unroll
          for (int r = 0; r < 4; r++) {
            const int row = m0 + wr * 32 + m * 16 + lg * 4 + r;
            const int col = n0 + wc * 32 + n * 16 + lr;
            a.out[(long)row * N + col] = acc[m][n][r];
          }
    }
  }
}

// =====================================================================================
// FALLBACK: original 7-kernel pipeline (used if cooperative launch is rejected)
// =====================================================================================

__global__ __launch_bounds__(256) void cvtdt_k(
    const float* __restrict__ hs, const float* __restrict__ Win, const float* __restrict__ Wout,
    short* __restrict__ hsbf, short* __restrict__ wibf, short* __restrict__ wobf,
    float* __restrict__ dtraw, int ncvt)
{
  const long na = (long)B_ * T_ * HID_, nb = (long)P_ * HID_, nc = (long)HID_ * INTER_;
  if ((int)blockIdx.x < ncvt) {
    const long i = ((long)blockIdx.x * 256 + threadIdx.x) * 8;
    const float* src; short* dst; long off;
    if (i < na)           { src = hs;   dst = hsbf; off = i; }
    else if (i < na + nb) { src = Win;  dst = wibf; off = i - na; }
    else if (i < na + nb + nc) { src = Wout; dst = wobf; off = i - na - nb; }
    else return;
    const long base = (off & ~31L) + ((off >> 3) & 3) * 4;
    float4 v0 = *(const float4*)(src + base);
    float4 v1 = *(const float4*)(src + base + 16);
    short8_t o;
    o[0] = f2bf(v0.x); o[1] = f2bf(v0.y); o[2] = f2bf(v0.z); o[3] = f2bf(v0.w);
    o[4] = f2bf(v1.x); o[5] = f2bf(v1.y); o[6] = f2bf(v1.z); o[7] = f2bf(v1.w);
    *(short8_t*)(dst + off) = o;
  } else {
    const int rowbt = ((int)blockIdx.x - ncvt) * 4 + (threadIdx.x >> 6);
    const int lane = threadIdx.x & 63;
    float hv[12];
    const float* hrow = hs + (long)rowbt * HID_ + lane * 12;
    #pragma unroll
    for (int j = 0; j < 12; j++) hv[j] = hrow[j];
    const float* wbase = Win + (long)(INTER_ + CONV_DIM_) * HID_ + lane * 12;
    for (int h = 0; h < NH_; h++) {
      const float* wr = wbase + (long)h * HID_;
      float s = 0.f;
      #pragma unroll
      for (int j = 0; j < 12; j++) s = fmaf(hv[j], wr[j], s);
      #pragma unroll
      for (int off = 32; off; off >>= 1) s += __shfl_xor(s, off);
      if (lane == 0) dtraw[(long)rowbt * NH_ + h] = s;
    }
  }
}

__global__ __launch_bounds__(256) void inproj_scan_k(
    const short* __restrict__ A, const short* __restrict__ B, short* __restrict__ C,
    const float* __restrict__ dtraw, const float* __restrict__ dt_bias,
    const float* __restrict__ A_log, float* __restrict__ dtT, float* __restrict__ cAT,
    float* __restrict__ qT)
{
  constexpr int TM = 128, TN = 128, K = HID_, BK = 64;
  constexpr int PSZ = TM * 32;
  constexpr int ASZ = 2 * PSZ;
  __shared__ short As[2 * ASZ];
  __shared__ short Bs[2 * ASZ];

  if (blockIdx.y >= 16) {
    const int sid = ((int)blockIdx.y - 16) * 29 + (int)blockIdx.x;
    if (sid >= B_ * NH_) return;
    const int b = sid / NH_;
    const int h = sid % NH_;
    const float bias = dt_bias[h];
    const float Ah = -__expf(A_log[h]);
    const long ob = (long)(h * B_ + b) * T_;
    float* sc = (float*)As;
    float carry = 0.f;
    for (int c0 = 0; c0 < T_; c0 += 256) {
      const int t = c0 + threadIdx.x;
      const long bt = (long)b * T_ + t;
      float sp = softplus_f(dtraw[bt * NH_ + h] + bias);
      dtT[ob + t] = sp;
      sc[threadIdx.x] = sp * Ah;
      __syncthreads();
      for (int off = 1; off < 256; off <<= 1) {
        float add = (threadIdx.x >= off) ? sc[threadIdx.x - off] : 0.f;
        __syncthreads();
        sc[threadIdx.x] += add;
        __syncthreads();
      }
      cAT[ob + t] = carry + sc[threadIdx.x];
      qT[ob + t] = sp * __expf(sc[threadIdx.x | 63] - sc[threadIdx.x]);
      float tot = sc[255];
      __syncthreads();
      carry += tot;
    }
    return;
  }

  const int tid = threadIdx.x;
  const int w = tid >> 6, lane = tid & 63;
  const int lr = lane & 15, lg = lane >> 4;
  const int wr = w >> 1, wc = w & 1;
  const int m0 = blockIdx.y * TM, n0 = blockIdx.x * TN;
  const int srow = lane >> 2;
  const int sc2 = (lane & 3) * 8;

  auto stage = [&](int buf, int k0) {
    #pragma unroll
    for (int it = 0; it < 2; it++) {
      const int cb = w + 4 * it;
      const int row = cb * 16 + srow;
      #pragma unroll
      for (int kg = 0; kg < 2; kg++) {
        gl_lds16(A + (long)(m0 + row) * K + k0 + kg * 32 + sc2,
                 As + buf * ASZ + kg * PSZ + cb * 512);
        gl_lds16(B + (long)(n0 + row) * K + k0 + kg * 32 + sc2,
                 Bs + buf * ASZ + kg * PSZ + cb * 512);
      }
    }
  };

  float4_t acc[4][4] = {};
  int cur = 0;
  stage(0, 0);
  for (int k0 = 0; k0 < K; k0 += BK) {
    __syncthreads();
    if (k0 + BK < K) stage(cur ^ 1, k0 + BK);
    #pragma unroll
    for (int kg = 0; kg < 2; kg++) {
      const short* Ab = As + cur * ASZ + kg * PSZ;
      const short* Bb = Bs + cur * ASZ + kg * PSZ;
      short8_t af[4], bf[4];
      #pragma unroll
      for (int m = 0; m < 4; m++) af[m] = ldfrag(Ab, wr * 64 + m * 16 + lr, lg);
      #pragma unroll
      for (int n = 0; n < 4; n++) bf[n] = ldfrag(Bb, wc * 64 + n * 16 + lr, lg);
      #pragma unroll
      for (int m = 0; m < 4; m++)
        #pragma unroll
        for (int n = 0; n < 4; n++)
          acc[m][n] = __builtin_amdgcn_mfma_f32_16x16x32_bf16(af[m], bf[n], acc[m][n], 0, 0, 0);
    }
    cur ^= 1;
  }

  #pragma unroll
  for (int m = 0; m < 4; m++)
    #pragma unroll
    for (int n = 0; n < 4; n++)
      #pragma unroll
      for (int r = 0; r < 4; r++) {
        const int row = m0 + wr * 64 + m * 16 + lg * 4 + r;
        const int col = n0 + wc * 64 + n * 16 + lr;
        C[(long)row * P_ + col] = f2bf(acc[m][n][r]);
      }
}

__global__ __launch_bounds__(256) void gemm_out_k(
    const short* __restrict__ A, const short* __restrict__ B, float* __restrict__ C,
    int M, int N, int K)
{
  constexpr int PSZ = 64 * 32;
  constexpr int BKG = 4;
  constexpr int BUF = PSZ * BKG;
  __shared__ short As[2 * BUF];
  __shared__ short Bs[2 * BUF];
  const int tid = threadIdx.x;
  const int w = tid >> 6, lane = tid & 63;
  const int lr = lane & 15, lg = lane >> 4;
  const int wr = w >> 1, wc = w & 1;
  const int m0 = blockIdx.y * 64, n0 = blockIdx.x * 64;
  const int srow = lane >> 2;
  const int sc = (lane & 3) * 8;

  auto stage = [&](int buf, int k0) {
    const int row = w * 16 + srow;
    #pragma unroll
    for (int kg = 0; kg < BKG; kg++) {
      gl_lds16(A + (long)(m0 + row) * K + k0 + kg * 32 + sc, As + buf * BUF + kg * PSZ + w * 512);
      gl_lds16(B + (long)(n0 + row) * K + k0 + kg * 32 + sc, Bs + buf * BUF + kg * PSZ + w * 512);
    }
  };

  float4_t acc[2][2] = {};
  int cur = 0;
  stage(0, 0);
  for (int k0 = 0; k0 < K; k0 += 128) {
    __syncthreads();
    if (k0 + 128 < K) stage(cur ^ 1, k0 + 128);
    #pragma unroll
    for (int kg = 0; kg < BKG; kg++) {
      const short* Ab = As + cur * BUF + kg * PSZ;
      const short* Bb = Bs + cur * BUF + kg * PSZ;
      short8_t af[2], bf[2];
      #pragma unroll
      for (int m = 0; m < 2; m++) af[m] = ldfrag(Ab, wr * 32 + m * 16 + lr, lg);
      #pragma unroll
      for (int n = 0; n < 2; n++) bf[n] = ldfrag(Bb, wc * 32 + n * 16 + lr, lg);
      #pragma unroll
      for (int m = 0; m < 2; m++)
        #pragma unroll
        for (int n = 0; n < 2; n++)
          acc[m][n] = __builtin_amdgcn_mfma_f32_16x16x32_bf16(af[m], bf[n], acc[m][n], 0, 0, 0);
    }
    cur ^= 1;
  }

  #pragma unroll
  for (int m = 0; m < 2; m++)
    #pragma unroll
    for (int n = 0; n < 2; n++)
      #pragma unroll
      for (int r = 0; r < 4; r++) {
        const int row = m0 + wr * 32 + m * 16 + lg * 4 + r;
        const int col = n0 + wc * 32 + n * 16 + lr;
        C[(long)row * N + col] = acc[m][n][r];
      }
}

__global__ __launch_bounds__(256) void gemm_cbh_k(
    const short* __restrict__ Chh, const short* __restrict__ Bh, short* __restrict__ CBh)
{
  if (blockIdx.x > blockIdx.y) return;
  Chh += (long)blockIdx.z * T_ * NS_;
  Bh  += (long)blockIdx.z * T_ * NS_;
  CBh += (long)blockIdx.z * T_ * T_;
  constexpr int PSZ = 64 * 32;
  __shared__ short As[4 * PSZ];
  __shared__ short Bs[4 * PSZ];
  const int tid = threadIdx.x;
  const int w = tid >> 6, lane = tid & 63;
  const int lr = lane & 15, lg = lane >> 4;
  const int wr = w >> 1, wc = w & 1;
  const int m0 = blockIdx.y * 64, n0 = blockIdx.x * 64;
  const int srow = lane >> 2;
  const int sc = (lane & 3) * 8;

  {
    const int row = w * 16 + srow;
    #pragma unroll
    for (int kg = 0; kg < 4; kg++) {
      gl_lds16(Chh + (long)(m0 + row) * NS_ + kg * 32 + sc, As + kg * PSZ + w * 512);
      gl_lds16(Bh  + (long)(n0 + row) * NS_ + kg * 32 + sc, Bs + kg * PSZ + w * 512);
    }
  }
  __syncthreads();

  float4_t acc[2][2] = {};
  #pragma unroll
  for (int kg = 0; kg < 4; kg++) {
    const short* Ab = As + kg * PSZ;
    const short* Bb = Bs + kg * PSZ;
    short8_t af[2], bf[2];
    #pragma unroll
    for (int m = 0; m < 2; m++) af[m] = ldfrag(Ab, wr * 32 + m * 16 + lr, lg);
    #pragma unroll
    for (int n = 0; n < 2; n++) bf[n] = ldfrag(Bb, wc * 32 + n * 16 + lr, lg);
    #pragma unroll
    for (int m = 0; m < 2; m++)
      #pragma unroll
      for (int n = 0; n < 2; n++)
        acc[m][n] = __builtin_amdgcn_mfma_f32_16x16x32_bf16(af[m], bf[n], acc[m][n], 0, 0, 0);
  }

  #pragma unroll
  for (int m = 0; m < 2; m++)
    #pragma unroll
    for (int n = 0; n < 2; n++)
      #pragma unroll
      for (int r = 0; r < 4; r++) {
        const int row = m0 + wr * 32 + m * 16 + lg * 4 + r;
        const int sl = wc * 32 + n * 16 + lr;
        const int g = sl >> 5, k32 = sl & 31;
        const int cc = g * 4 + ((k32 >> 2) & 3);
        const int off = ((cc ^ (row & 7)) * 8) + 4 * (k32 >> 4) + (k32 & 3);
        CBh[(long)row * T_ + n0 + off] = f2bf(acc[m][n][r]);
      }
}

__global__ __launch_bounds__(256) void conv_silu_k(
    const short* __restrict__ projh, const float* __restrict__ cw, const float* __restrict__ cbias,
    const float* __restrict__ qT,
    short* __restrict__ xTr, short* __restrict__ xTq,
    short* __restrict__ Bh, short* __restrict__ Chh)
{
  const int c0 = blockIdx.x * 256;
  const int t0 = blockIdx.y * 16;
  const int b  = blockIdx.z;
  const int tid = threadIdx.x;
  __shared__ float S[19][256];
  #pragma unroll
  for (int r = 0; r < 19; r++) {
    const int t = t0 - 3 + r;
    S[r][tid] = (t >= 0) ? bf2f(projh[((long)b * T_ + t) * P_ + INTER_ + c0 + tid]) : 0.f;
  }
  __syncthreads();
  const int c = c0 + tid;
  const float4 w = *(const float4*)(cw + c * 4);
  const float bias = cbias[c];
  float acc[16];
  #pragma unroll
  for (int tt = 0; tt < 16; tt++) {
    float a = bias + w.w * S[tt + 3][tid] + w.z * S[tt + 2][tid]
                   + w.y * S[tt + 1][tid] + w.x * S[tt][tid];
    acc[tt] = a / (1.f + __expf(-a));
  }
  if (c < INTER_) {
    const int h = c >> 6, hd = c & 63;
    const long chb = (long)(h * B_ + b) * T_;
    float qv[16];
    #pragma unroll
    for (int qq = 0; qq < 4; qq++) {
      float4 q4 = *(const float4*)(qT + chb + t0 + qq * 4);
      qv[qq*4+0] = q4.x; qv[qq*4+1] = q4.y; qv[qq*4+2] = q4.z; qv[qq*4+3] = q4.w;
    }
    const long base = ((long)(b * NH_ + h) * HD_ + hd) * T_ + (t0 & ~63);
    const int g = (t0 >> 5) & 1, h2 = (t0 >> 4) & 1, sw = hd & 7;
    #pragma unroll
    for (int a = 0; a < 4; a++) {
      short4_t xr, xq;
      #pragma unroll
      for (int r = 0; r < 4; r++) {
        xr[r] = f2bf(acc[a * 4 + r]);
        xq[r] = f2bf(acc[a * 4 + r] * qv[a * 4 + r]);
      }
      const int off = (((g * 4 + a) ^ sw) * 8) + h2 * 4;
      *(short4_t*)(xTr + base + off) = xr;
      *(short4_t*)(xTq + base + off) = xq;
    }
  } else {
    const int ch0 = c - INTER_;
    const bool isB = ch0 < NS_;
    const int k = isB ? ch0 : ch0 - NS_;
    const int k32 = k & 31;
    const int P = (k & ~31) + 8 * ((k32 >> 2) & 3) + 4 * (k32 >> 4) + (k32 & 3);
    short* dst = isB ? Bh : Chh;
    #pragma unroll
    for (int tt = 0; tt < 16; tt++) {
      const long bt = (long)b * T_ + t0 + tt;
      dst[bt * NS_ + P] = f2bf(acc[tt]);
    }
  }
}

__global__ __launch_bounds__(256) void attn_mfma3_k(
    const short* __restrict__ xTr, const short* __restrict__ xTq,
    const short* __restrict__ CBh,
    const float* __restrict__ cAT, const float* __restrict__ dtT,
    const short* __restrict__ projh, const float* __restrict__ Lw,
    const float* __restrict__ Dv,
    short* __restrict__ ybh)
{
  const int h = blockIdx.x;
  const int tt = (T_ / 64 - 1) - blockIdx.y;
  const int b = blockIdx.z;
  const int t0 = tt * 64;
  const int tid = threadIdx.x;
  const int w = tid >> 6, lane = tid & 63;
  const int lr = lane & 15, lg = lane >> 4;

  __shared__ short CBl[2][64 * 64];
  __shared__ short Xl[2][64 * 64];
  __shared__ float lamS[64][17];

  for (int f = tid; f < 64 * NLVL_; f += 256) {
    int r = f / NLVL_, l = f - r * NLVL_;
    lamS[r][l] = softplus_f(
        bf2f(projh[((long)b * T_ + t0 + r) * P_ + INTER_ + CONV_DIM_ + NH_ + h * NLVL_ + l]))
        * Lw[h * NLVL_ + l];
  }

  const int tl = w * 16 + lr;
  const int t  = t0 + tl;
  const int orow = w * 16 + lg * 4;
  const long chb = (long)(h * B_ + b) * T_;
  const float catv = cAT[chb + t];
  float cao[4];
  #pragma unroll
  for (int r = 0; r < 4; r++) cao[r] = cAT[chb + t0 + orow + r];

  const short* xbr = xTr + (long)(b * NH_ + h) * HD_ * T_;
  const short* xbq = xTq + (long)(b * NH_ + h) * HD_ * T_;
  const short* CBbase = CBh + (long)b * T_ * T_ + (long)t0 * T_;

  const int srow = w * 16 + (lane >> 3);
  const int sch = (lane & 7) * 8;

  auto stage = [&](int buf, int st) {
    const int s0 = st * 64;
    const short* xsrc = (st == tt) ? xbr : xbq;
    #pragma unroll
    for (int i = 0; i < 2; i++) {
      gl_lds16(CBbase + (long)(srow + i * 8) * T_ + s0 + sch, &CBl[buf][(w * 16 + i * 8) * 64]);
      gl_lds16(xsrc + (long)(srow + i * 8) * T_ + s0 + sch, &Xl[buf][(w * 16 + i * 8) * 64]);
    }
  };

  float4_t acc[4] = {};
  int cur = 0;
  stage(0, 0);
  for (int st = 0; st <= tt; st++) {
    __syncthreads();
    if (st < tt) stage(cur ^ 1, st + 1);
    const int s0 = st * 64;
    if (st < tt) {
      const float caE = cAT[chb + s0 + 63];
      const int lev = 32 - __clz(t0 ^ s0);
      float k1o[4];
      #pragma unroll
      for (int r = 0; r < 4; r++)
        k1o[r] = __expf(cao[r] - caE) * lamS[orow + r][lev];
      float4_t dtile[4] = {};
      __builtin_amdgcn_s_setprio(1);
      #pragma unroll
      for (int kk = 0; kk < 2; kk++) {
        short8_t af = ldfrag64(CBl[cur], tl, kk, lg);
        #pragma unroll
        for (int n = 0; n < 4; n++) {
          short8_t bfv = ldfrag64(Xl[cur], n * 16 + lr, kk, lg);
          dtile[n] = __builtin_amdgcn_mfma_f32_16x16x32_bf16(af, bfv, dtile[n], 0, 0, 0);
        }
      }
      __builtin_amdgcn_s_setprio(0);
      #pragma unroll
      for (int n = 0; n < 4; n++)
        #pragma unroll
        for (int r = 0; r < 4; r++)
          acc[n][r] = fmaf(k1o[r], dtile[n][r], acc[n][r]);
    } else {
      #pragma unroll
      for (int kk = 0; kk < 2; kk++) {
        short8_t cb8 = ldfrag64(CBl[cur], tl, kk, lg);
        short8_t af;
        #pragma unroll
        for (int g = 0; g < 2; g++) {
          const int sb = s0 + kk * 32 + g * 16 + lg * 4;
          float4_t ca4 = *(const float4_t*)(cAT + chb + sb);
          float4_t dt4 = *(const float4_t*)(dtT + chb + sb);
          #pragma unroll
          for (int a = 0; a < 4; a++) {
            const int sg = sb + a;
            float m = 0.f;
            if (sg <= t) {
              const int xo = t ^ sg;
              const int lev2 = xo ? (32 - __clz(xo)) : 0;
              m = bf2f(cb8[g * 4 + a]) * __expf(catv - ca4[a]) * lamS[tl][lev2] * dt4[a];
            }
            af[g * 4 + a] = f2bf(m);
          }
        }
        __builtin_amdgcn_s_setprio(1);
        #pragma unroll
        for (int n = 0; n < 4; n++) {
          short8_t bfv = ldfrag64(Xl[cur], n * 16 + lr, kk, lg);
          acc[n] = __builtin_amdgcn_mfma_f32_16x16x32_bf16(af, bfv, acc[n], 0, 0, 0);
        }
        __builtin_amdgcn_s_setprio(0);
      }
    }
    cur ^= 1;
  }

  const float Dh = Dv[h];
  const short* Xd = Xl[cur ^ 1];
  #pragma unroll
  for (int n = 0; n < 4; n++) {
    #pragma unroll
    for (int r = 0; r < 4; r++) {
      const int trow = t0 + orow + r;
      const int hd = n * 16 + lr;
      const int xoff = hd * 64 + ((((w >> 1) * 4 + lg) ^ (hd & 7)) * 8) + (w & 1) * 4 + r;
      const float xv = bf2f(Xd[xoff]);
      ybh[((long)b * T_ + trow) * INTER_ + h * HD_ + hd] = f2bf(acc[n][r] + Dh * xv);
    }
  }
}

__global__ __launch_bounds__(192) void gate_rms_k(
    const short* __restrict__ ybh, const short* __restrict__ projh,
    const float* __restrict__ nw, short* __restrict__ ynorm)
{
  const long bt = blockIdx.x;
  const short* gp = projh + bt * P_;
  const short* yp = ybh + bt * INTER_;
  const int i = threadIdx.x;
  const int lo = (i >> 2) * 32 + (i & 3) * 4;
  const int hi = lo + 16;
  float v[8];
  float ss = 0.f;
  {
    short4_t g0 = *(const short4_t*)(gp + lo);
    short4_t g1 = *(const short4_t*)(gp + hi);
    short4_t y0 = *(const short4_t*)(yp + lo);
    short4_t y1 = *(const short4_t*)(yp + hi);
    float ga[8] = {bf2f(g0[0]), bf2f(g0[1]), bf2f(g0[2]), bf2f(g0[3]),
                   bf2f(g1[0]), bf2f(g1[1]), bf2f(g1[2]), bf2f(g1[3])};
    float ya[8] = {bf2f(y0[0]), bf2f(y0[1]), bf2f(y0[2]), bf2f(y0[3]),
                   bf2f(y1[0]), bf2f(y1[1]), bf2f(y1[2]), bf2f(y1[3])};
    #pragma unroll
    for (int j = 0; j < 8; j++) {
      float val = ya[j] * (ga[j] / (1.f + __expf(-ga[j])));
      v[j] = val;
      ss += val * val;
    }
  }
  #pragma unroll
  for (int off = 32; off > 0; off >>= 1) ss += __shfl_xor(ss, off);
  __shared__ float part[3];
  if ((i & 63) == 0) part[i >> 6] = ss;
  __syncthreads();
  const float tot = part[0] + part[1] + part[2];
  const float r = rsqrtf(tot * (1.f / INTER_) + EPS_);
  short8_t o;
  #pragma unroll
  for (int j = 0; j < 8; j++) {
    const int idx = (j < 4) ? (lo + j) : (hi + j - 4);
    o[j] = f2bf(v[j] * r * nw[idx]);
  }
  *(short8_t*)(ynorm + bt * INTER_ + i * 8) = o;
}

extern "C" void kernel_launch(void* const* d_in, const int* in_sizes, int n_in,
                              void* d_out, int out_size, void* d_ws, size_t ws_size,
                              hipStream_t stream) {
  const float* hs   = (const float*)d_in[0];
  const float* Win  = (const float*)d_in[1];
  const float* cw   = (const float*)d_in[2];
  const float* cb   = (const float*)d_in[3];
  const float* dtb  = (const float*)d_in[4];
  const float* Alog = (const float*)d_in[5];
  const float* Lw   = (const float*)d_in[6];
  const float* Dv   = (const float*)d_in[7];
  const float* nw   = (const float*)d_in[8];
  const float* Wout = (const float*)d_in[9];
  float* out = (float*)d_out;

  const long n_hs = (long)B_ * T_ * HID_;
  const long n_wi = (long)P_ * HID_;
  const long n_wo = (long)HID_ * INTER_;

  float* ws = (float*)d_ws;
  long o = 0;
  float* projreg = ws + o; o += (long)B_ * T_ * P_ / 2 + 16;
  short* xbf   = (short*)(ws + o); o += (long)B_ * T_ * INTER_ / 2;  // (slot retained, unused)
  short* Bh    = (short*)(ws + o); o += (long)B_ * T_ * NS_ / 2;
  short* Chh   = (short*)(ws + o); o += (long)B_ * T_ * NS_ / 2;
  float* dtT   = ws + o; o += (long)B_ * T_ * NH_;
  float* cAT   = ws + o; o += (long)B_ * T_ * NH_;
  float* qT    = ws + o; o += (long)B_ * T_ * NH_;
  float* dtraw = ws + o; o += (long)B_ * T_ * NH_;
  short* CBh   = (short*)(ws + o); o += (long)B_ * T_ * T_ / 2;
  short* ybh   = (short*)(ws + o); o += (long)B_ * T_ * INTER_ / 2;
  float* yxreg = ws + o; o += (long)B_ * T_ * INTER_ / 2;
  short* hsbf  = (short*)(ws + o); o += n_hs / 2;
  short* wibf  = (short*)(ws + o); o += n_wi / 2;
  short* wobf  = (short*)(ws + o); o += n_wo / 2;
  unsigned* bar = (unsigned*)(ws + o); o += 64;
  short* projh = (short*)projreg;
  short* xTr   = (short*)yxreg;
  short* ynrmb = (short*)yxreg;
  short* xTq   = hsbf;
  (void)xbf;

  // zero the barrier counter (workspace is poisoned each reset)
  hipMemsetAsync(bar, 0, 64, stream);

  // ---- preferred path: single cooperative mega-kernel (512 blocks = 2/CU @ 64KB LDS) ----
  MegaArgs ma;
  ma.hs = hs; ma.Win = Win; ma.cw = cw; ma.cb = cb; ma.dtb = dtb; ma.Alog = Alog;
  ma.Lw = Lw; ma.Dv = Dv; ma.nw = nw; ma.Wout = Wout; ma.out = out;
  ma.hsbf = hsbf; ma.wibf = wibf; ma.wobf = wobf;
  ma.dtraw = dtraw; ma.dtT = dtT; ma.cAT = cAT; ma.qT = qT;
  ma.projh = projh; ma.xTr = xTr; ma.xTq = xTq; ma.Bh = Bh; ma.Chh = Chh;
  ma.CBh = CBh; ma.ybh = ybh; ma.ynrmb = ynrmb; ma.bar = bar;
  void* kargs[] = { (void*)&ma };
  hipError_t ce = hipLaunchCooperativeKernel(
      (const void*)mega_k, dim3(512), dim3(256), kargs, 0, stream);
  if (ce == hipSuccess) return;

  // ---- fallback: proven 7-kernel pipeline ----
  const int ncvt = (int)((n_hs + n_wi + n_wo) / 8 / 256);
  cvtdt_k<<<ncvt + (B_ * T_) / 4, 256, 0, stream>>>(
      hs, Win, Wout, hsbf, wibf, wobf, dtraw, ncvt);
  inproj_scan_k<<<dim3(P_ / 128, 18), 256, 0, stream>>>(
      hsbf, wibf, projh, dtraw, dtb, Alog, dtT, cAT, qT);
  conv_silu_k<<<dim3(CONV_DIM_ / 256, T_ / 16, B_), 256, 0, stream>>>(
      projh, cw, cb, qT, xTr, xTq, Bh, Chh);
  gemm_cbh_k<<<dim3(T_ / 64, T_ / 64, B_), 256, 0, stream>>>(Chh, Bh, CBh);
  attn_mfma3_k<<<dim3(NH_, T_ / 64, B_), 256, 0, stream>>>(
      xTr, xTq, CBh, cAT, dtT, projh, Lw, Dv, ybh);
  gate_rms_k<<<B_ * T_, 192, 0, stream>>>(ybh, projh, nw, ynrmb);
  gemm_out_k<<<dim3(HID_ / 64, (B_ * T_) / 64), 256, 0, stream>>>(
      ynrmb, wobf, out, B_ * T_, HID_, INTER_);
}

// Round 4
// 409.753 us; speedup vs baseline: 1.9833x; 1.4286x over previous
//
#include <hip/hip_runtime.h>
#include <hip/hip_bf16.h>
#include <math.h>

#define B_ 2
#define T_ 1024
#define HID_ 768
#define INTER_ 1536
#define NH_ 24
#define HD_ 64
#define NS_ 128
#define NLVL_ 15
#define CONV_DIM_ 1792
#define P_ 3712
#define EPS_ 1e-5f

typedef short short8_t __attribute__((ext_vector_type(8)));
typedef short short4_t __attribute__((ext_vector_type(4)));
typedef float float4_t __attribute__((ext_vector_type(4)));

// K-permutation (within each 32-element K-group): physical p = 8a + 4h + r for
// logical k = 16h + 4a + r. A lane's MFMA operand (k = lg*4+{0..3} and +16) is then
// ONE contiguous 16B chunk at p = 8*lg  ->  single ds_read_b128 per fragment.

__device__ __forceinline__ float softplus_f(float x) {
  return (x > 20.f) ? x : log1pf(__expf(x));
}
__device__ __forceinline__ short f2bf(float f) {
  union { float f; unsigned u; } v; v.f = f;
  unsigned r = v.u + 0x7FFF + ((v.u >> 16) & 1);   // RNE
  return (short)(r >> 16);
}
__device__ __forceinline__ float bf2f(short s) {
  union { unsigned u; float f; } v; v.u = ((unsigned)(unsigned short)s) << 16;
  return v.f;
}
__device__ __forceinline__ void gl_lds16(const void* g, void* l) {
  __builtin_amdgcn_global_load_lds(
      (const __attribute__((address_space(1))) unsigned int*)g,
      (__attribute__((address_space(3))) unsigned int*)l, 16, 0, 0);
}

// Fence-minimal grid barrier. R3's version had ALL threads execute __threadfence()
// (= buffer_wbl2 + buffer_inv whole-L2 ops) -> ~131k full-L2 walks per barrier,
// ~80us each. Here: release/acquire via scoped atomic orderings on thread 0 ONLY
// (1 wbl2 + 1 inv per BLOCK). __syncthreads() drains vmcnt(0) for every wave first,
// so each block's stores are in its XCD L2 before its release-wbl2; the final
// ACQUIRE load (buffer_inv) invalidates this CU's L1 + XCD L2 before any thread
// of the block passes the trailing __syncthreads.
__device__ __forceinline__ void grid_bar(unsigned* bar, unsigned target) {
  __syncthreads();
  if (threadIdx.x == 0) {
    __hip_atomic_fetch_add(bar, 1u, __ATOMIC_RELEASE, __HIP_MEMORY_SCOPE_AGENT);
    while (__hip_atomic_load(bar, __ATOMIC_RELAXED, __HIP_MEMORY_SCOPE_AGENT) < target)
      __builtin_amdgcn_s_sleep(4);                  // ~256 cycles per poll
    (void)__hip_atomic_load(bar, __ATOMIC_ACQUIRE, __HIP_MEMORY_SCOPE_AGENT);
  }
  __syncthreads();
}

// Permuted LDS fragment read (BK-panel of 32 K): one b128 per fragment.
__device__ __forceinline__ short8_t ldfrag(const short* Ts, int row, int lg) {
  return *(const short8_t*)(Ts + row * 32 + lg * 8);
}

// Permuted+row-swizzled 64-wide fragment read (attn): one b128 per fragment.
__device__ __forceinline__ short8_t ldfrag64(const short* Ts, int row, int kk, int lg) {
  const int cc = (kk * 4 + lg) ^ (row & 7);
  return *(const short8_t*)(Ts + row * 64 + cc * 8);
}

// =====================================================================================
// MEGA KERNEL: whole pipeline, 512 blocks x 256 threads (2 blocks/CU @ 64KB LDS),
// phases separated by custom grid barrier. Eliminates 6 kernel-boundary gaps/drains.
// =====================================================================================
struct MegaArgs {
  const float *hs, *Win, *cw, *cb, *dtb, *Alog, *Lw, *Dv, *nw, *Wout;
  float *out;
  short *hsbf, *wibf, *wobf;
  float *dtraw, *dtT, *cAT, *qT;
  short *projh, *xTr, *xTq, *Bh, *Chh, *CBh, *ybh, *ynrmb;
  unsigned *bar;
};

__global__ __launch_bounds__(256, 2) void mega_k(MegaArgs a)
{
  const int bid = blockIdx.x;
  const int tid = threadIdx.x;
  const int w = tid >> 6, lane = tid & 63;
  const int lr = lane & 15, lg = lane >> 4;
  const int wr = w >> 1, wc = w & 1;
  __shared__ char SMEM[65536] __attribute__((aligned(16)));

  // ---------------- phase 0: f32->bf16 K-permuted cvt (hs/Win/Wout) + fp32 dt columns ----------
  {
    const long na = (long)B_ * T_ * HID_, nb = (long)P_ * HID_, nc = (long)HID_ * INTER_;
    const long tot8 = (na + nb + nc) / 8;
    for (long it = (long)bid * 256 + tid; it < tot8; it += 512L * 256) {
      const long i = it * 8;
      const float* src; short* dst; long off;
      if (i < na)           { src = a.hs;   dst = a.hsbf; off = i; }
      else if (i < na + nb) { src = a.Win;  dst = a.wibf; off = i - na; }
      else                  { src = a.Wout; dst = a.wobf; off = i - na - nb; }
      const long base = (off & ~31L) + ((off >> 3) & 3) * 4;
      float4 v0 = *(const float4*)(src + base);
      float4 v1 = *(const float4*)(src + base + 16);
      short8_t o;
      o[0] = f2bf(v0.x); o[1] = f2bf(v0.y); o[2] = f2bf(v0.z); o[3] = f2bf(v0.w);
      o[4] = f2bf(v1.x); o[5] = f2bf(v1.y); o[6] = f2bf(v1.z); o[7] = f2bf(v1.w);
      *(short8_t*)(dst + off) = o;
    }
    // dt GEMV: one bt-row per wave, 4 per block (512*4 = 2048)
    const int rowbt = bid * 4 + w;
    float hv[12];
    const float* hrow = a.hs + (long)rowbt * HID_ + lane * 12;
    #pragma unroll
    for (int j = 0; j < 12; j++) hv[j] = hrow[j];
    const float* wbase = a.Win + (long)(INTER_ + CONV_DIM_) * HID_ + lane * 12;
    for (int h = 0; h < NH_; h++) {
      const float* wrp = wbase + (long)h * HID_;
      float s = 0.f;
      #pragma unroll
      for (int j = 0; j < 12; j++) s = fmaf(hv[j], wrp[j], s);
      #pragma unroll
      for (int sof = 32; sof; sof >>= 1) s += __shfl_xor(s, sof);
      if (lane == 0) a.dtraw[(long)rowbt * NH_ + h] = s;
    }
  }
  grid_bar(a.bar, 512u * 1);

  // ---------------- phase 1: in-proj GEMM (128x128, BK=64, bf16 out) + dt_scan ----------------
  {
    if (bid < 464) {
      constexpr int K = HID_, BK = 64;
      constexpr int PSZ = 128 * 32;     // 4096 shorts
      constexpr int ASZ = 2 * PSZ;      // per buffer: 8192 shorts
      short* As = (short*)SMEM;                 // 2*ASZ = 32KB
      short* Bs = (short*)SMEM + 2 * ASZ;       // 32KB
      const int by = bid / 29, bx = bid - by * 29;
      const int m0 = by * 128, n0 = bx * 128;
      const int srow = lane >> 2;
      const int sc2 = (lane & 3) * 8;
      const short* A = a.hsbf;
      const short* Bm = a.wibf;

      auto stage = [&](int buf, int k0) {
        #pragma unroll
        for (int it2 = 0; it2 < 2; it2++) {
          const int cb = w + 4 * it2;
          const int row = cb * 16 + srow;
          #pragma unroll
          for (int kg = 0; kg < 2; kg++) {
            gl_lds16(A + (long)(m0 + row) * K + k0 + kg * 32 + sc2,
                     As + buf * ASZ + kg * PSZ + cb * 512);
            gl_lds16(Bm + (long)(n0 + row) * K + k0 + kg * 32 + sc2,
                     Bs + buf * ASZ + kg * PSZ + cb * 512);
          }
        }
      };

      float4_t acc[4][4] = {};
      int cur = 0;
      stage(0, 0);
      for (int k0 = 0; k0 < K; k0 += BK) {
        __syncthreads();
        if (k0 + BK < K) stage(cur ^ 1, k0 + BK);
        #pragma unroll
        for (int kg = 0; kg < 2; kg++) {
          const short* Ab = As + cur * ASZ + kg * PSZ;
          const short* Bb = Bs + cur * ASZ + kg * PSZ;
          short8_t af[4], bf[4];
          #pragma unroll
          for (int m = 0; m < 4; m++) af[m] = ldfrag(Ab, wr * 64 + m * 16 + lr, lg);
          #pragma unroll
          for (int n = 0; n < 4; n++) bf[n] = ldfrag(Bb, wc * 64 + n * 16 + lr, lg);
          #pragma unroll
          for (int m = 0; m < 4; m++)
            #pragma unroll
            for (int n = 0; n < 4; n++)
              acc[m][n] = __builtin_amdgcn_mfma_f32_16x16x32_bf16(af[m], bf[n], acc[m][n], 0, 0, 0);
        }
        cur ^= 1;
      }
      #pragma unroll
      for (int m = 0; m < 4; m++)
        #pragma unroll
        for (int n = 0; n < 4; n++)
          #pragma unroll
          for (int r = 0; r < 4; r++) {
            const int row = m0 + wr * 64 + m * 16 + lg * 4 + r;
            const int col = n0 + wc * 64 + n * 16 + lr;
            a.projh[(long)row * P_ + col] = f2bf(acc[m][n][r]);
          }
    } else {
      const int sid = bid - 464;     // 0..47 == B_*NH_
      const int b = sid / NH_;
      const int h = sid % NH_;
      const float bias = a.dtb[h];
      const float Ah = -__expf(a.Alog[h]);
      const long ob = (long)(h * B_ + b) * T_;
      float* scn = (float*)SMEM;
      float carry = 0.f;
      for (int c0 = 0; c0 < T_; c0 += 256) {
        const int t = c0 + tid;
        const long bt = (long)b * T_ + t;
        float sp = softplus_f(a.dtraw[bt * NH_ + h] + bias);
        a.dtT[ob + t] = sp;
        scn[tid] = sp * Ah;
        __syncthreads();
        for (int off = 1; off < 256; off <<= 1) {
          float add = (tid >= off) ? scn[tid - off] : 0.f;
          __syncthreads();
          scn[tid] += add;
          __syncthreads();
        }
        a.cAT[ob + t] = carry + scn[tid];
        a.qT[ob + t] = sp * __expf(scn[tid | 63] - scn[tid]);
        float tot = scn[255];
        __syncthreads();
        carry += tot;
      }
    }
  }
  grid_bar(a.bar, 512u * 2);

  // ---------------- phase 2: conv (K=4) + bias + SiLU + fused x-transpose; B/C permuted --------
  {
    float* S = (float*)SMEM;   // [19][256]
    #pragma unroll 1
    for (int u = bid; u < 7 * 64 * B_; u += 512) {
      const int cgi = u % 7;
      const int rest = u / 7;
      const int ty = rest % 64;
      const int b = rest / 64;
      const int c0 = cgi * 256, t0 = ty * 16;
      __syncthreads();   // guard LDS reuse across units/phases
      #pragma unroll
      for (int r = 0; r < 19; r++) {
        const int t = t0 - 3 + r;
        S[r * 256 + tid] = (t >= 0) ? bf2f(a.projh[((long)b * T_ + t) * P_ + INTER_ + c0 + tid]) : 0.f;
      }
      __syncthreads();
      const int c = c0 + tid;
      const float4 cwv = *(const float4*)(a.cw + c * 4);
      const float bias = a.cb[c];
      float acc[16];
      #pragma unroll
      for (int tt = 0; tt < 16; tt++) {
        float v = bias + cwv.w * S[(tt + 3) * 256 + tid] + cwv.z * S[(tt + 2) * 256 + tid]
                       + cwv.y * S[(tt + 1) * 256 + tid] + cwv.x * S[tt * 256 + tid];
        acc[tt] = v / (1.f + __expf(-v));   // SiLU
      }
      if (c < INTER_) {
        const int h = c >> 6, hd = c & 63;
        const long chb = (long)(h * B_ + b) * T_;
        float qv[16];
        #pragma unroll
        for (int qq = 0; qq < 4; qq++) {
          float4 q4 = *(const float4*)(a.qT + chb + t0 + qq * 4);
          qv[qq*4+0] = q4.x; qv[qq*4+1] = q4.y; qv[qq*4+2] = q4.z; qv[qq*4+3] = q4.w;
        }
        const long base = ((long)(b * NH_ + h) * HD_ + hd) * T_ + (t0 & ~63);
        const int g = (t0 >> 5) & 1, h2 = (t0 >> 4) & 1, sw = hd & 7;
        #pragma unroll
        for (int aa = 0; aa < 4; aa++) {
          short4_t xr, xq;
          #pragma unroll
          for (int r = 0; r < 4; r++) {
            xr[r] = f2bf(acc[aa * 4 + r]);
            xq[r] = f2bf(acc[aa * 4 + r] * qv[aa * 4 + r]);
          }
          const int off = (((g * 4 + aa) ^ sw) * 8) + h2 * 4;
          *(short4_t*)(a.xTr + base + off) = xr;
          *(short4_t*)(a.xTq + base + off) = xq;
        }
      } else {
        const int ch0 = c - INTER_;
        const bool isB = ch0 < NS_;
        const int k = isB ? ch0 : ch0 - NS_;
        const int k32 = k & 31;
        const int Pp = (k & ~31) + 8 * ((k32 >> 2) & 3) + 4 * (k32 >> 4) + (k32 & 3);
        short* dst = isB ? a.Bh : a.Chh;
        #pragma unroll
        for (int tt = 0; tt < 16; tt++) {
          const long bt = (long)b * T_ + t0 + tt;
          dst[bt * NS_ + Pp] = f2bf(acc[tt]);
        }
      }
    }
  }
  grid_bar(a.bar, 512u * 3);

  // ---------------- phase 3: CB GEMM (single-phase K=128, lower-tri, swizzled bf16 out) --------
  {
    const int x = bid & 15, y = (bid >> 4) & 15, b = bid >> 8;
    if (x <= y) {
      constexpr int PSZ = 64 * 32;
      short* As = (short*)SMEM;                 // 4*PSZ = 16KB
      short* Bs = (short*)SMEM + 4 * PSZ;       // 16KB
      const short* Chh = a.Chh + (long)b * T_ * NS_;
      const short* Bhp = a.Bh + (long)b * T_ * NS_;
      short* CBhp = a.CBh + (long)b * T_ * T_;
      const int m0 = y * 64, n0 = x * 64;
      const int srow = lane >> 2;
      const int sc3 = (lane & 3) * 8;
      {
        const int row = w * 16 + srow;
        #pragma unroll
        for (int kg = 0; kg < 4; kg++) {
          gl_lds16(Chh + (long)(m0 + row) * NS_ + kg * 32 + sc3, As + kg * PSZ + w * 512);
          gl_lds16(Bhp + (long)(n0 + row) * NS_ + kg * 32 + sc3, Bs + kg * PSZ + w * 512);
        }
      }
      __syncthreads();
      float4_t acc[2][2] = {};
      #pragma unroll
      for (int kg = 0; kg < 4; kg++) {
        const short* Ab = As + kg * PSZ;
        const short* Bb = Bs + kg * PSZ;
        short8_t af[2], bf[2];
        #pragma unroll
        for (int m = 0; m < 2; m++) af[m] = ldfrag(Ab, wr * 32 + m * 16 + lr, lg);
        #pragma unroll
        for (int n = 0; n < 2; n++) bf[n] = ldfrag(Bb, wc * 32 + n * 16 + lr, lg);
        #pragma unroll
        for (int m = 0; m < 2; m++)
          #pragma unroll
          for (int n = 0; n < 2; n++)
            acc[m][n] = __builtin_amdgcn_mfma_f32_16x16x32_bf16(af[m], bf[n], acc[m][n], 0, 0, 0);
      }
      #pragma unroll
      for (int m = 0; m < 2; m++)
        #pragma unroll
        for (int n = 0; n < 2; n++)
          #pragma unroll
          for (int r = 0; r < 4; r++) {
            const int row = m0 + wr * 32 + m * 16 + lg * 4 + r;
            const int sl = wc * 32 + n * 16 + lr;
            const int g = sl >> 5, k32 = sl & 31;
            const int cc = g * 4 + ((k32 >> 2) & 3);
            const int off = ((cc ^ (row & 7)) * 8) + 4 * (k32 >> 4) + (k32 & 3);
            CBhp[(long)row * T_ + n0 + off] = f2bf(acc[m][n][r]);
          }
    }
  }
  grid_bar(a.bar, 512u * 4);

  // ---------------- phase 4: MFMA attention (snake-paired units, D*x folded epilogue) ----------
  {
    short* CBl = (short*)SMEM;                               // [2][4096]
    short* Xl  = (short*)SMEM + 8192;                        // [2][4096]
    float (*lamS)[17] = (float (*)[17])((short*)SMEM + 16384);
    #pragma unroll 1
    for (int pass = 0; pass < 2; pass++) {
      const int u = pass ? (1023 - bid) : bid;
      if (u < NH_ * 16 * B_) {
        const int ttrank = u / 48, rem = u - ttrank * 48;
        const int h = rem >> 1, b = rem & 1;
        const int tt = 15 - ttrank;
        const int t0 = tt * 64;
        __syncthreads();   // guard LDS reuse from previous unit/phase
        for (int f = tid; f < 64 * NLVL_; f += 256) {
          int r = f / NLVL_, l = f - r * NLVL_;
          lamS[r][l] = softplus_f(
              bf2f(a.projh[((long)b * T_ + t0 + r) * P_ + INTER_ + CONV_DIM_ + NH_ + h * NLVL_ + l]))
              * a.Lw[h * NLVL_ + l];
        }
        const int tl = w * 16 + lr;
        const int t  = t0 + tl;
        const int orow = w * 16 + lg * 4;
        const long chb = (long)(h * B_ + b) * T_;
        const float catv = a.cAT[chb + t];
        float cao[4];
        #pragma unroll
        for (int r = 0; r < 4; r++) cao[r] = a.cAT[chb + t0 + orow + r];
        const short* xbr = a.xTr + (long)(b * NH_ + h) * HD_ * T_;
        const short* xbq = a.xTq + (long)(b * NH_ + h) * HD_ * T_;
        const short* CBbase = a.CBh + (long)b * T_ * T_ + (long)t0 * T_;
        const int srow2 = w * 16 + (lane >> 3);
        const int sch = (lane & 7) * 8;

        auto stage = [&](int buf, int st) {
          const int s0 = st * 64;
          const short* xsrc = (st == tt) ? xbr : xbq;
          #pragma unroll
          for (int i = 0; i < 2; i++) {
            gl_lds16(CBbase + (long)(srow2 + i * 8) * T_ + s0 + sch,
                     CBl + buf * 4096 + (w * 16 + i * 8) * 64);
            gl_lds16(xsrc + (long)(srow2 + i * 8) * T_ + s0 + sch,
                     Xl + buf * 4096 + (w * 16 + i * 8) * 64);
          }
        };

        float4_t acc[4] = {};
        int cur = 0;
        stage(0, 0);
        for (int st = 0; st <= tt; st++) {
          __syncthreads();
          if (st < tt) stage(cur ^ 1, st + 1);
          const int s0 = st * 64;
          if (st < tt) {
            const float caE = a.cAT[chb + s0 + 63];
            const int lev = 32 - __clz(t0 ^ s0);
            float k1o[4];
            #pragma unroll
            for (int r = 0; r < 4; r++)
              k1o[r] = __expf(cao[r] - caE) * lamS[orow + r][lev];
            float4_t dtile[4] = {};
            __builtin_amdgcn_s_setprio(1);
            #pragma unroll
            for (int kk = 0; kk < 2; kk++) {
              short8_t af = ldfrag64(CBl + cur * 4096, tl, kk, lg);
              #pragma unroll
              for (int n = 0; n < 4; n++) {
                short8_t bfv = ldfrag64(Xl + cur * 4096, n * 16 + lr, kk, lg);
                dtile[n] = __builtin_amdgcn_mfma_f32_16x16x32_bf16(af, bfv, dtile[n], 0, 0, 0);
              }
            }
            __builtin_amdgcn_s_setprio(0);
            #pragma unroll
            for (int n = 0; n < 4; n++)
              #pragma unroll
              for (int r = 0; r < 4; r++)
                acc[n][r] = fmaf(k1o[r], dtile[n][r], acc[n][r]);
          } else {
            #pragma unroll
            for (int kk = 0; kk < 2; kk++) {
              short8_t cb8 = ldfrag64(CBl + cur * 4096, tl, kk, lg);
              short8_t af;
              #pragma unroll
              for (int g = 0; g < 2; g++) {
                const int sb = s0 + kk * 32 + g * 16 + lg * 4;
                float4_t ca4 = *(const float4_t*)(a.cAT + chb + sb);
                float4_t dt4 = *(const float4_t*)(a.dtT + chb + sb);
                #pragma unroll
                for (int aa = 0; aa < 4; aa++) {
                  const int sg = sb + aa;
                  float m = 0.f;
                  if (sg <= t) {
                    const int xo = t ^ sg;
                    const int lev2 = xo ? (32 - __clz(xo)) : 0;
                    m = bf2f(cb8[g * 4 + aa]) * __expf(catv - ca4[aa]) * lamS[tl][lev2] * dt4[aa];
                  }
                  af[g * 4 + aa] = f2bf(m);
                }
              }
              __builtin_amdgcn_s_setprio(1);
              #pragma unroll
              for (int n = 0; n < 4; n++) {
                short8_t bfv = ldfrag64(Xl + cur * 4096, n * 16 + lr, kk, lg);
                acc[n] = __builtin_amdgcn_mfma_f32_16x16x32_bf16(af, bfv, acc[n], 0, 0, 0);
              }
              __builtin_amdgcn_s_setprio(0);
            }
          }
          cur ^= 1;
        }

        // epilogue: y + D*x -> bf16 (x tile still in Xl[cur^1])
        const float Dh = a.Dv[h];
        const short* Xd = Xl + (cur ^ 1) * 4096;
        #pragma unroll
        for (int n = 0; n < 4; n++) {
          #pragma unroll
          for (int r = 0; r < 4; r++) {
            const int trow = t0 + orow + r;
            const int hd = n * 16 + lr;
            const int xoff = hd * 64 + ((((w >> 1) * 4 + lg) ^ (hd & 7)) * 8) + (w & 1) * 4 + r;
            const float xv = bf2f(Xd[xoff]);
            a.ybh[((long)b * T_ + trow) * INTER_ + h * HD_ + hd] = f2bf(acc[n][r] + Dh * xv);
          }
        }
      }
    }
  }
  grid_bar(a.bar, 512u * 5);

  // ---------------- phase 5: gate * SiLU + RMSNorm -> bf16 permuted (4 rows/block) -------------
  {
    float* part = (float*)SMEM;
    const int i = tid;
    const int lo = (i >> 2) * 32 + (i & 3) * 4;
    const int hi = lo + 16;
    #pragma unroll 1
    for (int rr = 0; rr < 4; rr++) {
      const long bt = (long)bid * 4 + rr;
      float v[8];
      float ss = 0.f;
      if (i < 192) {
        const short* gp = a.projh + bt * P_;
        const short* yp = a.ybh + bt * INTER_;
        short4_t g0 = *(const short4_t*)(gp + lo);
        short4_t g1 = *(const short4_t*)(gp + hi);
        short4_t y0 = *(const short4_t*)(yp + lo);
        short4_t y1 = *(const short4_t*)(yp + hi);
        float ga[8] = {bf2f(g0[0]), bf2f(g0[1]), bf2f(g0[2]), bf2f(g0[3]),
                       bf2f(g1[0]), bf2f(g1[1]), bf2f(g1[2]), bf2f(g1[3])};
        float ya[8] = {bf2f(y0[0]), bf2f(y0[1]), bf2f(y0[2]), bf2f(y0[3]),
                       bf2f(y1[0]), bf2f(y1[1]), bf2f(y1[2]), bf2f(y1[3])};
        #pragma unroll
        for (int j = 0; j < 8; j++) {
          float val = ya[j] * (ga[j] / (1.f + __expf(-ga[j])));
          v[j] = val;
          ss += val * val;
        }
      }
      #pragma unroll
      for (int sof = 32; sof > 0; sof >>= 1) ss += __shfl_xor(ss, sof);
      __syncthreads();   // guard part[] reuse
      if ((i & 63) == 0 && i < 192) part[i >> 6] = ss;
      __syncthreads();
      if (i < 192) {
        const float tot = part[0] + part[1] + part[2];
        const float r2 = rsqrtf(tot * (1.f / INTER_) + EPS_);
        short8_t o;
        #pragma unroll
        for (int j = 0; j < 8; j++) {
          const int idx = (j < 4) ? (lo + j) : (hi + j - 4);
          o[j] = f2bf(v[j] * r2 * a.nw[idx]);
        }
        *(short8_t*)(a.ynrmb + bt * INTER_ + i * 8) = o;
      }
    }
  }
  grid_bar(a.bar, 512u * 6);

  // ---------------- phase 6: out-proj GEMM (64x64, BK=128) -> fp32 out ----------------
  {
    if (bid < 384) {
      constexpr int PSZ = 64 * 32;
      constexpr int BKG = 4;
      constexpr int BUF = PSZ * BKG;    // 8192 shorts per matrix per buffer
      constexpr int N = HID_, K = INTER_;
      short* As = (short*)SMEM;                 // 2*BUF = 32KB
      short* Bs = (short*)SMEM + 2 * BUF;       // 32KB
      const int m0 = (bid / 12) * 64, n0 = (bid % 12) * 64;
      const int srow = lane >> 2;
      const int sc6 = (lane & 3) * 8;
      const short* A = a.ynrmb;
      const short* Bm = a.wobf;

      auto stage = [&](int buf, int k0) {
        const int row = w * 16 + srow;
        #pragma unroll
        for (int kg = 0; kg < BKG; kg++) {
          gl_lds16(A + (long)(m0 + row) * K + k0 + kg * 32 + sc6, As + buf * BUF + kg * PSZ + w * 512);
          gl_lds16(Bm + (long)(n0 + row) * K + k0 + kg * 32 + sc6, Bs + buf * BUF + kg * PSZ + w * 512);
        }
      };

      float4_t acc[2][2] = {};
      int cur = 0;
      stage(0, 0);
      for (int k0 = 0; k0 < K; k0 += 128) {
        __syncthreads();
        if (k0 + 128 < K) stage(cur ^ 1, k0 + 128);
        #pragma unroll
        for (int kg = 0; kg < BKG; kg++) {
          const short* Ab = As + cur * BUF + kg * PSZ;
          const short* Bb = Bs + cur * BUF + kg * PSZ;
          short8_t af[2], bf[2];
          #pragma unroll
          for (int m = 0; m < 2; m++) af[m] = ldfrag(Ab, wr * 32 + m * 16 + lr, lg);
          #pragma unroll
          for (int n = 0; n < 2; n++) bf[n] = ldfrag(Bb, wc * 32 + n * 16 + lr, lg);
          #pragma unroll
          for (int m = 0; m < 2; m++)
            #pragma unroll
            for (int n = 0; n < 2; n++)
              acc[m][n] = __builtin_amdgcn_mfma_f32_16x16x32_bf16(af[m], bf[n], acc[m][n], 0, 0, 0);
        }
        cur ^= 1;
      }
      #pragma unroll
      for (int m = 0; m < 2; m++)
        #pragma unroll
        for (int n = 0; n < 2; n++)
          #pragma unroll
          for (int r = 0; r < 4; r++) {
            const int row = m0 + wr * 32 + m * 16 + lg * 4 + r;
            const int col = n0 + wc * 32 + n * 16 + lr;
            a.out[(long)row * N + col] = acc[m][n][r];
          }
    }
  }
}

// =====================================================================================
// FALLBACK: original 7-kernel pipeline (used if cooperative launch is rejected)
// =====================================================================================

__global__ __launch_bounds__(256) void cvtdt_k(
    const float* __restrict__ hs, const float* __restrict__ Win, const float* __restrict__ Wout,
    short* __restrict__ hsbf, short* __restrict__ wibf, short* __restrict__ wobf,
    float* __restrict__ dtraw, int ncvt)
{
  const long na = (long)B_ * T_ * HID_, nb = (long)P_ * HID_, nc = (long)HID_ * INTER_;
  if ((int)blockIdx.x < ncvt) {
    const long i = ((long)blockIdx.x * 256 + threadIdx.x) * 8;
    const float* src; short* dst; long off;
    if (i < na)           { src = hs;   dst = hsbf; off = i; }
    else if (i < na + nb) { src = Win;  dst = wibf; off = i - na; }
    else if (i < na + nb + nc) { src = Wout; dst = wobf; off = i - na - nb; }
    else return;
    const long base = (off & ~31L) + ((off >> 3) & 3) * 4;
    float4 v0 = *(const float4*)(src + base);
    float4 v1 = *(const float4*)(src + base + 16);
    short8_t o;
    o[0] = f2bf(v0.x); o[1] = f2bf(v0.y); o[2] = f2bf(v0.z); o[3] = f2bf(v0.w);
    o[4] = f2bf(v1.x); o[5] = f2bf(v1.y); o[6] = f2bf(v1.z); o[7] = f2bf(v1.w);
    *(short8_t*)(dst + off) = o;
  } else {
    const int rowbt = ((int)blockIdx.x - ncvt) * 4 + (threadIdx.x >> 6);
    const int lane = threadIdx.x & 63;
    float hv[12];
    const float* hrow = hs + (long)rowbt * HID_ + lane * 12;
    #pragma unroll
    for (int j = 0; j < 12; j++) hv[j] = hrow[j];
    const float* wbase = Win + (long)(INTER_ + CONV_DIM_) * HID_ + lane * 12;
    for (int h = 0; h < NH_; h++) {
      const float* wr = wbase + (long)h * HID_;
      float s = 0.f;
      #pragma unroll
      for (int j = 0; j < 12; j++) s = fmaf(hv[j], wr[j], s);
      #pragma unroll
      for (int off = 32; off; off >>= 1) s += __shfl_xor(s, off);
      if (lane == 0) dtraw[(long)rowbt * NH_ + h] = s;
    }
  }
}

__global__ __launch_bounds__(256) void inproj_scan_k(
    const short* __restrict__ A, const short* __restrict__ B, short* __restrict__ C,
    const float* __restrict__ dtraw, const float* __restrict__ dt_bias,
    const float* __restrict__ A_log, float* __restrict__ dtT, float* __restrict__ cAT,
    float* __restrict__ qT)
{
  constexpr int TM = 128, TN = 128, K = HID_, BK = 64;
  constexpr int PSZ = TM * 32;
  constexpr int ASZ = 2 * PSZ;
  __shared__ short As[2 * ASZ];
  __shared__ short Bs[2 * ASZ];

  if (blockIdx.y >= 16) {
    const int sid = ((int)blockIdx.y - 16) * 29 + (int)blockIdx.x;
    if (sid >= B_ * NH_) return;
    const int b = sid / NH_;
    const int h = sid % NH_;
    const float bias = dt_bias[h];
    const float Ah = -__expf(A_log[h]);
    const long ob = (long)(h * B_ + b) * T_;
    float* sc = (float*)As;
    float carry = 0.f;
    for (int c0 = 0; c0 < T_; c0 += 256) {
      const int t = c0 + threadIdx.x;
      const long bt = (long)b * T_ + t;
      float sp = softplus_f(dtraw[bt * NH_ + h] + bias);
      dtT[ob + t] = sp;
      sc[threadIdx.x] = sp * Ah;
      __syncthreads();
      for (int off = 1; off < 256; off <<= 1) {
        float add = (threadIdx.x >= off) ? sc[threadIdx.x - off] : 0.f;
        __syncthreads();
        sc[threadIdx.x] += add;
        __syncthreads();
      }
      cAT[ob + t] = carry + sc[threadIdx.x];
      qT[ob + t] = sp * __expf(sc[threadIdx.x | 63] - sc[threadIdx.x]);
      float tot = sc[255];
      __syncthreads();
      carry += tot;
    }
    return;
  }

  const int tid = threadIdx.x;
  const int w = tid >> 6, lane = tid & 63;
  const int lr = lane & 15, lg = lane >> 4;
  const int wr = w >> 1, wc = w & 1;
  const int m0 = blockIdx.y * TM, n0 = blockIdx.x * TN;
  const int srow = lane >> 2;
  const int sc2 = (lane & 3) * 8;

  auto stage = [&](int buf, int k0) {
    #pragma unroll
    for (int it = 0; it < 2; it++) {
      const int cb = w + 4 * it;
      const int row = cb * 16 + srow;
      #pragma unroll
      for (int kg = 0; kg < 2; kg++) {
        gl_lds16(A + (long)(m0 + row) * K + k0 + kg * 32 + sc2,
                 As + buf * ASZ + kg * PSZ + cb * 512);
        gl_lds16(B + (long)(n0 + row) * K + k0 + kg * 32 + sc2,
                 Bs + buf * ASZ + kg * PSZ + cb * 512);
      }
    }
  };

  float4_t acc[4][4] = {};
  int cur = 0;
  stage(0, 0);
  for (int k0 = 0; k0 < K; k0 += BK) {
    __syncthreads();
    if (k0 + BK < K) stage(cur ^ 1, k0 + BK);
    #pragma unroll
    for (int kg = 0; kg < 2; kg++) {
      const short* Ab = As + cur * ASZ + kg * PSZ;
      const short* Bb = Bs + cur * ASZ + kg * PSZ;
      short8_t af[4], bf[4];
      #pragma unroll
      for (int m = 0; m < 4; m++) af[m] = ldfrag(Ab, wr * 64 + m * 16 + lr, lg);
      #pragma unroll
      for (int n = 0; n < 4; n++) bf[n] = ldfrag(Bb, wc * 64 + n * 16 + lr, lg);
      #pragma unroll
      for (int m = 0; m < 4; m++)
        #pragma unroll
        for (int n = 0; n < 4; n++)
          acc[m][n] = __builtin_amdgcn_mfma_f32_16x16x32_bf16(af[m], bf[n], acc[m][n], 0, 0, 0);
    }
    cur ^= 1;
  }

  #pragma unroll
  for (int m = 0; m < 4; m++)
    #pragma unroll
    for (int n = 0; n < 4; n++)
      #pragma unroll
      for (int r = 0; r < 4; r++) {
        const int row = m0 + wr * 64 + m * 16 + lg * 4 + r;
        const int col = n0 + wc * 64 + n * 16 + lr;
        C[(long)row * P_ + col] = f2bf(acc[m][n][r]);
      }
}

__global__ __launch_bounds__(256) void gemm_out_k(
    const short* __restrict__ A, const short* __restrict__ B, float* __restrict__ C,
    int M, int N, int K)
{
  constexpr int PSZ = 64 * 32;
  constexpr int BKG = 4;
  constexpr int BUF = PSZ * BKG;
  __shared__ short As[2 * BUF];
  __shared__ short Bs[2 * BUF];
  const int tid = threadIdx.x;
  const int w = tid >> 6, lane = tid & 63;
  const int lr = lane & 15, lg = lane >> 4;
  const int wr = w >> 1, wc = w & 1;
  const int m0 = blockIdx.y * 64, n0 = blockIdx.x * 64;
  const int srow = lane >> 2;
  const int sc = (lane & 3) * 8;

  auto stage = [&](int buf, int k0) {
    const int row = w * 16 + srow;
    #pragma unroll
    for (int kg = 0; kg < BKG; kg++) {
      gl_lds16(A + (long)(m0 + row) * K + k0 + kg * 32 + sc, As + buf * BUF + kg * PSZ + w * 512);
      gl_lds16(B + (long)(n0 + row) * K + k0 + kg * 32 + sc, Bs + buf * BUF + kg * PSZ + w * 512);
    }
  };

  float4_t acc[2][2] = {};
  int cur = 0;
  stage(0, 0);
  for (int k0 = 0; k0 < K; k0 += 128) {
    __syncthreads();
    if (k0 + 128 < K) stage(cur ^ 1, k0 + 128);
    #pragma unroll
    for (int kg = 0; kg < BKG; kg++) {
      const short* Ab = As + cur * BUF + kg * PSZ;
      const short* Bb = Bs + cur * BUF + kg * PSZ;
      short8_t af[2], bf[2];
      #pragma unroll
      for (int m = 0; m < 2; m++) af[m] = ldfrag(Ab, wr * 32 + m * 16 + lr, lg);
      #pragma unroll
      for (int n = 0; n < 2; n++) bf[n] = ldfrag(Bb, wc * 32 + n * 16 + lr, lg);
      #pragma unroll
      for (int m = 0; m < 2; m++)
        #pragma unroll
        for (int n = 0; n < 2; n++)
          acc[m][n] = __builtin_amdgcn_mfma_f32_16x16x32_bf16(af[m], bf[n], acc[m][n], 0, 0, 0);
    }
    cur ^= 1;
  }

  #pragma unroll
  for (int m = 0; m < 2; m++)
    #pragma unroll
    for (int n = 0; n < 2; n++)
      #pragma unroll
      for (int r = 0; r < 4; r++) {
        const int row = m0 + wr * 32 + m * 16 + lg * 4 + r;
        const int col = n0 + wc * 32 + n * 16 + lr;
        C[(long)row * N + col] = acc[m][n][r];
      }
}

__global__ __launch_bounds__(256) void gemm_cbh_k(
    const short* __restrict__ Chh, const short* __restrict__ Bh, short* __restrict__ CBh)
{
  if (blockIdx.x > blockIdx.y) return;
  Chh += (long)blockIdx.z * T_ * NS_;
  Bh  += (long)blockIdx.z * T_ * NS_;
  CBh += (long)blockIdx.z * T_ * T_;
  constexpr int PSZ = 64 * 32;
  __shared__ short As[4 * PSZ];
  __shared__ short Bs[4 * PSZ];
  const int tid = threadIdx.x;
  const int w = tid >> 6, lane = tid & 63;
  const int lr = lane & 15, lg = lane >> 4;
  const int wr = w >> 1, wc = w & 1;
  const int m0 = blockIdx.y * 64, n0 = blockIdx.x * 64;
  const int srow = lane >> 2;
  const int sc = (lane & 3) * 8;

  {
    const int row = w * 16 + srow;
    #pragma unroll
    for (int kg = 0; kg < 4; kg++) {
      gl_lds16(Chh + (long)(m0 + row) * NS_ + kg * 32 + sc, As + kg * PSZ + w * 512);
      gl_lds16(Bh  + (long)(n0 + row) * NS_ + kg * 32 + sc, Bs + kg * PSZ + w * 512);
    }
  }
  __syncthreads();

  float4_t acc[2][2] = {};
  #pragma unroll
  for (int kg = 0; kg < 4; kg++) {
    const short* Ab = As + kg * PSZ;
    const short* Bb = Bs + kg * PSZ;
    short8_t af[2], bf[2];
    #pragma unroll
    for (int m = 0; m < 2; m++) af[m] = ldfrag(Ab, wr * 32 + m * 16 + lr, lg);
    #pragma unroll
    for (int n = 0; n < 2; n++) bf[n] = ldfrag(Bb, wc * 32 + n * 16 + lr, lg);
    #pragma unroll
    for (int m = 0; m < 2; m++)
      #pragma unroll
      for (int n = 0; n < 2; n++)
        acc[m][n] = __builtin_amdgcn_mfma_f32_16x16x32_bf16(af[m], bf[n], acc[m][n], 0, 0, 0);
  }

  #pragma unroll
  for (int m = 0; m < 2; m++)
    #pragma unroll
    for (int n = 0; n < 2; n++)
      #pragma unroll
      for (int r = 0; r < 4; r++) {
        const int row = m0 + wr * 32 + m * 16 + lg * 4 + r;
        const int sl = wc * 32 + n * 16 + lr;
        const int g = sl >> 5, k32 = sl & 31;
        const int cc = g * 4 + ((k32 >> 2) & 3);
        const int off = ((cc ^ (row & 7)) * 8) + 4 * (k32 >> 4) + (k32 & 3);
        CBh[(long)row * T_ + n0 + off] = f2bf(acc[m][n][r]);
      }
}

__global__ __launch_bounds__(256) void conv_silu_k(
    const short* __restrict__ projh, const float* __restrict__ cw, const float* __restrict__ cbias,
    const float* __restrict__ qT,
    short* __restrict__ xTr, short* __restrict__ xTq,
    short* __restrict__ Bh, short* __restrict__ Chh)
{
  const int c0 = blockIdx.x * 256;
  const int t0 = blockIdx.y * 16;
  const int b  = blockIdx.z;
  const int tid = threadIdx.x;
  __shared__ float S[19][256];
  #pragma unroll
  for (int r = 0; r < 19; r++) {
    const int t = t0 - 3 + r;
    S[r][tid] = (t >= 0) ? bf2f(projh[((long)b * T_ + t) * P_ + INTER_ + c0 + tid]) : 0.f;
  }
  __syncthreads();
  const int c = c0 + tid;
  const float4 w = *(const float4*)(cw + c * 4);
  const float bias = cbias[c];
  float acc[16];
  #pragma unroll
  for (int tt = 0; tt < 16; tt++) {
    float a = bias + w.w * S[tt + 3][tid] + w.z * S[tt + 2][tid]
                   + w.y * S[tt + 1][tid] + w.x * S[tt][tid];
    acc[tt] = a / (1.f + __expf(-a));
  }
  if (c < INTER_) {
    const int h = c >> 6, hd = c & 63;
    const long chb = (long)(h * B_ + b) * T_;
    float qv[16];
    #pragma unroll
    for (int qq = 0; qq < 4; qq++) {
      float4 q4 = *(const float4*)(qT + chb + t0 + qq * 4);
      qv[qq*4+0] = q4.x; qv[qq*4+1] = q4.y; qv[qq*4+2] = q4.z; qv[qq*4+3] = q4.w;
    }
    const long base = ((long)(b * NH_ + h) * HD_ + hd) * T_ + (t0 & ~63);
    const int g = (t0 >> 5) & 1, h2 = (t0 >> 4) & 1, sw = hd & 7;
    #pragma unroll
    for (int a = 0; a < 4; a++) {
      short4_t xr, xq;
      #pragma unroll
      for (int r = 0; r < 4; r++) {
        xr[r] = f2bf(acc[a * 4 + r]);
        xq[r] = f2bf(acc[a * 4 + r] * qv[a * 4 + r]);
      }
      const int off = (((g * 4 + a) ^ sw) * 8) + h2 * 4;
      *(short4_t*)(xTr + base + off) = xr;
      *(short4_t*)(xTq + base + off) = xq;
    }
  } else {
    const int ch0 = c - INTER_;
    const bool isB = ch0 < NS_;
    const int k = isB ? ch0 : ch0 - NS_;
    const int k32 = k & 31;
    const int P = (k & ~31) + 8 * ((k32 >> 2) & 3) + 4 * (k32 >> 4) + (k32 & 3);
    short* dst = isB ? Bh : Chh;
    #pragma unroll
    for (int tt = 0; tt < 16; tt++) {
      const long bt = (long)b * T_ + t0 + tt;
      dst[bt * NS_ + P] = f2bf(acc[tt]);
    }
  }
}

__global__ __launch_bounds__(256) void attn_mfma3_k(
    const short* __restrict__ xTr, const short* __restrict__ xTq,
    const short* __restrict__ CBh,
    const float* __restrict__ cAT, const float* __restrict__ dtT,
    const short* __restrict__ projh, const float* __restrict__ Lw,
    const float* __restrict__ Dv,
    short* __restrict__ ybh)
{
  const int h = blockIdx.x;
  const int tt = (T_ / 64 - 1) - blockIdx.y;
  const int b = blockIdx.z;
  const int t0 = tt * 64;
  const int tid = threadIdx.x;
  const int w = tid >> 6, lane = tid & 63;
  const int lr = lane & 15, lg = lane >> 4;

  __shared__ short CBl[2][64 * 64];
  __shared__ short Xl[2][64 * 64];
  __shared__ float lamS[64][17];

  for (int f = tid; f < 64 * NLVL_; f += 256) {
    int r = f / NLVL_, l = f - r * NLVL_;
    lamS[r][l] = softplus_f(
        bf2f(projh[((long)b * T_ + t0 + r) * P_ + INTER_ + CONV_DIM_ + NH_ + h * NLVL_ + l]))
        * Lw[h * NLVL_ + l];
  }

  const int tl = w * 16 + lr;
  const int t  = t0 + tl;
  const int orow = w * 16 + lg * 4;
  const long chb = (long)(h * B_ + b) * T_;
  const float catv = cAT[chb + t];
  float cao[4];
  #pragma unroll
  for (int r = 0; r < 4; r++) cao[r] = cAT[chb + t0 + orow + r];

  const short* xbr = xTr + (long)(b * NH_ + h) * HD_ * T_;
  const short* xbq = xTq + (long)(b * NH_ + h) * HD_ * T_;
  const short* CBbase = CBh + (long)b * T_ * T_ + (long)t0 * T_;

  const int srow = w * 16 + (lane >> 3);
  const int sch = (lane & 7) * 8;

  auto stage = [&](int buf, int st) {
    const int s0 = st * 64;
    const short* xsrc = (st == tt) ? xbr : xbq;
    #pragma unroll
    for (int i = 0; i < 2; i++) {
      gl_lds16(CBbase + (long)(srow + i * 8) * T_ + s0 + sch, &CBl[buf][(w * 16 + i * 8) * 64]);
      gl_lds16(xsrc + (long)(srow + i * 8) * T_ + s0 + sch, &Xl[buf][(w * 16 + i * 8) * 64]);
    }
  };

  float4_t acc[4] = {};
  int cur = 0;
  stage(0, 0);
  for (int st = 0; st <= tt; st++) {
    __syncthreads();
    if (st < tt) stage(cur ^ 1, st + 1);
    const int s0 = st * 64;
    if (st < tt) {
      const float caE = cAT[chb + s0 + 63];
      const int lev = 32 - __clz(t0 ^ s0);
      float k1o[4];
      #pragma unroll
      for (int r = 0; r < 4; r++)
        k1o[r] = __expf(cao[r] - caE) * lamS[orow + r][lev];
      float4_t dtile[4] = {};
      __builtin_amdgcn_s_setprio(1);
      #pragma unroll
      for (int kk = 0; kk < 2; kk++) {
        short8_t af = ldfrag64(CBl[cur], tl, kk, lg);
        #pragma unroll
        for (int n = 0; n < 4; n++) {
          short8_t bfv = ldfrag64(Xl[cur], n * 16 + lr, kk, lg);
          dtile[n] = __builtin_amdgcn_mfma_f32_16x16x32_bf16(af, bfv, dtile[n], 0, 0, 0);
        }
      }
      __builtin_amdgcn_s_setprio(0);
      #pragma unroll
      for (int n = 0; n < 4; n++)
        #pragma unroll
        for (int r = 0; r < 4; r++)
          acc[n][r] = fmaf(k1o[r], dtile[n][r], acc[n][r]);
    } else {
      #pragma unroll
      for (int kk = 0; kk < 2; kk++) {
        short8_t cb8 = ldfrag64(CBl[cur], tl, kk, lg);
        short8_t af;
        #pragma unroll
        for (int g = 0; g < 2; g++) {
          const int sb = s0 + kk * 32 + g * 16 + lg * 4;
          float4_t ca4 = *(const float4_t*)(cAT + chb + sb);
          float4_t dt4 = *(const float4_t*)(dtT + chb + sb);
          #pragma unroll
          for (int a = 0; a < 4; a++) {
            const int sg = sb + a;
            float m = 0.f;
            if (sg <= t) {
              const int xo = t ^ sg;
              const int lev2 = xo ? (32 - __clz(xo)) : 0;
              m = bf2f(cb8[g * 4 + a]) * __expf(catv - ca4[a]) * lamS[tl][lev2] * dt4[a];
            }
            af[g * 4 + a] = f2bf(m);
          }
        }
        __builtin_amdgcn_s_setprio(1);
        #pragma unroll
        for (int n = 0; n < 4; n++) {
          short8_t bfv = ldfrag64(Xl[cur], n * 16 + lr, kk, lg);
          acc[n] = __builtin_amdgcn_mfma_f32_16x16x32_bf16(af, bfv, acc[n], 0, 0, 0);
        }
        __builtin_amdgcn_s_setprio(0);
      }
    }
    cur ^= 1;
  }

  const float Dh = Dv[h];
  const short* Xd = Xl[cur ^ 1];
  #pragma unroll
  for (int n = 0; n < 4; n++) {
    #pragma unroll
    for (int r = 0; r < 4; r++) {
      const int trow = t0 + orow + r;
      const int hd = n * 16 + lr;
      const int xoff = hd * 64 + ((((w >> 1) * 4 + lg) ^ (hd & 7)) * 8) + (w & 1) * 4 + r;
      const float xv = bf2f(Xd[xoff]);
      ybh[((long)b * T_ + trow) * INTER_ + h * HD_ + hd] = f2bf(acc[n][r] + Dh * xv);
    }
  }
}

__global__ __launch_bounds__(192) void gate_rms_k(
    const short* __restrict__ ybh, const short* __restrict__ projh,
    const float* __restrict__ nw, short* __restrict__ ynorm)
{
  const long bt = blockIdx.x;
  const short* gp = projh + bt * P_;
  const short* yp = ybh + bt * INTER_;
  const int i = threadIdx.x;
  const int lo = (i >> 2) * 32 + (i & 3) * 4;
  const int hi = lo + 16;
  float v[8];
  float ss = 0.f;
  {
    short4_t g0 = *(const short4_t*)(gp + lo);
    short4_t g1 = *(const short4_t*)(gp + hi);
    short4_t y0 = *(const short4_t*)(yp + lo);
    short4_t y1 = *(const short4_t*)(yp + hi);
    float ga[8] = {bf2f(g0[0]), bf2f(g0[1]), bf2f(g0[2]), bf2f(g0[3]),
                   bf2f(g1[0]), bf2f(g1[1]), bf2f(g1[2]), bf2f(g1[3])};
    float ya[8] = {bf2f(y0[0]), bf2f(y0[1]), bf2f(y0[2]), bf2f(y0[3]),
                   bf2f(y1[0]), bf2f(y1[1]), bf2f(y1[2]), bf2f(y1[3])};
    #pragma unroll
    for (int j = 0; j < 8; j++) {
      float val = ya[j] * (ga[j] / (1.f + __expf(-ga[j])));
      v[j] = val;
      ss += val * val;
    }
  }
  #pragma unroll
  for (int off = 32; off > 0; off >>= 1) ss += __shfl_xor(ss, off);
  __shared__ float part[3];
  if ((i & 63) == 0) part[i >> 6] = ss;
  __syncthreads();
  const float tot = part[0] + part[1] + part[2];
  const float r = rsqrtf(tot * (1.f / INTER_) + EPS_);
  short8_t o;
  #pragma unroll
  for (int j = 0; j < 8; j++) {
    const int idx = (j < 4) ? (lo + j) : (hi + j - 4);
    o[j] = f2bf(v[j] * r * nw[idx]);
  }
  *(short8_t*)(ynorm + bt * INTER_ + i * 8) = o;
}

extern "C" void kernel_launch(void* const* d_in, const int* in_sizes, int n_in,
                              void* d_out, int out_size, void* d_ws, size_t ws_size,
                              hipStream_t stream) {
  const float* hs   = (const float*)d_in[0];
  const float* Win  = (const float*)d_in[1];
  const float* cw   = (const float*)d_in[2];
  const float* cb   = (const float*)d_in[3];
  const float* dtb  = (const float*)d_in[4];
  const float* Alog = (const float*)d_in[5];
  const float* Lw   = (const float*)d_in[6];
  const float* Dv   = (const float*)d_in[7];
  const float* nw   = (const float*)d_in[8];
  const float* Wout = (const float*)d_in[9];
  float* out = (float*)d_out;

  const long n_hs = (long)B_ * T_ * HID_;
  const long n_wi = (long)P_ * HID_;
  const long n_wo = (long)HID_ * INTER_;

  float* ws = (float*)d_ws;
  long o = 0;
  float* projreg = ws + o; o += (long)B_ * T_ * P_ / 2 + 16;
  short* xbf   = (short*)(ws + o); o += (long)B_ * T_ * INTER_ / 2;  // (slot retained, unused)
  short* Bh    = (short*)(ws + o); o += (long)B_ * T_ * NS_ / 2;
  short* Chh   = (short*)(ws + o); o += (long)B_ * T_ * NS_ / 2;
  float* dtT   = ws + o; o += (long)B_ * T_ * NH_;
  float* cAT   = ws + o; o += (long)B_ * T_ * NH_;
  float* qT    = ws + o; o += (long)B_ * T_ * NH_;
  float* dtraw = ws + o; o += (long)B_ * T_ * NH_;
  short* CBh   = (short*)(ws + o); o += (long)B_ * T_ * T_ / 2;
  short* ybh   = (short*)(ws + o); o += (long)B_ * T_ * INTER_ / 2;
  float* yxreg = ws + o; o += (long)B_ * T_ * INTER_ / 2;
  short* hsbf  = (short*)(ws + o); o += n_hs / 2;
  short* wibf  = (short*)(ws + o); o += n_wi / 2;
  short* wobf  = (short*)(ws + o); o += n_wo / 2;
  unsigned* bar = (unsigned*)(ws + o); o += 64;
  short* projh = (short*)projreg;
  short* xTr   = (short*)yxreg;
  short* ynrmb = (short*)yxreg;
  short* xTq   = hsbf;
  (void)xbf;

  // zero the barrier counter (workspace is poisoned each reset)
  hipMemsetAsync(bar, 0, 64, stream);

  // ---- preferred path: single cooperative mega-kernel (512 blocks = 2/CU @ 64KB LDS) ----
  MegaArgs ma;
  ma.hs = hs; ma.Win = Win; ma.cw = cw; ma.cb = cb; ma.dtb = dtb; ma.Alog = Alog;
  ma.Lw = Lw; ma.Dv = Dv; ma.nw = nw; ma.Wout = Wout; ma.out = out;
  ma.hsbf = hsbf; ma.wibf = wibf; ma.wobf = wobf;
  ma.dtraw = dtraw; ma.dtT = dtT; ma.cAT = cAT; ma.qT = qT;
  ma.projh = projh; ma.xTr = xTr; ma.xTq = xTq; ma.Bh = Bh; ma.Chh = Chh;
  ma.CBh = CBh; ma.ybh = ybh; ma.ynrmb = ynrmb; ma.bar = bar;
  void* kargs[] = { (void*)&ma };
  hipError_t ce = hipLaunchCooperativeKernel(
      (const void*)mega_k, dim3(512), dim3(256), kargs, 0, stream);
  if (ce == hipSuccess) return;

  // ---- fallback: proven 7-kernel pipeline ----
  const int ncvt = (int)((n_hs + n_wi + n_wo) / 8 / 256);
  cvtdt_k<<<ncvt + (B_ * T_) / 4, 256, 0, stream>>>(
      hs, Win, Wout, hsbf, wibf, wobf, dtraw, ncvt);
  inproj_scan_k<<<dim3(P_ / 128, 18), 256, 0, stream>>>(
      hsbf, wibf, projh, dtraw, dtb, Alog, dtT, cAT, qT);
  conv_silu_k<<<dim3(CONV_DIM_ / 256, T_ / 16, B_), 256, 0, stream>>>(
      projh, cw, cb, qT, xTr, xTq, Bh, Chh);
  gemm_cbh_k<<<dim3(T_ / 64, T_ / 64, B_), 256, 0, stream>>>(Chh, Bh, CBh);
  attn_mfma3_k<<<dim3(NH_, T_ / 64, B_), 256, 0, stream>>>(
      xTr, xTq, CBh, cAT, dtT, projh, Lw, Dv, ybh);
  gate_rms_k<<<B_ * T_, 192, 0, stream>>>(ybh, projh, nw, ynrmb);
  gemm_out_k<<<dim3(HID_ / 64, (B_ * T_) / 64), 256, 0, stream>>>(
      ynrmb, wobf, out, B_ * T_, HID_, INTER_);
}

// Round 5
// 248.436 us; speedup vs baseline: 3.2711x; 1.6493x over previous
//
#include <hip/hip_runtime.h>
#include <hip/hip_bf16.h>
#include <math.h>

#define B_ 2
#define T_ 1024
#define HID_ 768
#define INTER_ 1536
#define NH_ 24
#define HD_ 64
#define NS_ 128
#define NLVL_ 15
#define CONV_DIM_ 1792
#define P_ 3712
#define EPS_ 1e-5f

typedef short short8_t __attribute__((ext_vector_type(8)));
typedef short short4_t __attribute__((ext_vector_type(4)));
typedef float float4_t __attribute__((ext_vector_type(4)));

// K-permutation (within each 32-element K-group): physical p = 8a + 4h + r for
// logical k = 16h + 4a + r. A lane's MFMA operand (k = lg*4+{0..3} and +16) is then
// ONE contiguous 16B chunk at p = 8*lg  ->  single ds_read_b128 per fragment.

__device__ __forceinline__ float softplus_f(float x) {
  return (x > 20.f) ? x : log1pf(__expf(x));
}
__device__ __forceinline__ short f2bf(float f) {
  union { float f; unsigned u; } v; v.f = f;
  unsigned r = v.u + 0x7FFF + ((v.u >> 16) & 1);   // RNE
  return (short)(r >> 16);
}
__device__ __forceinline__ float bf2f(short s) {
  union { unsigned u; float f; } v; v.u = ((unsigned)(unsigned short)s) << 16;
  return v.f;
}
__device__ __forceinline__ void gl_lds16(const void* g, void* l) {
  __builtin_amdgcn_global_load_lds(
      (const __attribute__((address_space(1))) unsigned int*)g,
      (__attribute__((address_space(3))) unsigned int*)l, 16, 0, 0);
}

// Slot-based hierarchical grid barrier (v3).
// R4's single fetch_add counter serialized 512 cross-XCD RMWs at one coherence
// point (~53us/barrier). Here: zero same-address RMW contention.
//   arrival : block RELEASE-stores phase p into its OWN slot arrive[bid]
//   group   : 8 master blocks (bid%64==0); master wave-0 polls its 64 slots in
//             parallel (1 lane/slot); RELEASE-stores garr[g] (128B-separated)
//   global  : masters poll all 8 garr slots with 8 lanes
//   release : master RELEASE-stores gflag[g]; group members spin (read-only),
//             exit with one ACQUIRE load (buffer_inv of this CU/XCD caches).
// Layout in bar[]: arrive[0..511], garr at 512+g*32, gflag at 768+g*32 (4KB).
__device__ __forceinline__ void grid_bar(unsigned* bar, unsigned p) {
  __syncthreads();
  const int bid = blockIdx.x;
  const int g = bid >> 6;
  const int sub = bid & 63;
  unsigned* garr  = bar + 512;
  unsigned* gflag = bar + 768;
  if (threadIdx.x < 64) {
    const int lane = threadIdx.x;
    if (lane == 0)
      __hip_atomic_store(&bar[bid], p, __ATOMIC_RELEASE, __HIP_MEMORY_SCOPE_AGENT);
    if (sub == 0) {                       // master block of group g
      for (;;) {
        unsigned v = __hip_atomic_load(&bar[g * 64 + lane], __ATOMIC_RELAXED,
                                       __HIP_MEMORY_SCOPE_AGENT);
        if (__all(v >= p)) break;
        __builtin_amdgcn_s_sleep(1);
      }
      if (lane == 0)
        __hip_atomic_store(&garr[g * 32], p, __ATOMIC_RELEASE, __HIP_MEMORY_SCOPE_AGENT);
      for (;;) {
        unsigned v = (lane < 8)
            ? __hip_atomic_load(&garr[lane * 32], __ATOMIC_RELAXED, __HIP_MEMORY_SCOPE_AGENT)
            : p;
        if (__all(v >= p)) break;
        __builtin_amdgcn_s_sleep(1);
      }
      if (lane == 0)
        __hip_atomic_store(&gflag[g * 32], p, __ATOMIC_RELEASE, __HIP_MEMORY_SCOPE_AGENT);
    }
    if (lane == 0) {
      while (__hip_atomic_load(&gflag[g * 32], __ATOMIC_RELAXED, __HIP_MEMORY_SCOPE_AGENT) < p)
        __builtin_amdgcn_s_sleep(2);
      (void)__hip_atomic_load(&gflag[g * 32], __ATOMIC_ACQUIRE, __HIP_MEMORY_SCOPE_AGENT);
    }
  }
  __syncthreads();
}

// Permuted LDS fragment read (BK-panel of 32 K): one b128 per fragment.
__device__ __forceinline__ short8_t ldfrag(const short* Ts, int row, int lg) {
  return *(const short8_t*)(Ts + row * 32 + lg * 8);
}

// Permuted+row-swizzled 64-wide fragment read (attn): one b128 per fragment.
__device__ __forceinline__ short8_t ldfrag64(const short* Ts, int row, int kk, int lg) {
  const int cc = (kk * 4 + lg) ^ (row & 7);
  return *(const short8_t*)(Ts + row * 64 + cc * 8);
}

// =====================================================================================
// MEGA KERNEL: whole pipeline, 512 blocks x 256 threads (2 blocks/CU @ 64KB LDS),
// phases separated by custom grid barrier. Eliminates 6 kernel-boundary gaps/drains.
// =====================================================================================
struct MegaArgs {
  const float *hs, *Win, *cw, *cb, *dtb, *Alog, *Lw, *Dv, *nw, *Wout;
  float *out;
  short *hsbf, *wibf, *wobf;
  float *dtraw, *dtT, *cAT, *qT;
  short *projh, *xTr, *xTq, *Bh, *Chh, *CBh, *ybh, *ynrmb;
  unsigned *bar;
};

__global__ __launch_bounds__(256, 2) void mega_k(MegaArgs a)
{
  const int bid = blockIdx.x;
  const int tid = threadIdx.x;
  const int w = tid >> 6, lane = tid & 63;
  const int lr = lane & 15, lg = lane >> 4;
  const int wr = w >> 1, wc = w & 1;
  __shared__ char SMEM[65536] __attribute__((aligned(16)));

  // ---------------- phase 0: f32->bf16 K-permuted cvt (hs/Win/Wout) + fp32 dt columns ----------
  {
    const long na = (long)B_ * T_ * HID_, nb = (long)P_ * HID_, nc = (long)HID_ * INTER_;
    const long tot8 = (na + nb + nc) / 8;
    for (long it = (long)bid * 256 + tid; it < tot8; it += 512L * 256) {
      const long i = it * 8;
      const float* src; short* dst; long off;
      if (i < na)           { src = a.hs;   dst = a.hsbf; off = i; }
      else if (i < na + nb) { src = a.Win;  dst = a.wibf; off = i - na; }
      else                  { src = a.Wout; dst = a.wobf; off = i - na - nb; }
      const long base = (off & ~31L) + ((off >> 3) & 3) * 4;
      float4 v0 = *(const float4*)(src + base);
      float4 v1 = *(const float4*)(src + base + 16);
      short8_t o;
      o[0] = f2bf(v0.x); o[1] = f2bf(v0.y); o[2] = f2bf(v0.z); o[3] = f2bf(v0.w);
      o[4] = f2bf(v1.x); o[5] = f2bf(v1.y); o[6] = f2bf(v1.z); o[7] = f2bf(v1.w);
      *(short8_t*)(dst + off) = o;
    }
    // dt GEMV: one bt-row per wave, 4 per block (512*4 = 2048)
    const int rowbt = bid * 4 + w;
    float hv[12];
    const float* hrow = a.hs + (long)rowbt * HID_ + lane * 12;
    #pragma unroll
    for (int j = 0; j < 12; j++) hv[j] = hrow[j];
    const float* wbase = a.Win + (long)(INTER_ + CONV_DIM_) * HID_ + lane * 12;
    for (int h = 0; h < NH_; h++) {
      const float* wrp = wbase + (long)h * HID_;
      float s = 0.f;
      #pragma unroll
      for (int j = 0; j < 12; j++) s = fmaf(hv[j], wrp[j], s);
      #pragma unroll
      for (int sof = 32; sof; sof >>= 1) s += __shfl_xor(s, sof);
      if (lane == 0) a.dtraw[(long)rowbt * NH_ + h] = s;
    }
  }
  grid_bar(a.bar, 1u);

  // ---------------- phase 1: in-proj GEMM (128x128, BK=64, bf16 out) + dt_scan ----------------
  {
    if (bid < 464) {
      constexpr int K = HID_, BK = 64;
      constexpr int PSZ = 128 * 32;     // 4096 shorts
      constexpr int ASZ = 2 * PSZ;      // per buffer: 8192 shorts
      short* As = (short*)SMEM;                 // 2*ASZ = 32KB
      short* Bs = (short*)SMEM + 2 * ASZ;       // 32KB
      const int by = bid / 29, bx = bid - by * 29;
      const int m0 = by * 128, n0 = bx * 128;
      const int srow = lane >> 2;
      const int sc2 = (lane & 3) * 8;
      const short* A = a.hsbf;
      const short* Bm = a.wibf;

      auto stage = [&](int buf, int k0) {
        #pragma unroll
        for (int it2 = 0; it2 < 2; it2++) {
          const int cb = w + 4 * it2;
          const int row = cb * 16 + srow;
          #pragma unroll
          for (int kg = 0; kg < 2; kg++) {
            gl_lds16(A + (long)(m0 + row) * K + k0 + kg * 32 + sc2,
                     As + buf * ASZ + kg * PSZ + cb * 512);
            gl_lds16(Bm + (long)(n0 + row) * K + k0 + kg * 32 + sc2,
                     Bs + buf * ASZ + kg * PSZ + cb * 512);
          }
        }
      };

      float4_t acc[4][4] = {};
      int cur = 0;
      stage(0, 0);
      for (int k0 = 0; k0 < K; k0 += BK) {
        __syncthreads();
        if (k0 + BK < K) stage(cur ^ 1, k0 + BK);
        #pragma unroll
        for (int kg = 0; kg < 2; kg++) {
          const short* Ab = As + cur * ASZ + kg * PSZ;
          const short* Bb = Bs + cur * ASZ + kg * PSZ;
          short8_t af[4], bf[4];
          #pragma unroll
          for (int m = 0; m < 4; m++) af[m] = ldfrag(Ab, wr * 64 + m * 16 + lr, lg);
          #pragma unroll
          for (int n = 0; n < 4; n++) bf[n] = ldfrag(Bb, wc * 64 + n * 16 + lr, lg);
          #pragma unroll
          for (int m = 0; m < 4; m++)
            #pragma unroll
            for (int n = 0; n < 4; n++)
              acc[m][n] = __builtin_amdgcn_mfma_f32_16x16x32_bf16(af[m], bf[n], acc[m][n], 0, 0, 0);
        }
        cur ^= 1;
      }
      #pragma unroll
      for (int m = 0; m < 4; m++)
        #pragma unroll
        for (int n = 0; n < 4; n++)
          #pragma unroll
          for (int r = 0; r < 4; r++) {
            const int row = m0 + wr * 64 + m * 16 + lg * 4 + r;
            const int col = n0 + wc * 64 + n * 16 + lr;
            a.projh[(long)row * P_ + col] = f2bf(acc[m][n][r]);
          }
    } else {
      const int sid = bid - 464;     // 0..47 == B_*NH_
      const int b = sid / NH_;
      const int h = sid % NH_;
      const float bias = a.dtb[h];
      const float Ah = -__expf(a.Alog[h]);
      const long ob = (long)(h * B_ + b) * T_;
      float* scn = (float*)SMEM;
      float carry = 0.f;
      for (int c0 = 0; c0 < T_; c0 += 256) {
        const int t = c0 + tid;
        const long bt = (long)b * T_ + t;
        float sp = softplus_f(a.dtraw[bt * NH_ + h] + bias);
        a.dtT[ob + t] = sp;
        scn[tid] = sp * Ah;
        __syncthreads();
        for (int off = 1; off < 256; off <<= 1) {
          float add = (tid >= off) ? scn[tid - off] : 0.f;
          __syncthreads();
          scn[tid] += add;
          __syncthreads();
        }
        a.cAT[ob + t] = carry + scn[tid];
        a.qT[ob + t] = sp * __expf(scn[tid | 63] - scn[tid]);
        float tot = scn[255];
        __syncthreads();
        carry += tot;
      }
    }
  }
  grid_bar(a.bar, 2u);

  // ---------------- phase 2: conv (K=4) + bias + SiLU + fused x-transpose; B/C permuted --------
  {
    float* S = (float*)SMEM;   // [19][256]
    #pragma unroll 1
    for (int u = bid; u < 7 * 64 * B_; u += 512) {
      const int cgi = u % 7;
      const int rest = u / 7;
      const int ty = rest % 64;
      const int b = rest / 64;
      const int c0 = cgi * 256, t0 = ty * 16;
      __syncthreads();   // guard LDS reuse across units/phases
      #pragma unroll
      for (int r = 0; r < 19; r++) {
        const int t = t0 - 3 + r;
        S[r * 256 + tid] = (t >= 0) ? bf2f(a.projh[((long)b * T_ + t) * P_ + INTER_ + c0 + tid]) : 0.f;
      }
      __syncthreads();
      const int c = c0 + tid;
      const float4 cwv = *(const float4*)(a.cw + c * 4);
      const float bias = a.cb[c];
      float acc[16];
      #pragma unroll
      for (int tt = 0; tt < 16; tt++) {
        float v = bias + cwv.w * S[(tt + 3) * 256 + tid] + cwv.z * S[(tt + 2) * 256 + tid]
                       + cwv.y * S[(tt + 1) * 256 + tid] + cwv.x * S[tt * 256 + tid];
        acc[tt] = v / (1.f + __expf(-v));   // SiLU
      }
      if (c < INTER_) {
        const int h = c >> 6, hd = c & 63;
        const long chb = (long)(h * B_ + b) * T_;
        float qv[16];
        #pragma unroll
        for (int qq = 0; qq < 4; qq++) {
          float4 q4 = *(const float4*)(a.qT + chb + t0 + qq * 4);
          qv[qq*4+0] = q4.x; qv[qq*4+1] = q4.y; qv[qq*4+2] = q4.z; qv[qq*4+3] = q4.w;
        }
        const long base = ((long)(b * NH_ + h) * HD_ + hd) * T_ + (t0 & ~63);
        const int g = (t0 >> 5) & 1, h2 = (t0 >> 4) & 1, sw = hd & 7;
        #pragma unroll
        for (int aa = 0; aa < 4; aa++) {
          short4_t xr, xq;
          #pragma unroll
          for (int r = 0; r < 4; r++) {
            xr[r] = f2bf(acc[aa * 4 + r]);
            xq[r] = f2bf(acc[aa * 4 + r] * qv[aa * 4 + r]);
          }
          const int off = (((g * 4 + aa) ^ sw) * 8) + h2 * 4;
          *(short4_t*)(a.xTr + base + off) = xr;
          *(short4_t*)(a.xTq + base + off) = xq;
        }
      } else {
        const int ch0 = c - INTER_;
        const bool isB = ch0 < NS_;
        const int k = isB ? ch0 : ch0 - NS_;
        const int k32 = k & 31;
        const int Pp = (k & ~31) + 8 * ((k32 >> 2) & 3) + 4 * (k32 >> 4) + (k32 & 3);
        short* dst = isB ? a.Bh : a.Chh;
        #pragma unroll
        for (int tt = 0; tt < 16; tt++) {
          const long bt = (long)b * T_ + t0 + tt;
          dst[bt * NS_ + Pp] = f2bf(acc[tt]);
        }
      }
    }
  }
  grid_bar(a.bar, 3u);

  // ---------------- phase 3: CB GEMM (single-phase K=128, lower-tri, swizzled bf16 out) --------
  {
    const int x = bid & 15, y = (bid >> 4) & 15, b = bid >> 8;
    if (x <= y) {
      constexpr int PSZ = 64 * 32;
      short* As = (short*)SMEM;                 // 4*PSZ = 16KB
      short* Bs = (short*)SMEM + 4 * PSZ;       // 16KB
      const short* Chh = a.Chh + (long)b * T_ * NS_;
      const short* Bhp = a.Bh + (long)b * T_ * NS_;
      short* CBhp = a.CBh + (long)b * T_ * T_;
      const int m0 = y * 64, n0 = x * 64;
      const int srow = lane >> 2;
      const int sc3 = (lane & 3) * 8;
      {
        const int row = w * 16 + srow;
        #pragma unroll
        for (int kg = 0; kg < 4; kg++) {
          gl_lds16(Chh + (long)(m0 + row) * NS_ + kg * 32 + sc3, As + kg * PSZ + w * 512);
          gl_lds16(Bhp + (long)(n0 + row) * NS_ + kg * 32 + sc3, Bs + kg * PSZ + w * 512);
        }
      }
      __syncthreads();
      float4_t acc[2][2] = {};
      #pragma unroll
      for (int kg = 0; kg < 4; kg++) {
        const short* Ab = As + kg * PSZ;
        const short* Bb = Bs + kg * PSZ;
        short8_t af[2], bf[2];
        #pragma unroll
        for (int m = 0; m < 2; m++) af[m] = ldfrag(Ab, wr * 32 + m * 16 + lr, lg);
        #pragma unroll
        for (int n = 0; n < 2; n++) bf[n] = ldfrag(Bb, wc * 32 + n * 16 + lr, lg);
        #pragma unroll
        for (int m = 0; m < 2; m++)
          #pragma unroll
          for (int n = 0; n < 2; n++)
            acc[m][n] = __builtin_amdgcn_mfma_f32_16x16x32_bf16(af[m], bf[n], acc[m][n], 0, 0, 0);
      }
      #pragma unroll
      for (int m = 0; m < 2; m++)
        #pragma unroll
        for (int n = 0; n < 2; n++)
          #pragma unroll
          for (int r = 0; r < 4; r++) {
            const int row = m0 + wr * 32 + m * 16 + lg * 4 + r;
            const int sl = wc * 32 + n * 16 + lr;
            const int g = sl >> 5, k32 = sl & 31;
            const int cc = g * 4 + ((k32 >> 2) & 3);
            const int off = ((cc ^ (row & 7)) * 8) + 4 * (k32 >> 4) + (k32 & 3);
            CBhp[(long)row * T_ + n0 + off] = f2bf(acc[m][n][r]);
          }
    }
  }
  grid_bar(a.bar, 4u);

  // ---------------- phase 4: MFMA attention (snake-paired units, D*x folded epilogue) ----------
  {
    short* CBl = (short*)SMEM;                               // [2][4096]
    short* Xl  = (short*)SMEM + 8192;                        // [2][4096]
    float (*lamS)[17] = (float (*)[17])((short*)SMEM + 16384);
    #pragma unroll 1
    for (int pass = 0; pass < 2; pass++) {
      const int u = pass ? (1023 - bid) : bid;
      if (u < NH_ * 16 * B_) {
        const int ttrank = u / 48, rem = u - ttrank * 48;
        const int h = rem >> 1, b = rem & 1;
        const int tt = 15 - ttrank;
        const int t0 = tt * 64;
        __syncthreads();   // guard LDS reuse from previous unit/phase
        for (int f = tid; f < 64 * NLVL_; f += 256) {
          int r = f / NLVL_, l = f - r * NLVL_;
          lamS[r][l] = softplus_f(
              bf2f(a.projh[((long)b * T_ + t0 + r) * P_ + INTER_ + CONV_DIM_ + NH_ + h * NLVL_ + l]))
              * a.Lw[h * NLVL_ + l];
        }
        const int tl = w * 16 + lr;
        const int t  = t0 + tl;
        const int orow = w * 16 + lg * 4;
        const long chb = (long)(h * B_ + b) * T_;
        const float catv = a.cAT[chb + t];
        float cao[4];
        #pragma unroll
        for (int r = 0; r < 4; r++) cao[r] = a.cAT[chb + t0 + orow + r];
        const short* xbr = a.xTr + (long)(b * NH_ + h) * HD_ * T_;
        const short* xbq = a.xTq + (long)(b * NH_ + h) * HD_ * T_;
        const short* CBbase = a.CBh + (long)b * T_ * T_ + (long)t0 * T_;
        const int srow2 = w * 16 + (lane >> 3);
        const int sch = (lane & 7) * 8;

        auto stage = [&](int buf, int st) {
          const int s0 = st * 64;
          const short* xsrc = (st == tt) ? xbr : xbq;
          #pragma unroll
          for (int i = 0; i < 2; i++) {
            gl_lds16(CBbase + (long)(srow2 + i * 8) * T_ + s0 + sch,
                     CBl + buf * 4096 + (w * 16 + i * 8) * 64);
            gl_lds16(xsrc + (long)(srow2 + i * 8) * T_ + s0 + sch,
                     Xl + buf * 4096 + (w * 16 + i * 8) * 64);
          }
        };

        float4_t acc[4] = {};
        int cur = 0;
        stage(0, 0);
        for (int st = 0; st <= tt; st++) {
          __syncthreads();
          if (st < tt) stage(cur ^ 1, st + 1);
          const int s0 = st * 64;
          if (st < tt) {
            const float caE = a.cAT[chb + s0 + 63];
            const int lev = 32 - __clz(t0 ^ s0);
            float k1o[4];
            #pragma unroll
            for (int r = 0; r < 4; r++)
              k1o[r] = __expf(cao[r] - caE) * lamS[orow + r][lev];
            float4_t dtile[4] = {};
            __builtin_amdgcn_s_setprio(1);
            #pragma unroll
            for (int kk = 0; kk < 2; kk++) {
              short8_t af = ldfrag64(CBl + cur * 4096, tl, kk, lg);
              #pragma unroll
              for (int n = 0; n < 4; n++) {
                short8_t bfv = ldfrag64(Xl + cur * 4096, n * 16 + lr, kk, lg);
                dtile[n] = __builtin_amdgcn_mfma_f32_16x16x32_bf16(af, bfv, dtile[n], 0, 0, 0);
              }
            }
            __builtin_amdgcn_s_setprio(0);
            #pragma unroll
            for (int n = 0; n < 4; n++)
              #pragma unroll
              for (int r = 0; r < 4; r++)
                acc[n][r] = fmaf(k1o[r], dtile[n][r], acc[n][r]);
          } else {
            #pragma unroll
            for (int kk = 0; kk < 2; kk++) {
              short8_t cb8 = ldfrag64(CBl + cur * 4096, tl, kk, lg);
              short8_t af;
              #pragma unroll
              for (int g = 0; g < 2; g++) {
                const int sb = s0 + kk * 32 + g * 16 + lg * 4;
                float4_t ca4 = *(const float4_t*)(a.cAT + chb + sb);
                float4_t dt4 = *(const float4_t*)(a.dtT + chb + sb);
                #pragma unroll
                for (int aa = 0; aa < 4; aa++) {
                  const int sg = sb + aa;
                  float m = 0.f;
                  if (sg <= t) {
                    const int xo = t ^ sg;
                    const int lev2 = xo ? (32 - __clz(xo)) : 0;
                    m = bf2f(cb8[g * 4 + aa]) * __expf(catv - ca4[aa]) * lamS[tl][lev2] * dt4[aa];
                  }
                  af[g * 4 + aa] = f2bf(m);
                }
              }
              __builtin_amdgcn_s_setprio(1);
              #pragma unroll
              for (int n = 0; n < 4; n++) {
                short8_t bfv = ldfrag64(Xl + cur * 4096, n * 16 + lr, kk, lg);
                acc[n] = __builtin_amdgcn_mfma_f32_16x16x32_bf16(af, bfv, acc[n], 0, 0, 0);
              }
              __builtin_amdgcn_s_setprio(0);
            }
          }
          cur ^= 1;
        }

        // epilogue: y + D*x -> bf16 (x tile still in Xl[cur^1])
        const float Dh = a.Dv[h];
        const short* Xd = Xl + (cur ^ 1) * 4096;
        #pragma unroll
        for (int n = 0; n < 4; n++) {
          #pragma unroll
          for (int r = 0; r < 4; r++) {
            const int trow = t0 + orow + r;
            const int hd = n * 16 + lr;
            const int xoff = hd * 64 + ((((w >> 1) * 4 + lg) ^ (hd & 7)) * 8) + (w & 1) * 4 + r;
            const float xv = bf2f(Xd[xoff]);
            a.ybh[((long)b * T_ + trow) * INTER_ + h * HD_ + hd] = f2bf(acc[n][r] + Dh * xv);
          }
        }
      }
    }
  }
  grid_bar(a.bar, 5u);

  // ---------------- phase 5: gate * SiLU + RMSNorm -> bf16 permuted (4 rows/block) -------------
  {
    float* part = (float*)SMEM;
    const int i = tid;
    const int lo = (i >> 2) * 32 + (i & 3) * 4;
    const int hi = lo + 16;
    #pragma unroll 1
    for (int rr = 0; rr < 4; rr++) {
      const long bt = (long)bid * 4 + rr;
      float v[8];
      float ss = 0.f;
      if (i < 192) {
        const short* gp = a.projh + bt * P_;
        const short* yp = a.ybh + bt * INTER_;
        short4_t g0 = *(const short4_t*)(gp + lo);
        short4_t g1 = *(const short4_t*)(gp + hi);
        short4_t y0 = *(const short4_t*)(yp + lo);
        short4_t y1 = *(const short4_t*)(yp + hi);
        float ga[8] = {bf2f(g0[0]), bf2f(g0[1]), bf2f(g0[2]), bf2f(g0[3]),
                       bf2f(g1[0]), bf2f(g1[1]), bf2f(g1[2]), bf2f(g1[3])};
        float ya[8] = {bf2f(y0[0]), bf2f(y0[1]), bf2f(y0[2]), bf2f(y0[3]),
                       bf2f(y1[0]), bf2f(y1[1]), bf2f(y1[2]), bf2f(y1[3])};
        #pragma unroll
        for (int j = 0; j < 8; j++) {
          float val = ya[j] * (ga[j] / (1.f + __expf(-ga[j])));
          v[j] = val;
          ss += val * val;
        }
      }
      #pragma unroll
      for (int sof = 32; sof > 0; sof >>= 1) ss += __shfl_xor(ss, sof);
      __syncthreads();   // guard part[] reuse
      if ((i & 63) == 0 && i < 192) part[i >> 6] = ss;
      __syncthreads();
      if (i < 192) {
        const float tot = part[0] + part[1] + part[2];
        const float r2 = rsqrtf(tot * (1.f / INTER_) + EPS_);
        short8_t o;
        #pragma unroll
        for (int j = 0; j < 8; j++) {
          const int idx = (j < 4) ? (lo + j) : (hi + j - 4);
          o[j] = f2bf(v[j] * r2 * a.nw[idx]);
        }
        *(short8_t*)(a.ynrmb + bt * INTER_ + i * 8) = o;
      }
    }
  }
  grid_bar(a.bar, 6u);

  // ---------------- phase 6: out-proj GEMM (64x64, BK=128) -> fp32 out ----------------
  {
    if (bid < 384) {
      constexpr int PSZ = 64 * 32;
      constexpr int BKG = 4;
      constexpr int BUF = PSZ * BKG;    // 8192 shorts per matrix per buffer
      constexpr int N = HID_, K = INTER_;
      short* As = (short*)SMEM;                 // 2*BUF = 32KB
      short* Bs = (short*)SMEM + 2 * BUF;       // 32KB
      const int m0 = (bid / 12) * 64, n0 = (bid % 12) * 64;
      const int srow = lane >> 2;
      const int sc6 = (lane & 3) * 8;
      const short* A = a.ynrmb;
      const short* Bm = a.wobf;

      auto stage = [&](int buf, int k0) {
        const int row = w * 16 + srow;
        #pragma unroll
        for (int kg = 0; kg < BKG; kg++) {
          gl_lds16(A + (long)(m0 + row) * K + k0 + kg * 32 + sc6, As + buf * BUF + kg * PSZ + w * 512);
          gl_lds16(Bm + (long)(n0 + row) * K + k0 + kg * 32 + sc6, Bs + buf * BUF + kg * PSZ + w * 512);
        }
      };

      float4_t acc[2][2] = {};
      int cur = 0;
      stage(0, 0);
      for (int k0 = 0; k0 < K; k0 += 128) {
        __syncthreads();
        if (k0 + 128 < K) stage(cur ^ 1, k0 + 128);
        #pragma unroll
        for (int kg = 0; kg < BKG; kg++) {
          const short* Ab = As + cur * BUF + kg * PSZ;
          const short* Bb = Bs + cur * BUF + kg * PSZ;
          short8_t af[2], bf[2];
          #pragma unroll
          for (int m = 0; m < 2; m++) af[m] = ldfrag(Ab, wr * 32 + m * 16 + lr, lg);
          #pragma unroll
          for (int n = 0; n < 2; n++) bf[n] = ldfrag(Bb, wc * 32 + n * 16 + lr, lg);
          #pragma unroll
          for (int m = 0; m < 2; m++)
            #pragma unroll
            for (int n = 0; n < 2; n++)
              acc[m][n] = __builtin_amdgcn_mfma_f32_16x16x32_bf16(af[m], bf[n], acc[m][n], 0, 0, 0);
        }
        cur ^= 1;
      }
      #pragma unroll
      for (int m = 0; m < 2; m++)
        #pragma unroll
        for (int n = 0; n < 2; n++)
          #pragma unroll
          for (int r = 0; r < 4; r++) {
            const int row = m0 + wr * 32 + m * 16 + lg * 4 + r;
            const int col = n0 + wc * 32 + n * 16 + lr;
            a.out[(long)row * N + col] = acc[m][n][r];
          }
    }
  }
}

// =====================================================================================
// FALLBACK: original 7-kernel pipeline (used if cooperative launch is rejected)
// =====================================================================================

__global__ __launch_bounds__(256) void cvtdt_k(
    const float* __restrict__ hs, const float* __restrict__ Win, const float* __restrict__ Wout,
    short* __restrict__ hsbf, short* __restrict__ wibf, short* __restrict__ wobf,
    float* __restrict__ dtraw, int ncvt)
{
  const long na = (long)B_ * T_ * HID_, nb = (long)P_ * HID_, nc = (long)HID_ * INTER_;
  if ((int)blockIdx.x < ncvt) {
    const long i = ((long)blockIdx.x * 256 + threadIdx.x) * 8;
    const float* src; short* dst; long off;
    if (i < na)           { src = hs;   dst = hsbf; off = i; }
    else if (i < na + nb) { src = Win;  dst = wibf; off = i - na; }
    else if (i < na + nb + nc) { src = Wout; dst = wobf; off = i - na - nb; }
    else return;
    const long base = (off & ~31L) + ((off >> 3) & 3) * 4;
    float4 v0 = *(const float4*)(src + base);
    float4 v1 = *(const float4*)(src + base + 16);
    short8_t o;
    o[0] = f2bf(v0.x); o[1] = f2bf(v0.y); o[2] = f2bf(v0.z); o[3] = f2bf(v0.w);
    o[4] = f2bf(v1.x); o[5] = f2bf(v1.y); o[6] = f2bf(v1.z); o[7] = f2bf(v1.w);
    *(short8_t*)(dst + off) = o;
  } else {
    const int rowbt = ((int)blockIdx.x - ncvt) * 4 + (threadIdx.x >> 6);
    const int lane = threadIdx.x & 63;
    float hv[12];
    const float* hrow = hs + (long)rowbt * HID_ + lane * 12;
    #pragma unroll
    for (int j = 0; j < 12; j++) hv[j] = hrow[j];
    const float* wbase = Win + (long)(INTER_ + CONV_DIM_) * HID_ + lane * 12;
    for (int h = 0; h < NH_; h++) {
      const float* wr = wbase + (long)h * HID_;
      float s = 0.f;
      #pragma unroll
      for (int j = 0; j < 12; j++) s = fmaf(hv[j], wr[j], s);
      #pragma unroll
      for (int off = 32; off; off >>= 1) s += __shfl_xor(s, off);
      if (lane == 0) dtraw[(long)rowbt * NH_ + h] = s;
    }
  }
}

__global__ __launch_bounds__(256) void inproj_scan_k(
    const short* __restrict__ A, const short* __restrict__ B, short* __restrict__ C,
    const float* __restrict__ dtraw, const float* __restrict__ dt_bias,
    const float* __restrict__ A_log, float* __restrict__ dtT, float* __restrict__ cAT,
    float* __restrict__ qT)
{
  constexpr int TM = 128, TN = 128, K = HID_, BK = 64;
  constexpr int PSZ = TM * 32;
  constexpr int ASZ = 2 * PSZ;
  __shared__ short As[2 * ASZ];
  __shared__ short Bs[2 * ASZ];

  if (blockIdx.y >= 16) {
    const int sid = ((int)blockIdx.y - 16) * 29 + (int)blockIdx.x;
    if (sid >= B_ * NH_) return;
    const int b = sid / NH_;
    const int h = sid % NH_;
    const float bias = dt_bias[h];
    const float Ah = -__expf(A_log[h]);
    const long ob = (long)(h * B_ + b) * T_;
    float* sc = (float*)As;
    float carry = 0.f;
    for (int c0 = 0; c0 < T_; c0 += 256) {
      const int t = c0 + threadIdx.x;
      const long bt = (long)b * T_ + t;
      float sp = softplus_f(dtraw[bt * NH_ + h] + bias);
      dtT[ob + t] = sp;
      sc[threadIdx.x] = sp * Ah;
      __syncthreads();
      for (int off = 1; off < 256; off <<= 1) {
        float add = (threadIdx.x >= off) ? sc[threadIdx.x - off] : 0.f;
        __syncthreads();
        sc[threadIdx.x] += add;
        __syncthreads();
      }
      cAT[ob + t] = carry + sc[threadIdx.x];
      qT[ob + t] = sp * __expf(sc[threadIdx.x | 63] - sc[threadIdx.x]);
      float tot = sc[255];
      __syncthreads();
      carry += tot;
    }
    return;
  }

  const int tid = threadIdx.x;
  const int w = tid >> 6, lane = tid & 63;
  const int lr = lane & 15, lg = lane >> 4;
  const int wr = w >> 1, wc = w & 1;
  const int m0 = blockIdx.y * TM, n0 = blockIdx.x * TN;
  const int srow = lane >> 2;
  const int sc2 = (lane & 3) * 8;

  auto stage = [&](int buf, int k0) {
    #pragma unroll
    for (int it = 0; it < 2; it++) {
      const int cb = w + 4 * it;
      const int row = cb * 16 + srow;
      #pragma unroll
      for (int kg = 0; kg < 2; kg++) {
        gl_lds16(A + (long)(m0 + row) * K + k0 + kg * 32 + sc2,
                 As + buf * ASZ + kg * PSZ + cb * 512);
        gl_lds16(B + (long)(n0 + row) * K + k0 + kg * 32 + sc2,
                 Bs + buf * ASZ + kg * PSZ + cb * 512);
      }
    }
  };

  float4_t acc[4][4] = {};
  int cur = 0;
  stage(0, 0);
  for (int k0 = 0; k0 < K; k0 += BK) {
    __syncthreads();
    if (k0 + BK < K) stage(cur ^ 1, k0 + BK);
    #pragma unroll
    for (int kg = 0; kg < 2; kg++) {
      const short* Ab = As + cur * ASZ + kg * PSZ;
      const short* Bb = Bs + cur * ASZ + kg * PSZ;
      short8_t af[4], bf[4];
      #pragma unroll
      for (int m = 0; m < 4; m++) af[m] = ldfrag(Ab, wr * 64 + m * 16 + lr, lg);
      #pragma unroll
      for (int n = 0; n < 4; n++) bf[n] = ldfrag(Bb, wc * 64 + n * 16 + lr, lg);
      #pragma unroll
      for (int m = 0; m < 4; m++)
        #pragma unroll
        for (int n = 0; n < 4; n++)
          acc[m][n] = __builtin_amdgcn_mfma_f32_16x16x32_bf16(af[m], bf[n], acc[m][n], 0, 0, 0);
    }
    cur ^= 1;
  }

  #pragma unroll
  for (int m = 0; m < 4; m++)
    #pragma unroll
    for (int n = 0; n < 4; n++)
      #pragma unroll
      for (int r = 0; r < 4; r++) {
        const int row = m0 + wr * 64 + m * 16 + lg * 4 + r;
        const int col = n0 + wc * 64 + n * 16 + lr;
        C[(long)row * P_ + col] = f2bf(acc[m][n][r]);
      }
}

__global__ __launch_bounds__(256) void gemm_out_k(
    const short* __restrict__ A, const short* __restrict__ B, float* __restrict__ C,
    int M, int N, int K)
{
  constexpr int PSZ = 64 * 32;
  constexpr int BKG = 4;
  constexpr int BUF = PSZ * BKG;
  __shared__ short As[2 * BUF];
  __shared__ short Bs[2 * BUF];
  const int tid = threadIdx.x;
  const int w = tid >> 6, lane = tid & 63;
  const int lr = lane & 15, lg = lane >> 4;
  const int wr = w >> 1, wc = w & 1;
  const int m0 = blockIdx.y * 64, n0 = blockIdx.x * 64;
  const int srow = lane >> 2;
  const int sc = (lane & 3) * 8;

  auto stage = [&](int buf, int k0) {
    const int row = w * 16 + srow;
    #pragma unroll
    for (int kg = 0; kg < BKG; kg++) {
      gl_lds16(A + (long)(m0 + row) * K + k0 + kg * 32 + sc, As + buf * BUF + kg * PSZ + w * 512);
      gl_lds16(B + (long)(n0 + row) * K + k0 + kg * 32 + sc, Bs + buf * BUF + kg * PSZ + w * 512);
    }
  };

  float4_t acc[2][2] = {};
  int cur = 0;
  stage(0, 0);
  for (int k0 = 0; k0 < K; k0 += 128) {
    __syncthreads();
    if (k0 + 128 < K) stage(cur ^ 1, k0 + 128);
    #pragma unroll
    for (int kg = 0; kg < BKG; kg++) {
      const short* Ab = As + cur * BUF + kg * PSZ;
      const short* Bb = Bs + cur * BUF + kg * PSZ;
      short8_t af[2], bf[2];
      #pragma unroll
      for (int m = 0; m < 2; m++) af[m] = ldfrag(Ab, wr * 32 + m * 16 + lr, lg);
      #pragma unroll
      for (int n = 0; n < 2; n++) bf[n] = ldfrag(Bb, wc * 32 + n * 16 + lr, lg);
      #pragma unroll
      for (int m = 0; m < 2; m++)
        #pragma unroll
        for (int n = 0; n < 2; n++)
          acc[m][n] = __builtin_amdgcn_mfma_f32_16x16x32_bf16(af[m], bf[n], acc[m][n], 0, 0, 0);
    }
    cur ^= 1;
  }

  #pragma unroll
  for (int m = 0; m < 2; m++)
    #pragma unroll
    for (int n = 0; n < 2; n++)
      #pragma unroll
      for (int r = 0; r < 4; r++) {
        const int row = m0 + wr * 32 + m * 16 + lg * 4 + r;
        const int col = n0 + wc * 32 + n * 16 + lr;
        C[(long)row * N + col] = acc[m][n][r];
      }
}

__global__ __launch_bounds__(256) void gemm_cbh_k(
    const short* __restrict__ Chh, const short* __restrict__ Bh, short* __restrict__ CBh)
{
  if (blockIdx.x > blockIdx.y) return;
  Chh += (long)blockIdx.z * T_ * NS_;
  Bh  += (long)blockIdx.z * T_ * NS_;
  CBh += (long)blockIdx.z * T_ * T_;
  constexpr int PSZ = 64 * 32;
  __shared__ short As[4 * PSZ];
  __shared__ short Bs[4 * PSZ];
  const int tid = threadIdx.x;
  const int w = tid >> 6, lane = tid & 63;
  const int lr = lane & 15, lg = lane >> 4;
  const int wr = w >> 1, wc = w & 1;
  const int m0 = blockIdx.y * 64, n0 = blockIdx.x * 64;
  const int srow = lane >> 2;
  const int sc = (lane & 3) * 8;

  {
    const int row = w * 16 + srow;
    #pragma unroll
    for (int kg = 0; kg < 4; kg++) {
      gl_lds16(Chh + (long)(m0 + row) * NS_ + kg * 32 + sc, As + kg * PSZ + w * 512);
      gl_lds16(Bh  + (long)(n0 + row) * NS_ + kg * 32 + sc, Bs + kg * PSZ + w * 512);
    }
  }
  __syncthreads();

  float4_t acc[2][2] = {};
  #pragma unroll
  for (int kg = 0; kg < 4; kg++) {
    const short* Ab = As + kg * PSZ;
    const short* Bb = Bs + kg * PSZ;
    short8_t af[2], bf[2];
    #pragma unroll
    for (int m = 0; m < 2; m++) af[m] = ldfrag(Ab, wr * 32 + m * 16 + lr, lg);
    #pragma unroll
    for (int n = 0; n < 2; n++) bf[n] = ldfrag(Bb, wc * 32 + n * 16 + lr, lg);
    #pragma unroll
    for (int m = 0; m < 2; m++)
      #pragma unroll
      for (int n = 0; n < 2; n++)
        acc[m][n] = __builtin_amdgcn_mfma_f32_16x16x32_bf16(af[m], bf[n], acc[m][n], 0, 0, 0);
  }

  #pragma unroll
  for (int m = 0; m < 2; m++)
    #pragma unroll
    for (int n = 0; n < 2; n++)
      #pragma unroll
      for (int r = 0; r < 4; r++) {
        const int row = m0 + wr * 32 + m * 16 + lg * 4 + r;
        const int sl = wc * 32 + n * 16 + lr;
        const int g = sl >> 5, k32 = sl & 31;
        const int cc = g * 4 + ((k32 >> 2) & 3);
        const int off = ((cc ^ (row & 7)) * 8) + 4 * (k32 >> 4) + (k32 & 3);
        CBh[(long)row * T_ + n0 + off] = f2bf(acc[m][n][r]);
      }
}

__global__ __launch_bounds__(256) void conv_silu_k(
    const short* __restrict__ projh, const float* __restrict__ cw, const float* __restrict__ cbias,
    const float* __restrict__ qT,
    short* __restrict__ xTr, short* __restrict__ xTq,
    short* __restrict__ Bh, short* __restrict__ Chh)
{
  const int c0 = blockIdx.x * 256;
  const int t0 = blockIdx.y * 16;
  const int b  = blockIdx.z;
  const int tid = threadIdx.x;
  __shared__ float S[19][256];
  #pragma unroll
  for (int r = 0; r < 19; r++) {
    const int t = t0 - 3 + r;
    S[r][tid] = (t >= 0) ? bf2f(projh[((long)b * T_ + t) * P_ + INTER_ + c0 + tid]) : 0.f;
  }
  __syncthreads();
  const int c = c0 + tid;
  const float4 w = *(const float4*)(cw + c * 4);
  const float bias = cbias[c];
  float acc[16];
  #pragma unroll
  for (int tt = 0; tt < 16; tt++) {
    float a = bias + w.w * S[tt + 3][tid] + w.z * S[tt + 2][tid]
                   + w.y * S[tt + 1][tid] + w.x * S[tt][tid];
    acc[tt] = a / (1.f + __expf(-a));
  }
  if (c < INTER_) {
    const int h = c >> 6, hd = c & 63;
    const long chb = (long)(h * B_ + b) * T_;
    float qv[16];
    #pragma unroll
    for (int qq = 0; qq < 4; qq++) {
      float4 q4 = *(const float4*)(qT + chb + t0 + qq * 4);
      qv[qq*4+0] = q4.x; qv[qq*4+1] = q4.y; qv[qq*4+2] = q4.z; qv[qq*4+3] = q4.w;
    }
    const long base = ((long)(b * NH_ + h) * HD_ + hd) * T_ + (t0 & ~63);
    const int g = (t0 >> 5) & 1, h2 = (t0 >> 4) & 1, sw = hd & 7;
    #pragma unroll
    for (int a = 0; a < 4; a++) {
      short4_t xr, xq;
      #pragma unroll
      for (int r = 0; r < 4; r++) {
        xr[r] = f2bf(acc[a * 4 + r]);
        xq[r] = f2bf(acc[a * 4 + r] * qv[a * 4 + r]);
      }
      const int off = (((g * 4 + a) ^ sw) * 8) + h2 * 4;
      *(short4_t*)(xTr + base + off) = xr;
      *(short4_t*)(xTq + base + off) = xq;
    }
  } else {
    const int ch0 = c - INTER_;
    const bool isB = ch0 < NS_;
    const int k = isB ? ch0 : ch0 - NS_;
    const int k32 = k & 31;
    const int P = (k & ~31) + 8 * ((k32 >> 2) & 3) + 4 * (k32 >> 4) + (k32 & 3);
    short* dst = isB ? Bh : Chh;
    #pragma unroll
    for (int tt = 0; tt < 16; tt++) {
      const long bt = (long)b * T_ + t0 + tt;
      dst[bt * NS_ + P] = f2bf(acc[tt]);
    }
  }
}

__global__ __launch_bounds__(256) void attn_mfma3_k(
    const short* __restrict__ xTr, const short* __restrict__ xTq,
    const short* __restrict__ CBh,
    const float* __restrict__ cAT, const float* __restrict__ dtT,
    const short* __restrict__ projh, const float* __restrict__ Lw,
    const float* __restrict__ Dv,
    short* __restrict__ ybh)
{
  const int h = blockIdx.x;
  const int tt = (T_ / 64 - 1) - blockIdx.y;
  const int b = blockIdx.z;
  const int t0 = tt * 64;
  const int tid = threadIdx.x;
  const int w = tid >> 6, lane = tid & 63;
  const int lr = lane & 15, lg = lane >> 4;

  __shared__ short CBl[2][64 * 64];
  __shared__ short Xl[2][64 * 64];
  __shared__ float lamS[64][17];

  for (int f = tid; f < 64 * NLVL_; f += 256) {
    int r = f / NLVL_, l = f - r * NLVL_;
    lamS[r][l] = softplus_f(
        bf2f(projh[((long)b * T_ + t0 + r) * P_ + INTER_ + CONV_DIM_ + NH_ + h * NLVL_ + l]))
        * Lw[h * NLVL_ + l];
  }

  const int tl = w * 16 + lr;
  const int t  = t0 + tl;
  const int orow = w * 16 + lg * 4;
  const long chb = (long)(h * B_ + b) * T_;
  const float catv = cAT[chb + t];
  float cao[4];
  #pragma unroll
  for (int r = 0; r < 4; r++) cao[r] = cAT[chb + t0 + orow + r];

  const short* xbr = xTr + (long)(b * NH_ + h) * HD_ * T_;
  const short* xbq = xTq + (long)(b * NH_ + h) * HD_ * T_;
  const short* CBbase = CBh + (long)b * T_ * T_ + (long)t0 * T_;

  const int srow = w * 16 + (lane >> 3);
  const int sch = (lane & 7) * 8;

  auto stage = [&](int buf, int st) {
    const int s0 = st * 64;
    const short* xsrc = (st == tt) ? xbr : xbq;
    #pragma unroll
    for (int i = 0; i < 2; i++) {
      gl_lds16(CBbase + (long)(srow + i * 8) * T_ + s0 + sch, &CBl[buf][(w * 16 + i * 8) * 64]);
      gl_lds16(xsrc + (long)(srow + i * 8) * T_ + s0 + sch, &Xl[buf][(w * 16 + i * 8) * 64]);
    }
  };

  float4_t acc[4] = {};
  int cur = 0;
  stage(0, 0);
  for (int st = 0; st <= tt; st++) {
    __syncthreads();
    if (st < tt) stage(cur ^ 1, st + 1);
    const int s0 = st * 64;
    if (st < tt) {
      const float caE = cAT[chb + s0 + 63];
      const int lev = 32 - __clz(t0 ^ s0);
      float k1o[4];
      #pragma unroll
      for (int r = 0; r < 4; r++)
        k1o[r] = __expf(cao[r] - caE) * lamS[orow + r][lev];
      float4_t dtile[4] = {};
      __builtin_amdgcn_s_setprio(1);
      #pragma unroll
      for (int kk = 0; kk < 2; kk++) {
        short8_t af = ldfrag64(CBl[cur], tl, kk, lg);
        #pragma unroll
        for (int n = 0; n < 4; n++) {
          short8_t bfv = ldfrag64(Xl[cur], n * 16 + lr, kk, lg);
          dtile[n] = __builtin_amdgcn_mfma_f32_16x16x32_bf16(af, bfv, dtile[n], 0, 0, 0);
        }
      }
      __builtin_amdgcn_s_setprio(0);
      #pragma unroll
      for (int n = 0; n < 4; n++)
        #pragma unroll
        for (int r = 0; r < 4; r++)
          acc[n][r] = fmaf(k1o[r], dtile[n][r], acc[n][r]);
    } else {
      #pragma unroll
      for (int kk = 0; kk < 2; kk++) {
        short8_t cb8 = ldfrag64(CBl[cur], tl, kk, lg);
        short8_t af;
        #pragma unroll
        for (int g = 0; g < 2; g++) {
          const int sb = s0 + kk * 32 + g * 16 + lg * 4;
          float4_t ca4 = *(const float4_t*)(cAT + chb + sb);
          float4_t dt4 = *(const float4_t*)(dtT + chb + sb);
          #pragma unroll
          for (int a = 0; a < 4; a++) {
            const int sg = sb + a;
            float m = 0.f;
            if (sg <= t) {
              const int xo = t ^ sg;
              const int lev2 = xo ? (32 - __clz(xo)) : 0;
              m = bf2f(cb8[g * 4 + a]) * __expf(catv - ca4[a]) * lamS[tl][lev2] * dt4[a];
            }
            af[g * 4 + a] = f2bf(m);
          }
        }
        __builtin_amdgcn_s_setprio(1);
        #pragma unroll
        for (int n = 0; n < 4; n++) {
          short8_t bfv = ldfrag64(Xl[cur], n * 16 + lr, kk, lg);
          acc[n] = __builtin_amdgcn_mfma_f32_16x16x32_bf16(af, bfv, acc[n], 0, 0, 0);
        }
        __builtin_amdgcn_s_setprio(0);
      }
    }
    cur ^= 1;
  }

  const float Dh = Dv[h];
  const short* Xd = Xl[cur ^ 1];
  #pragma unroll
  for (int n = 0; n < 4; n++) {
    #pragma unroll
    for (int r = 0; r < 4; r++) {
      const int trow = t0 + orow + r;
      const int hd = n * 16 + lr;
      const int xoff = hd * 64 + ((((w >> 1) * 4 + lg) ^ (hd & 7)) * 8) + (w & 1) * 4 + r;
      const float xv = bf2f(Xd[xoff]);
      ybh[((long)b * T_ + trow) * INTER_ + h * HD_ + hd] = f2bf(acc[n][r] + Dh * xv);
    }
  }
}

__global__ __launch_bounds__(192) void gate_rms_k(
    const short* __restrict__ ybh, const short* __restrict__ projh,
    const float* __restrict__ nw, short* __restrict__ ynorm)
{
  const long bt = blockIdx.x;
  const short* gp = projh + bt * P_;
  const short* yp = ybh + bt * INTER_;
  const int i = threadIdx.x;
  const int lo = (i >> 2) * 32 + (i & 3) * 4;
  const int hi = lo + 16;
  float v[8];
  float ss = 0.f;
  {
    short4_t g0 = *(const short4_t*)(gp + lo);
    short4_t g1 = *(const short4_t*)(gp + hi);
    short4_t y0 = *(const short4_t*)(yp + lo);
    short4_t y1 = *(const short4_t*)(yp + hi);
    float ga[8] = {bf2f(g0[0]), bf2f(g0[1]), bf2f(g0[2]), bf2f(g0[3]),
                   bf2f(g1[0]), bf2f(g1[1]), bf2f(g1[2]), bf2f(g1[3])};
    float ya[8] = {bf2f(y0[0]), bf2f(y0[1]), bf2f(y0[2]), bf2f(y0[3]),
                   bf2f(y1[0]), bf2f(y1[1]), bf2f(y1[2]), bf2f(y1[3])};
    #pragma unroll
    for (int j = 0; j < 8; j++) {
      float val = ya[j] * (ga[j] / (1.f + __expf(-ga[j])));
      v[j] = val;
      ss += val * val;
    }
  }
  #pragma unroll
  for (int off = 32; off > 0; off >>= 1) ss += __shfl_xor(ss, off);
  __shared__ float part[3];
  if ((i & 63) == 0) part[i >> 6] = ss;
  __syncthreads();
  const float tot = part[0] + part[1] + part[2];
  const float r = rsqrtf(tot * (1.f / INTER_) + EPS_);
  short8_t o;
  #pragma unroll
  for (int j = 0; j < 8; j++) {
    const int idx = (j < 4) ? (lo + j) : (hi + j - 4);
    o[j] = f2bf(v[j] * r * nw[idx]);
  }
  *(short8_t*)(ynorm + bt * INTER_ + i * 8) = o;
}

extern "C" void kernel_launch(void* const* d_in, const int* in_sizes, int n_in,
                              void* d_out, int out_size, void* d_ws, size_t ws_size,
                              hipStream_t stream) {
  const float* hs   = (const float*)d_in[0];
  const float* Win  = (const float*)d_in[1];
  const float* cw   = (const float*)d_in[2];
  const float* cb   = (const float*)d_in[3];
  const float* dtb  = (const float*)d_in[4];
  const float* Alog = (const float*)d_in[5];
  const float* Lw   = (const float*)d_in[6];
  const float* Dv   = (const float*)d_in[7];
  const float* nw   = (const float*)d_in[8];
  const float* Wout = (const float*)d_in[9];
  float* out = (float*)d_out;

  const long n_hs = (long)B_ * T_ * HID_;
  const long n_wi = (long)P_ * HID_;
  const long n_wo = (long)HID_ * INTER_;

  float* ws = (float*)d_ws;
  long o = 0;
  float* projreg = ws + o; o += (long)B_ * T_ * P_ / 2 + 16;
  short* xbf   = (short*)(ws + o); o += (long)B_ * T_ * INTER_ / 2;  // (slot retained, unused)
  short* Bh    = (short*)(ws + o); o += (long)B_ * T_ * NS_ / 2;
  short* Chh   = (short*)(ws + o); o += (long)B_ * T_ * NS_ / 2;
  float* dtT   = ws + o; o += (long)B_ * T_ * NH_;
  float* cAT   = ws + o; o += (long)B_ * T_ * NH_;
  float* qT    = ws + o; o += (long)B_ * T_ * NH_;
  float* dtraw = ws + o; o += (long)B_ * T_ * NH_;
  short* CBh   = (short*)(ws + o); o += (long)B_ * T_ * T_ / 2;
  short* ybh   = (short*)(ws + o); o += (long)B_ * T_ * INTER_ / 2;
  float* yxreg = ws + o; o += (long)B_ * T_ * INTER_ / 2;
  short* hsbf  = (short*)(ws + o); o += n_hs / 2;
  short* wibf  = (short*)(ws + o); o += n_wi / 2;
  short* wobf  = (short*)(ws + o); o += n_wo / 2;
  unsigned* bar = (unsigned*)(ws + o); o += 1024;   // 4KB barrier state
  short* projh = (short*)projreg;
  short* xTr   = (short*)yxreg;
  short* ynrmb = (short*)yxreg;
  short* xTq   = hsbf;
  (void)xbf;

  // zero the barrier state (workspace is poisoned each reset)
  hipMemsetAsync(bar, 0, 4096, stream);

  // ---- preferred path: single cooperative mega-kernel (512 blocks = 2/CU @ 64KB LDS) ----
  MegaArgs ma;
  ma.hs = hs; ma.Win = Win; ma.cw = cw; ma.cb = cb; ma.dtb = dtb; ma.Alog = Alog;
  ma.Lw = Lw; ma.Dv = Dv; ma.nw = nw; ma.Wout = Wout; ma.out = out;
  ma.hsbf = hsbf; ma.wibf = wibf; ma.wobf = wobf;
  ma.dtraw = dtraw; ma.dtT = dtT; ma.cAT = cAT; ma.qT = qT;
  ma.projh = projh; ma.xTr = xTr; ma.xTq = xTq; ma.Bh = Bh; ma.Chh = Chh;
  ma.CBh = CBh; ma.ybh = ybh; ma.ynrmb = ynrmb; ma.bar = bar;
  void* kargs[] = { (void*)&ma };
  hipError_t ce = hipLaunchCooperativeKernel(
      (const void*)mega_k, dim3(512), dim3(256), kargs, 0, stream);
  if (ce == hipSuccess) return;

  // ---- fallback: proven 7-kernel pipeline ----
  const int ncvt = (int)((n_hs + n_wi + n_wo) / 8 / 256);
  cvtdt_k<<<ncvt + (B_ * T_) / 4, 256, 0, stream>>>(
      hs, Win, Wout, hsbf, wibf, wobf, dtraw, ncvt);
  inproj_scan_k<<<dim3(P_ / 128, 18), 256, 0, stream>>>(
      hsbf, wibf, projh, dtraw, dtb, Alog, dtT, cAT, qT);
  conv_silu_k<<<dim3(CONV_DIM_ / 256, T_ / 16, B_), 256, 0, stream>>>(
      projh, cw, cb, qT, xTr, xTq, Bh, Chh);
  gemm_cbh_k<<<dim3(T_ / 64, T_ / 64, B_), 256, 0, stream>>>(Chh, Bh, CBh);
  attn_mfma3_k<<<dim3(NH_, T_ / 64, B_), 256, 0, stream>>>(
      xTr, xTq, CBh, cAT, dtT, projh, Lw, Dv, ybh);
  gate_rms_k<<<B_ * T_, 192, 0, stream>>>(ybh, projh, nw, ynrmb);
  gemm_out_k<<<dim3(HID_ / 64, (B_ * T_) / 64), 256, 0, stream>>>(
      ynrmb, wobf, out, B_ * T_, HID_, INTER_);
}

// Round 6
// 107.313 us; speedup vs baseline: 7.5728x; 2.3151x over previous
//
#include <hip/hip_runtime.h>
#include <hip/hip_bf16.h>
#include <math.h>

#define B_ 2
#define T_ 1024
#define HID_ 768
#define INTER_ 1536
#define NH_ 24
#define HD_ 64
#define NS_ 128
#define NLVL_ 15
#define CONV_DIM_ 1792
#define P_ 3712
#define EPS_ 1e-5f

typedef short short8_t __attribute__((ext_vector_type(8)));
typedef short short4_t __attribute__((ext_vector_type(4)));
typedef float float4_t __attribute__((ext_vector_type(4)));

// K-permutation (within each 32-element K-group): physical p = 8a + 4h + r for
// logical k = 16h + 4a + r. A lane's MFMA operand (k = lg*4+{0..3} and +16) is then
// ONE contiguous 16B chunk at p = 8*lg  ->  single ds_read_b128 per fragment.

__device__ __forceinline__ float softplus_f(float x) {
  return (x > 20.f) ? x : log1pf(__expf(x));
}
__device__ __forceinline__ short f2bf(float f) {
  union { float f; unsigned u; } v; v.f = f;
  unsigned r = v.u + 0x7FFF + ((v.u >> 16) & 1);   // RNE
  return (short)(r >> 16);
}
__device__ __forceinline__ float bf2f(short s) {
  union { unsigned u; float f; } v; v.u = ((unsigned)(unsigned short)s) << 16;
  return v.f;
}
__device__ __forceinline__ void gl_lds16(const void* g, void* l) {
  __builtin_amdgcn_global_load_lds(
      (const __attribute__((address_space(1))) unsigned int*)g,
      (__attribute__((address_space(3))) unsigned int*)l, 16, 0, 0);
}

// ---------------- fused: f32->bf16 K-permuted cvt (hs/Win/Wout) + fp32 dt columns ----------------
__global__ __launch_bounds__(256) void cvtdt_k(
    const float* __restrict__ hs, const float* __restrict__ Win, const float* __restrict__ Wout,
    short* __restrict__ hsbf, short* __restrict__ wibf, short* __restrict__ wobf,
    float* __restrict__ dtraw, int ncvt)
{
  const long na = (long)B_ * T_ * HID_, nb = (long)P_ * HID_, nc = (long)HID_ * INTER_;
  if ((int)blockIdx.x < ncvt) {
    const long i = ((long)blockIdx.x * 256 + threadIdx.x) * 8;
    const float* src; short* dst; long off;
    if (i < na)           { src = hs;   dst = hsbf; off = i; }
    else if (i < na + nb) { src = Win;  dst = wibf; off = i - na; }
    else if (i < na + nb + nc) { src = Wout; dst = wobf; off = i - na - nb; }
    else return;
    const long base = (off & ~31L) + ((off >> 3) & 3) * 4;  // logical source of this physical chunk
    float4 v0 = *(const float4*)(src + base);
    float4 v1 = *(const float4*)(src + base + 16);
    short8_t o;
    o[0] = f2bf(v0.x); o[1] = f2bf(v0.y); o[2] = f2bf(v0.z); o[3] = f2bf(v0.w);
    o[4] = f2bf(v1.x); o[5] = f2bf(v1.y); o[6] = f2bf(v1.z); o[7] = f2bf(v1.w);
    *(short8_t*)(dst + off) = o;
  } else {
    const int rowbt = ((int)blockIdx.x - ncvt) * 4 + (threadIdx.x >> 6);
    const int lane = threadIdx.x & 63;
    float hv[12];
    const float* hrow = hs + (long)rowbt * HID_ + lane * 12;
    #pragma unroll
    for (int j = 0; j < 12; j++) hv[j] = hrow[j];
    const float* wbase = Win + (long)(INTER_ + CONV_DIM_) * HID_ + lane * 12;
    for (int h = 0; h < NH_; h++) {
      const float* wr = wbase + (long)h * HID_;
      float s = 0.f;
      #pragma unroll
      for (int j = 0; j < 12; j++) s = fmaf(hv[j], wr[j], s);
      #pragma unroll
      for (int off = 32; off; off >>= 1) s += __shfl_xor(s, off);
      if (lane == 0) dtraw[(long)rowbt * NH_ + h] = s;
    }
  }
}

// Permuted LDS fragment read (BK-panel of 32 K): one b128 per fragment.
__device__ __forceinline__ short8_t ldfrag(const short* Ts, int row, int lg) {
  return *(const short8_t*)(Ts + row * 32 + lg * 8);
}

// Permuted+row-swizzled 64-wide fragment read (attn): one b128 per fragment.
__device__ __forceinline__ short8_t ldfrag64(const short* Ts, int row, int kk, int lg) {
  const int cc = (kk * 4 + lg) ^ (row & 7);
  return *(const short8_t*)(Ts + row * 64 + cc * 8);
}

// ---------------- in-proj GEMM (128x128, BK=64, bf16 out) + fused dt_scan (extra grid rows) ------
__global__ __launch_bounds__(256) void inproj_scan_k(
    const short* __restrict__ A, const short* __restrict__ B, short* __restrict__ C,
    const float* __restrict__ dtraw, const float* __restrict__ dt_bias,
    const float* __restrict__ A_log, float* __restrict__ dtT, float* __restrict__ cAT,
    float* __restrict__ qT)
{
  constexpr int TM = 128, TN = 128, K = HID_, BK = 64;
  constexpr int PSZ = TM * 32;        // one 32-K panel: 4096 shorts
  constexpr int ASZ = 2 * PSZ;        // per buffer per matrix: 8192 shorts (16KB)
  __shared__ short As[2 * ASZ];
  __shared__ short Bs[2 * ASZ];

  if (blockIdx.y >= 16) {
    const int sid = ((int)blockIdx.y - 16) * 29 + (int)blockIdx.x;
    if (sid >= B_ * NH_) return;
    const int b = sid / NH_;
    const int h = sid % NH_;
    const float bias = dt_bias[h];
    const float Ah = -__expf(A_log[h]);
    const long ob = (long)(h * B_ + b) * T_;
    float* sc = (float*)As;
    float carry = 0.f;
    for (int c0 = 0; c0 < T_; c0 += 256) {
      const int t = c0 + threadIdx.x;
      const long bt = (long)b * T_ + t;
      float sp = softplus_f(dtraw[bt * NH_ + h] + bias);
      dtT[ob + t] = sp;
      sc[threadIdx.x] = sp * Ah;
      __syncthreads();
      for (int off = 1; off < 256; off <<= 1) {
        float add = (threadIdx.x >= off) ? sc[threadIdx.x - off] : 0.f;
        __syncthreads();
        sc[threadIdx.x] += add;
        __syncthreads();
      }
      cAT[ob + t] = carry + sc[threadIdx.x];
      qT[ob + t] = sp * __expf(sc[threadIdx.x | 63] - sc[threadIdx.x]);
      float tot = sc[255];
      __syncthreads();
      carry += tot;
    }
    return;
  }

  const int tid = threadIdx.x;
  const int w = tid >> 6, lane = tid & 63;
  const int lr = lane & 15, lg = lane >> 4;
  const int wr = w >> 1, wc = w & 1;
  const int m0 = blockIdx.y * TM, n0 = blockIdx.x * TN;
  const int srow = lane >> 2;
  const int sc2 = (lane & 3) * 8;

  auto stage = [&](int buf, int k0) {
    #pragma unroll
    for (int it = 0; it < 2; it++) {
      const int cb = w + 4 * it;
      const int row = cb * 16 + srow;
      #pragma unroll
      for (int kg = 0; kg < 2; kg++) {
        gl_lds16(A + (long)(m0 + row) * K + k0 + kg * 32 + sc2,
                 As + buf * ASZ + kg * PSZ + cb * 512);
        gl_lds16(B + (long)(n0 + row) * K + k0 + kg * 32 + sc2,
                 Bs + buf * ASZ + kg * PSZ + cb * 512);
      }
    }
  };

  float4_t acc[4][4] = {};
  int cur = 0;
  stage(0, 0);
  for (int k0 = 0; k0 < K; k0 += BK) {
    __syncthreads();
    if (k0 + BK < K) stage(cur ^ 1, k0 + BK);
    #pragma unroll
    for (int kg = 0; kg < 2; kg++) {
      const short* Ab = As + cur * ASZ + kg * PSZ;
      const short* Bb = Bs + cur * ASZ + kg * PSZ;
      short8_t af[4], bf[4];
      #pragma unroll
      for (int m = 0; m < 4; m++) af[m] = ldfrag(Ab, wr * 64 + m * 16 + lr, lg);
      #pragma unroll
      for (int n = 0; n < 4; n++) bf[n] = ldfrag(Bb, wc * 64 + n * 16 + lr, lg);
      #pragma unroll
      for (int m = 0; m < 4; m++)
        #pragma unroll
        for (int n = 0; n < 4; n++)
          acc[m][n] = __builtin_amdgcn_mfma_f32_16x16x32_bf16(af[m], bf[n], acc[m][n], 0, 0, 0);
    }
    cur ^= 1;
  }

  #pragma unroll
  for (int m = 0; m < 4; m++)
    #pragma unroll
    for (int n = 0; n < 4; n++)
      #pragma unroll
      for (int r = 0; r < 4; r++) {
        const int row = m0 + wr * 64 + m * 16 + lg * 4 + r;
        const int col = n0 + wc * 64 + n * 16 + lr;
        C[(long)row * P_ + col] = f2bf(acc[m][n][r]);
      }
}

// ---------------- out-proj GEMM: 64x64 tile, BK=128 (panel LDS [kg][64][32]), 12 phases ----------
__global__ __launch_bounds__(256) void gemm_out_k(
    const short* __restrict__ A, const short* __restrict__ B, float* __restrict__ C,
    int M, int N, int K)
{
  constexpr int PSZ = 64 * 32;
  constexpr int BKG = 4;
  constexpr int BUF = PSZ * BKG;
  __shared__ short As[2 * BUF];
  __shared__ short Bs[2 * BUF];
  const int tid = threadIdx.x;
  const int w = tid >> 6, lane = tid & 63;
  const int lr = lane & 15, lg = lane >> 4;
  const int wr = w >> 1, wc = w & 1;
  const int m0 = blockIdx.y * 64, n0 = blockIdx.x * 64;
  const int srow = lane >> 2;
  const int sc = (lane & 3) * 8;

  auto stage = [&](int buf, int k0) {
    const int row = w * 16 + srow;
    #pragma unroll
    for (int kg = 0; kg < BKG; kg++) {
      gl_lds16(A + (long)(m0 + row) * K + k0 + kg * 32 + sc, As + buf * BUF + kg * PSZ + w * 512);
      gl_lds16(B + (long)(n0 + row) * K + k0 + kg * 32 + sc, Bs + buf * BUF + kg * PSZ + w * 512);
    }
  };

  float4_t acc[2][2] = {};
  int cur = 0;
  stage(0, 0);
  for (int k0 = 0; k0 < K; k0 += 128) {
    __syncthreads();
    if (k0 + 128 < K) stage(cur ^ 1, k0 + 128);
    #pragma unroll
    for (int kg = 0; kg < BKG; kg++) {
      const short* Ab = As + cur * BUF + kg * PSZ;
      const short* Bb = Bs + cur * BUF + kg * PSZ;
      short8_t af[2], bf[2];
      #pragma unroll
      for (int m = 0; m < 2; m++) af[m] = ldfrag(Ab, wr * 32 + m * 16 + lr, lg);
      #pragma unroll
      for (int n = 0; n < 2; n++) bf[n] = ldfrag(Bb, wc * 32 + n * 16 + lr, lg);
      #pragma unroll
      for (int m = 0; m < 2; m++)
        #pragma unroll
        for (int n = 0; n < 2; n++)
          acc[m][n] = __builtin_amdgcn_mfma_f32_16x16x32_bf16(af[m], bf[n], acc[m][n], 0, 0, 0);
    }
    cur ^= 1;
  }

  #pragma unroll
  for (int m = 0; m < 2; m++)
    #pragma unroll
    for (int n = 0; n < 2; n++)
      #pragma unroll
      for (int r = 0; r < 4; r++) {
        const int row = m0 + wr * 32 + m * 16 + lg * 4 + r;
        const int col = n0 + wc * 32 + n * 16 + lr;
        C[(long)row * N + col] = acc[m][n][r];
      }
}

// ---------------- CB GEMM (bf16 MFMA, single phase: whole K=128 staged once) ----------------
__global__ __launch_bounds__(256) void gemm_cbh_k(
    const short* __restrict__ Chh, const short* __restrict__ Bh, short* __restrict__ CBh)
{
  if (blockIdx.x > blockIdx.y) return;
  Chh += (long)blockIdx.z * T_ * NS_;
  Bh  += (long)blockIdx.z * T_ * NS_;
  CBh += (long)blockIdx.z * T_ * T_;
  constexpr int PSZ = 64 * 32;
  __shared__ short As[4 * PSZ];
  __shared__ short Bs[4 * PSZ];
  const int tid = threadIdx.x;
  const int w = tid >> 6, lane = tid & 63;
  const int lr = lane & 15, lg = lane >> 4;
  const int wr = w >> 1, wc = w & 1;
  const int m0 = blockIdx.y * 64, n0 = blockIdx.x * 64;
  const int srow = lane >> 2;
  const int sc = (lane & 3) * 8;

  {
    const int row = w * 16 + srow;
    #pragma unroll
    for (int kg = 0; kg < 4; kg++) {
      gl_lds16(Chh + (long)(m0 + row) * NS_ + kg * 32 + sc, As + kg * PSZ + w * 512);
      gl_lds16(Bh  + (long)(n0 + row) * NS_ + kg * 32 + sc, Bs + kg * PSZ + w * 512);
    }
  }
  __syncthreads();

  float4_t acc[2][2] = {};
  #pragma unroll
  for (int kg = 0; kg < 4; kg++) {
    const short* Ab = As + kg * PSZ;
    const short* Bb = Bs + kg * PSZ;
    short8_t af[2], bf[2];
    #pragma unroll
    for (int m = 0; m < 2; m++) af[m] = ldfrag(Ab, wr * 32 + m * 16 + lr, lg);
    #pragma unroll
    for (int n = 0; n < 2; n++) bf[n] = ldfrag(Bb, wc * 32 + n * 16 + lr, lg);
    #pragma unroll
    for (int m = 0; m < 2; m++)
      #pragma unroll
      for (int n = 0; n < 2; n++)
        acc[m][n] = __builtin_amdgcn_mfma_f32_16x16x32_bf16(af[m], bf[n], acc[m][n], 0, 0, 0);
  }

  #pragma unroll
  for (int m = 0; m < 2; m++)
    #pragma unroll
    for (int n = 0; n < 2; n++)
      #pragma unroll
      for (int r = 0; r < 4; r++) {
        const int row = m0 + wr * 32 + m * 16 + lg * 4 + r;
        const int sl = wc * 32 + n * 16 + lr;        // local col 0..63
        const int g = sl >> 5, k32 = sl & 31;
        const int cc = g * 4 + ((k32 >> 2) & 3);
        const int off = ((cc ^ (row & 7)) * 8) + 4 * (k32 >> 4) + (k32 & 3);
        CBh[(long)row * T_ + n0 + off] = f2bf(acc[m][n][r]);
      }
}

// ---------------- conv (K=4) + bias + SiLU + fused x-transpose; B/C -> bf16 permuted --------------
// Staging now vectorized: short8 chunks (608 b128 loads/block) instead of 19 scalar bf16/thread.
__global__ __launch_bounds__(256) void conv_silu_k(
    const short* __restrict__ projh, const float* __restrict__ cw, const float* __restrict__ cbias,
    const float* __restrict__ qT,
    short* __restrict__ xTr, short* __restrict__ xTq,
    short* __restrict__ Bh, short* __restrict__ Chh)
{
  const int c0 = blockIdx.x * 256;
  const int t0 = blockIdx.y * 16;
  const int b  = blockIdx.z;
  const int tid = threadIdx.x;
  __shared__ float S[19][256];
  for (int q = tid; q < 19 * 32; q += 256) {
    const int r = q >> 5, c8 = (q & 31) * 8;
    const int t = t0 - 3 + r;
    float4 f0 = {0.f, 0.f, 0.f, 0.f}, f1 = {0.f, 0.f, 0.f, 0.f};
    if (t >= 0) {
      short8_t v = *(const short8_t*)(projh + ((long)b * T_ + t) * P_ + INTER_ + c0 + c8);
      f0.x = bf2f(v[0]); f0.y = bf2f(v[1]); f0.z = bf2f(v[2]); f0.w = bf2f(v[3]);
      f1.x = bf2f(v[4]); f1.y = bf2f(v[5]); f1.z = bf2f(v[6]); f1.w = bf2f(v[7]);
    }
    *(float4*)(&S[r][c8])     = f0;
    *(float4*)(&S[r][c8 + 4]) = f1;
  }
  __syncthreads();
  const int c = c0 + tid;
  const float4 w = *(const float4*)(cw + c * 4);
  const float bias = cbias[c];
  float acc[16];
  #pragma unroll
  for (int tt = 0; tt < 16; tt++) {
    float a = bias + w.w * S[tt + 3][tid] + w.z * S[tt + 2][tid]
                   + w.y * S[tt + 1][tid] + w.x * S[tt][tid];
    acc[tt] = a / (1.f + __expf(-a));   // SiLU
  }
  if (c < INTER_) {
    const int h = c >> 6, hd = c & 63;
    const long chb = (long)(h * B_ + b) * T_;
    float qv[16];
    #pragma unroll
    for (int qq = 0; qq < 4; qq++) {
      float4 q4 = *(const float4*)(qT + chb + t0 + qq * 4);
      qv[qq*4+0] = q4.x; qv[qq*4+1] = q4.y; qv[qq*4+2] = q4.z; qv[qq*4+3] = q4.w;
    }
    const long base = ((long)(b * NH_ + h) * HD_ + hd) * T_ + (t0 & ~63);
    const int g = (t0 >> 5) & 1, h2 = (t0 >> 4) & 1, sw = hd & 7;
    #pragma unroll
    for (int a = 0; a < 4; a++) {
      short4_t xr, xq;
      #pragma unroll
      for (int r = 0; r < 4; r++) {
        xr[r] = f2bf(acc[a * 4 + r]);
        xq[r] = f2bf(acc[a * 4 + r] * qv[a * 4 + r]);
      }
      const int off = (((g * 4 + a) ^ sw) * 8) + h2 * 4;
      *(short4_t*)(xTr + base + off) = xr;
      *(short4_t*)(xTq + base + off) = xq;
    }
  } else {
    const int ch0 = c - INTER_;
    const bool isB = ch0 < NS_;
    const int k = isB ? ch0 : ch0 - NS_;
    const int k32 = k & 31;
    const int P = (k & ~31) + 8 * ((k32 >> 2) & 3) + 4 * (k32 >> 4) + (k32 & 3);
    short* dst = isB ? Bh : Chh;
    #pragma unroll
    for (int tt = 0; tt < 16; tt++) {
      const long bt = (long)b * T_ + t0 + tt;
      dst[bt * NS_ + P] = f2bf(acc[tt]);
    }
  }
}

// ---------------- MFMA attention v4: depth-2 DMA pipeline (counted vmcnt, raw barriers) ----------
// 3 LDS buffers; stage st+2 issued while computing st; s_waitcnt vmcnt(4) keeps the next
// stage's 4 gl_lds16 in flight across the barrier (T3/T4). Off-diag iterations contain NO
// global loads (caE hoisted to LDS) so compiler pre-use waits can't drain our prefetch.
__global__ __launch_bounds__(256) void attn_mfma3_k(
    const short* __restrict__ xTr, const short* __restrict__ xTq,
    const short* __restrict__ CBh,
    const float* __restrict__ cAT, const float* __restrict__ dtT,
    const short* __restrict__ projh, const float* __restrict__ Lw,
    const float* __restrict__ Dv,
    short* __restrict__ ybh)
{
  const int h = blockIdx.x;
  const int tt = (T_ / 64 - 1) - blockIdx.y;   // heavy tiles first
  const int b = blockIdx.z;
  const int t0 = tt * 64;
  const int tid = threadIdx.x;
  const int w = tid >> 6, lane = tid & 63;
  const int lr = lane & 15, lg = lane >> 4;

  __shared__ short CBl[3][64 * 64];
  __shared__ short Xl[3][64 * 64];
  __shared__ float lamS[64][17];
  __shared__ float caEs[16];

  const long chb = (long)(h * B_ + b) * T_;
  for (int f = tid; f < 64 * NLVL_; f += 256) {
    int r = f / NLVL_, l = f - r * NLVL_;
    lamS[r][l] = softplus_f(
        bf2f(projh[((long)b * T_ + t0 + r) * P_ + INTER_ + CONV_DIM_ + NH_ + h * NLVL_ + l]))
        * Lw[h * NLVL_ + l];
  }
  if (tid < 16) caEs[tid] = cAT[chb + tid * 64 + 63];

  const int tl = w * 16 + lr;              // A-frag row (local)
  const int t  = t0 + tl;
  const int orow = w * 16 + lg * 4;        // C/D output row base (local)
  const float catv = cAT[chb + t];         // diag (A-row indexed)
  float cao[4];                            // off-diag post-scale (output rows)
  #pragma unroll
  for (int r = 0; r < 4; r++) cao[r] = cAT[chb + t0 + orow + r];

  const short* xbr = xTr + (long)(b * NH_ + h) * HD_ * T_;
  const short* xbq = xTq + (long)(b * NH_ + h) * HD_ * T_;
  const short* CBbase = CBh + (long)b * T_ * T_ + (long)t0 * T_;

  const int srow = w * 16 + (lane >> 3);   // staged row (+ i*8)
  const int sch = (lane & 7) * 8;          // staged 16B chunk (physical)

  auto stage = [&](int buf, int st) {
    const int s0 = st * 64;
    const short* xsrc = (st == tt) ? xbr : xbq;
    #pragma unroll
    for (int i = 0; i < 2; i++) {
      gl_lds16(CBbase + (long)(srow + i * 8) * T_ + s0 + sch, &CBl[buf][(w * 16 + i * 8) * 64]);
      gl_lds16(xsrc + (long)(srow + i * 8) * T_ + s0 + sch, &Xl[buf][(w * 16 + i * 8) * 64]);
    }
  };

  float4_t acc[4] = {};
  stage(0, 0);                       // 4 DMAs in flight
  if (tt >= 1) stage(1, 1);          // +4 = 8 in flight
  asm volatile("s_waitcnt lgkmcnt(0)" ::: "memory");   // lamS/caEs ds_writes drained

  for (int st = 0; st <= tt; st++) {
    // Wait only for THIS stage's 4 DMAs; keep stage st+1's 4 in flight.
    if (st < tt) asm volatile("s_waitcnt vmcnt(4)" ::: "memory");
    else         asm volatile("s_waitcnt vmcnt(0)" ::: "memory");
    __builtin_amdgcn_s_barrier();
    __builtin_amdgcn_sched_barrier(0);
    if (st + 2 <= tt) stage((st + 2) % 3, st + 2);   // prefetch depth 2
    const int cur = st % 3;
    const int s0 = st * 64;
    if (st < tt) {
      const float caE = caEs[st];                    // LDS (no global load here!)
      const int lev = 32 - __clz(t0 ^ s0);
      float k1o[4];
      #pragma unroll
      for (int r = 0; r < 4; r++)
        k1o[r] = __expf(cao[r] - caE) * lamS[orow + r][lev];
      float4_t dtile[4] = {};
      __builtin_amdgcn_s_setprio(1);
      #pragma unroll
      for (int kk = 0; kk < 2; kk++) {
        short8_t af = ldfrag64(CBl[cur], tl, kk, lg);
        #pragma unroll
        for (int n = 0; n < 4; n++) {
          short8_t bfv = ldfrag64(Xl[cur], n * 16 + lr, kk, lg);
          dtile[n] = __builtin_amdgcn_mfma_f32_16x16x32_bf16(af, bfv, dtile[n], 0, 0, 0);
        }
      }
      __builtin_amdgcn_s_setprio(0);
      #pragma unroll
      for (int n = 0; n < 4; n++)
        #pragma unroll
        for (int r = 0; r < 4; r++)
          acc[n][r] = fmaf(k1o[r], dtile[n][r], acc[n][r]);
    } else {
      #pragma unroll
      for (int kk = 0; kk < 2; kk++) {
        short8_t cb8 = ldfrag64(CBl[cur], tl, kk, lg);
        short8_t af;
        #pragma unroll
        for (int g = 0; g < 2; g++) {
          const int sb = s0 + kk * 32 + g * 16 + lg * 4;
          float4_t ca4 = *(const float4_t*)(cAT + chb + sb);
          float4_t dt4 = *(const float4_t*)(dtT + chb + sb);
          #pragma unroll
          for (int a = 0; a < 4; a++) {
            const int sg = sb + a;
            float m = 0.f;
            if (sg <= t) {
              const int xo = t ^ sg;
              const int lev2 = xo ? (32 - __clz(xo)) : 0;
              m = bf2f(cb8[g * 4 + a]) * __expf(catv - ca4[a]) * lamS[tl][lev2] * dt4[a];
            }
            af[g * 4 + a] = f2bf(m);
          }
        }
        __builtin_amdgcn_s_setprio(1);
        #pragma unroll
        for (int n = 0; n < 4; n++) {
          short8_t bfv = ldfrag64(Xl[cur], n * 16 + lr, kk, lg);
          acc[n] = __builtin_amdgcn_mfma_f32_16x16x32_bf16(af, bfv, acc[n], 0, 0, 0);
        }
        __builtin_amdgcn_s_setprio(0);
      }
    }
  }

  // epilogue: y + D*x -> bf16. Diagonal-stage X tile is in Xl[tt % 3].
  const float Dh = Dv[h];
  const short* Xd = Xl[tt % 3];
  #pragma unroll
  for (int n = 0; n < 4; n++) {
    #pragma unroll
    for (int r = 0; r < 4; r++) {
      const int trow = t0 + orow + r;
      const int hd = n * 16 + lr;
      const int xoff = hd * 64 + ((((w >> 1) * 4 + lg) ^ (hd & 7)) * 8) + (w & 1) * 4 + r;
      const float xv = bf2f(Xd[xoff]);
      ybh[((long)b * T_ + trow) * INTER_ + h * HD_ + hd] = f2bf(acc[n][r] + Dh * xv);
    }
  }
}

// ---------------- gate: y * SiLU(g), RMSNorm -> bf16 permuted (D*x already in y) ----------------
__global__ __launch_bounds__(192) void gate_rms_k(
    const short* __restrict__ ybh, const short* __restrict__ projh,
    const float* __restrict__ nw, short* __restrict__ ynorm)
{
  const long bt = blockIdx.x;
  const short* gp = projh + bt * P_;
  const short* yp = ybh + bt * INTER_;
  const int i = threadIdx.x;                 // 0..191, one physical 16B chunk each
  const int lo = (i >> 2) * 32 + (i & 3) * 4;
  const int hi = lo + 16;
  float v[8];
  float ss = 0.f;
  {
    short4_t g0 = *(const short4_t*)(gp + lo);
    short4_t g1 = *(const short4_t*)(gp + hi);
    short4_t y0 = *(const short4_t*)(yp + lo);
    short4_t y1 = *(const short4_t*)(yp + hi);
    float ga[8] = {bf2f(g0[0]), bf2f(g0[1]), bf2f(g0[2]), bf2f(g0[3]),
                   bf2f(g1[0]), bf2f(g1[1]), bf2f(g1[2]), bf2f(g1[3])};
    float ya[8] = {bf2f(y0[0]), bf2f(y0[1]), bf2f(y0[2]), bf2f(y0[3]),
                   bf2f(y1[0]), bf2f(y1[1]), bf2f(y1[2]), bf2f(y1[3])};
    #pragma unroll
    for (int j = 0; j < 8; j++) {
      float val = ya[j] * (ga[j] / (1.f + __expf(-ga[j])));
      v[j] = val;
      ss += val * val;
    }
  }
  #pragma unroll
  for (int off = 32; off > 0; off >>= 1) ss += __shfl_xor(ss, off);
  __shared__ float part[3];
  if ((i & 63) == 0) part[i >> 6] = ss;
  __syncthreads();
  const float tot = part[0] + part[1] + part[2];
  const float r = rsqrtf(tot * (1.f / INTER_) + EPS_);
  short8_t o;
  #pragma unroll
  for (int j = 0; j < 8; j++) {
    const int idx = (j < 4) ? (lo + j) : (hi + j - 4);
    o[j] = f2bf(v[j] * r * nw[idx]);
  }
  *(short8_t*)(ynorm + bt * INTER_ + i * 8) = o;
}

extern "C" void kernel_launch(void* const* d_in, const int* in_sizes, int n_in,
                              void* d_out, int out_size, void* d_ws, size_t ws_size,
                              hipStream_t stream) {
  const float* hs   = (const float*)d_in[0];
  const float* Win  = (const float*)d_in[1];
  const float* cw   = (const float*)d_in[2];
  const float* cb   = (const float*)d_in[3];
  const float* dtb  = (const float*)d_in[4];
  const float* Alog = (const float*)d_in[5];
  const float* Lw   = (const float*)d_in[6];
  const float* Dv   = (const float*)d_in[7];
  const float* nw   = (const float*)d_in[8];
  const float* Wout = (const float*)d_in[9];
  float* out = (float*)d_out;

  const long n_hs = (long)B_ * T_ * HID_;       // 1,572,864
  const long n_wi = (long)P_ * HID_;            // 2,850,816
  const long n_wo = (long)HID_ * INTER_;        // 1,179,648

  float* ws = (float*)d_ws;
  long o = 0;
  float* projreg = ws + o; o += (long)B_ * T_ * P_ / 2 + 16;         // bf16 proj
  short* xbf   = (short*)(ws + o); o += (long)B_ * T_ * INTER_ / 2;  // (slot retained, unused)
  short* Bh    = (short*)(ws + o); o += (long)B_ * T_ * NS_ / 2;     // bf16 permuted B
  short* Chh   = (short*)(ws + o); o += (long)B_ * T_ * NS_ / 2;     // bf16 permuted C
  float* dtT   = ws + o; o += (long)B_ * T_ * NH_;
  float* cAT   = ws + o; o += (long)B_ * T_ * NH_;
  float* qT    = ws + o; o += (long)B_ * T_ * NH_;
  float* dtraw = ws + o; o += (long)B_ * T_ * NH_;
  short* CBh   = (short*)(ws + o); o += (long)B_ * T_ * T_ / 2;
  short* ybh   = (short*)(ws + o); o += (long)B_ * T_ * INTER_ / 2;
  float* yxreg = ws + o; o += (long)B_ * T_ * INTER_ / 2;
  short* hsbf  = (short*)(ws + o); o += n_hs / 2;
  short* wibf  = (short*)(ws + o); o += n_wi / 2;
  short* wobf  = (short*)(ws + o); o += n_wo / 2;
  short* projh = (short*)projreg;  // bf16 proj: alive in-proj..gate_rms
  short* xTr   = (short*)yxreg;    // alive: conv..attn
  short* ynrmb = (short*)yxreg;    // alive: gate_rms..out-proj (after attn)
  short* xTq   = hsbf;             // aliases hsbf+wibf (dead after in-proj GEMM)
  (void)xbf;

  const int ncvt = (int)((n_hs + n_wi + n_wo) / 8 / 256);   // 2736

  // 0. fused cvt (bf16 K-permuted) + fp32 dt columns
  cvtdt_k<<<ncvt + (B_ * T_) / 4, 256, 0, stream>>>(
      hs, Win, Wout, hsbf, wibf, wobf, dtraw, ncvt);
  // 1. in-proj GEMM (bf16 MFMA, dbuf, 128x128, BK=64, bf16 out) + fused dt_scan rows
  inproj_scan_k<<<dim3(P_ / 128, 18), 256, 0, stream>>>(
      hsbf, wibf, projh, dtraw, dtb, Alog, dtT, cAT, qT);
  // 2. conv + SiLU + split + fused x-transpose; B/C bf16 permuted (vectorized staging)
  conv_silu_k<<<dim3(CONV_DIM_ / 256, T_ / 16, B_), 256, 0, stream>>>(
      projh, cw, cb, qT, xTr, xTq, Bh, Chh);
  // 3. CB (bf16 MFMA, single-phase K=128, lower-tri, permuted+swizzled bf16 out)
  gemm_cbh_k<<<dim3(T_ / 64, T_ / 64, B_), 256, 0, stream>>>(Chh, Bh, CBh);
  // 4. MFMA attention v4 (depth-2 counted-vmcnt pipeline) -> bf16 y (D*x folded)
  attn_mfma3_k<<<dim3(NH_, T_ / 64, B_), 256, 0, stream>>>(
      xTr, xTq, CBh, cAT, dtT, projh, Lw, Dv, ybh);
  // 5. gate + RMSNorm -> bf16 permuted  (last reader of projh)
  gate_rms_k<<<B_ * T_, 192, 0, stream>>>(ybh, projh, nw, ynrmb);
  // 6. out-proj GEMM (bf16 MFMA, BK=128, single-pass, fp32 -> out)
  gemm_out_k<<<dim3(HID_ / 64, (B_ * T_) / 64), 256, 0, stream>>>(
      ynrmb, wobf, out, B_ * T_, HID_, INTER_);
}